// Round 4
// baseline (491.453 us; speedup 1.0000x reference)
//
#include <hip/hip_runtime.h>
#include <hip/hip_bf16.h>
#include <math.h>

#define B_    8
#define CIN   32
#define CO    64
#define NN    512
#define TT    24
#define NT    (NN*TT)        /* 12288 */
#define LNCNT (CO*NT)        /* 786432 */
#define EPSL  1e-5f
#define MAXNZ 64
#define HSS   28             /* fp32 LDS row stride (hbuild) */

typedef const float* fp;
static __device__ __forceinline__ float lk(float x){ return x > 0.f ? x : 0.01f*x; }
static __device__ __forceinline__ float sg(float x){
    if(x >= 0.f){ float e = expf(-x); return 1.f/(1.f+e); }
    float e = expf(x); return e/(1.f+e);
}
// bf16 pair pack/unpack (lo = even element, hi = odd element)
static __device__ __forceinline__ unsigned pk2(float a, float b){
    __hip_bfloat16 x = __float2bfloat16(a), y = __float2bfloat16(b);
    unsigned lo = *(unsigned short*)&x, hi = *(unsigned short*)&y;
    return lo | (hi<<16);
}
static __device__ __forceinline__ float lo2f(unsigned u){ return __uint_as_float(u<<16); }
static __device__ __forceinline__ float hi2f(unsigned u){ return __uint_as_float(u & 0xffff0000u); }

// ---------------- CSC build from adj (2% dense), fully parallel ----------------
__global__ __launch_bounds__(256) void k_csc(fp adj, int* cnt, int* idx, float* val){
    int e = blockIdx.x*blockDim.x + threadIdx.x;   // 0 .. NN*NN-1
    if(e >= NN*NN) return;
    float a = adj[e];
    if(a != 0.f){
        int u = e >> 9, q = e & 511;
        int slot = atomicAdd(&cnt[q], 1);
        if(slot < MAXNZ){ idx[q*MAXNZ+slot] = u; val[q*MAXNZ+slot] = a; }
    }
}
__global__ void k_deg(int* cnt, float* deginv){
    int q = blockIdx.x*blockDim.x + threadIdx.x;
    if(q < NN){
        int c = cnt[q];
        deginv[q] = 1.f / (c < 1 ? 1.f : (float)c);
        if(c > MAXNZ) cnt[q] = MAXNZ;
    }
}

// load 8 weights w[m][kb..kb+7] (T=24 bounds -> 0 pad), split hi/lo bf16 frags
static __device__ __forceinline__ void ldw_split(fp w, int m, int kb, uint4* hi, uint4* lo){
    float vh[8], vl[8];
    #pragma unroll
    for(int j=0;j<8;++j){
        float v = (m < TT && (kb+j) < TT) ? w[m*TT + kb + j] : 0.f;
        __hip_bfloat16 hb = __float2bfloat16(v);
        float hf = __bfloat162float(hb);
        vh[j] = hf;
        vl[j] = v - hf;
    }
    *hi = make_uint4(pk2(vh[0],vh[1]),pk2(vh[2],vh[3]),pk2(vh[4],vh[5]),pk2(vh[6],vh[7]));
    *lo = make_uint4(pk2(vl[0],vl[1]),pk2(vl[2],vl[3]),pk2(vl[4],vl[5]),pk2(vl[6],vl[7]));
}

// ---- one-time weight fragment prep: wf[L*512 + g*128 + P*64 + lane] ----
// g: 0=(ws,mA) 1=(ws,mB) 2=(wn,mA) 3=(wn,mB); P: 0=hi 1=lo
__global__ __launch_bounds__(256) void k_wprep(fp s0ws, fp s0wn, fp s1ws, fp s1wn, uint4* wf){
    int t = threadIdx.x;
    int lane = t & 63, g = t >> 6;
    int M = g >> 1, H = g & 1;
    int m  = H*16 + (lane&15);
    int kb = (lane>>4)*8;
    for(int L=0; L<2; ++L){
        fp w = L ? (M ? s1wn : s1ws) : (M ? s0wn : s0ws);
        uint4 hi, lo;
        ldw_split(w, m, kb, &hi, &lo);
        wf[L*512 + g*128 +      lane] = hi;
        wf[L*512 + g*128 + 64 + lane] = lo;
    }
}

// ---- conv1 (1x1) + temporal conv (1x3) + LN stats; block=(b, 4-n tile) ----
// b128 LDS restructure (round 4): x rows stride 28 (7x float4, 16B aligned),
// nl-stride 904 (=8 mod 32 -> 4 broadcast addrs in distinct bank-quads);
// weights packed float4 (w1,wt0,wt1,wt2) row-stride 33 quads ((o+c)%8 spread).
// Values + FMA order identical to scalar version -> bit-identical output.
__global__ __launch_bounds__(256) void k_conv(fp x, fp w1, fp b1, fp wt, fp bt,
        float* xin, float* x1p, float* stats){
    __shared__ float xs[4*904];          // 14.5 KB: [nl][c*28 + t+1]
    __shared__ float wq[CO*33*4];        // 33.8 KB: float4 per (o,c)
    __shared__ float red[256];
    int bid = blockIdx.x; int b = bid>>7; int n0 = (bid&127)*4;
    int tid = threadIdx.x;
    for(int j=tid;j<CIN*4*TT;j+=256){
        int c = j/96; int r = j%96; int nl = r/24; int t = r%24;
        xs[nl*904 + c*28 + t+1] = x[((b*CIN+c)*NN + n0+nl)*TT + t];
    }
    for(int j=tid;j<CIN*4;j+=256){ int c=j>>2; int nl=j&3;
        xs[nl*904+c*28]=0.f; xs[nl*904+c*28+25]=0.f;
        xs[nl*904+c*28+26]=0.f; xs[nl*904+c*28+27]=0.f; }
    for(int j=tid;j<CO*CIN;j+=256){
        int o=j>>5, c=j&31;
        *(float4*)&wq[(o*33+c)*4] = make_float4(w1[j], wt[j*3], wt[j*3+1], wt[j*3+2]);
    }
    __syncthreads();
    int o = tid>>2, nl = tid&3;
    float a0[TT], a1[TT];
    float bb1=b1[o], bbt=bt[o];
    #pragma unroll
    for(int t=0;t<TT;++t){ a0[t]=bb1; a1[t]=bbt; }
    const float* xrow = &xs[nl*904];
    for(int c=0;c<CIN;++c){
        const float4 wv = *(const float4*)&wq[(o*33+c)*4];
        float xr[28];
        const float4* xp = (const float4*)&xrow[c*28];
        #pragma unroll
        for(int t=0;t<7;++t){
            float4 v = xp[t];
            xr[4*t]=v.x; xr[4*t+1]=v.y; xr[4*t+2]=v.z; xr[4*t+3]=v.w;
        }
        #pragma unroll
        for(int t=0;t<TT;++t){
            a0[t] += xr[t+1]*wv.x;
            a1[t] += xr[t]*wv.y + xr[t+1]*wv.z + xr[t+2]*wv.w;
        }
    }
    size_t base = (size_t)(b*CO+o)*NT + (size_t)(n0+nl)*TT;
    #pragma unroll
    for(int k=0;k<6;++k){
        *(float4*)(xin + base + 4*k) = make_float4(a0[4*k],a0[4*k+1],a0[4*k+2],a0[4*k+3]);
        *(float4*)(x1p + base + 4*k) = make_float4(a1[4*k],a1[4*k+1],a1[4*k+2],a1[4*k+3]);
    }
    float ls=0.f, lsq=0.f;
    #pragma unroll
    for(int t=0;t<TT;++t){ ls+=a1[t]; lsq+=a1[t]*a1[t]; }
    red[tid]=ls; __syncthreads();
    for(int s=128;s>0;s>>=1){ if(tid<s) red[tid]+=red[tid+s]; __syncthreads(); }
    float tsum = red[0]; __syncthreads();
    red[tid]=lsq; __syncthreads();
    for(int s=128;s>0;s>>=1){ if(tid<s) red[tid]+=red[tid+s]; __syncthreads(); }
    if(tid==0){ atomicAdd(&stats[b], tsum); atomicAdd(&stats[8+b], red[0]); }
}

// ---------------- finalize per-batch LN stats ----------------
__global__ void k_stat(float* stats, int off){
    int b = threadIdx.x;
    if(b < 8){
        float m = stats[off+b] / (float)LNCNT;
        float v = stats[off+8+b] / (float)LNCNT - m*m;
        v = fmaxf(v, 0.f);
        stats[off+16+b] = m;
        stats[off+24+b] = rsqrtf(v + EPSL);
    }
}

// ---- LN+leaky (fused) then h = stack(4*x1, adj^T x1); h stored packed bf16 ----
__global__ __launch_bounds__(256) void k_hbuild(fp x1p, fp lng, fp lnb,
        const float* stats, const int* cnt, const int* idx, const float* val, unsigned* h){
    __shared__ float xs[NN*HSS];          // 57.3 KB
    int blk = blockIdx.x; int b = blk >> 6; int c = blk & 63;
    int tid = threadIdx.x;
    float m = stats[16+b], inv = stats[24+b];
    fp src = x1p + (size_t)(b*CO + c)*NT;
    for(int i=tid;i<NT;i+=256){
        int n = i/TT, t = i%TT;
        xs[n*HSS + t] = lk((src[i] - m)*inv*lng[c*NT + i] + lnb[c*NT + i]);
    }
    __syncthreads();
    unsigned* h0 = h + (size_t)((b*CO+c)*2 + 0)*(NT/2);
    unsigned* h1 = h0 + NT/2;
    #pragma unroll
    for(int half=0; half<2; ++half){
        int n = tid + half*256;
        float t1[TT], acc[TT];
        const float4* sp = (const float4*)&xs[n*HSS];
        #pragma unroll
        for(int k=0;k<6;++k){
            float4 v = sp[k];
            t1[4*k]=v.x; t1[4*k+1]=v.y; t1[4*k+2]=v.z; t1[4*k+3]=v.w;
        }
        #pragma unroll
        for(int l=0;l<TT;++l) acc[l]=0.f;
        int cq = cnt[n];
        for(int j=0;j<cq;++j){
            int u = idx[n*MAXNZ+j];
            float v = val[n*MAXNZ+j];
            const float4* rp = (const float4*)&xs[u*HSS];
            #pragma unroll
            for(int k=0;k<6;++k){
                float4 w = rp[k];
                acc[4*k]+=v*w.x; acc[4*k+1]+=v*w.y; acc[4*k+2]+=v*w.z; acc[4*k+3]+=v*w.w;
            }
        }
        #pragma unroll
        for(int k=0;k<3;++k){
            *(uint4*)(h0 + n*12 + 4*k) = make_uint4(
                pk2(4.f*t1[8*k],  4.f*t1[8*k+1]), pk2(4.f*t1[8*k+2],4.f*t1[8*k+3]),
                pk2(4.f*t1[8*k+4],4.f*t1[8*k+5]), pk2(4.f*t1[8*k+6],4.f*t1[8*k+7]));
            *(uint4*)(h1 + n*12 + 4*k) = make_uint4(
                pk2(acc[8*k],  acc[8*k+1]), pk2(acc[8*k+2],acc[8*k+3]),
                pk2(acc[8*k+4],acc[8*k+5]), pk2(acc[8*k+6],acc[8*k+7]));
        }
    }
}

// ======================= MFMA-based fused GraphSAGE x2 =======================
// H slab: 512 rows x 12 uints (48B, packed bf16). Raw stride-12 rows put
// b128 accesses at the bank-access floor (B-frags 6/bank, gather ~8/bank).
// K=24..31 zero pad lives in REGISTERS (lanes>=48 zero frags), not LDS.
// Weight A-frags precomputed by k_wprep (hi/lo bf16 split; fp32-class error).
// NOTE: launch_bounds min-waves MUST stay <=4: at 6 the VGPR cap (~85)
// forces scratch spills (+230MB HBM traffic, round-2 regression).
typedef __attribute__((ext_vector_type(8))) short bf16x8;
typedef __attribute__((ext_vector_type(4))) float f32x4;

static __device__ __forceinline__ f32x4 MF(uint4 a, uint4 b, f32x4 c){
    union { uint4 u; bf16x8 v; } A, Bv; A.u = a; Bv.u = b;
    return __builtin_amdgcn_mfma_f32_16x16x32_bf16(A.v, Bv.v, c, 0, 0, 0);
}
static __device__ __forceinline__ void acc8(float* t, uint4 q){
    t[0]+=lo2f(q.x); t[1]+=hi2f(q.x); t[2]+=lo2f(q.y); t[3]+=hi2f(q.y);
    t[4]+=lo2f(q.z); t[5]+=hi2f(q.z); t[6]+=lo2f(q.w); t[7]+=hi2f(q.w);
}

#define GBODY(u) { int ro=(u)*12; \
    uint4 q0=*(const uint4*)&hsb[ro]; \
    uint4 q1=*(const uint4*)&hsb[ro+4]; \
    uint4 q2=*(const uint4*)&hsb[ro+8]; \
    acc8(t2,q0); acc8(t2+8,q1); acc8(t2+16,q2); }
#define GSTEP(J,U) if((J)<cq) GBODY(U)

__global__ __launch_bounds__(512, 4) void k_sageF(unsigned* h, const uint4* wf,
        fp s0b, fp s1b, const int* cnt, const int* idx, const float* deginv){
    __shared__ unsigned hsb[NN*12];       // 24 KB
    __shared__ unsigned t2s[NN*12];       // 24 KB
    int tid  = threadIdx.x;
    int lane = tid & 63;
    int wv   = tid >> 6;
    unsigned* base = h + (size_t)blockIdx.x*(NT/2);

    for(int i=tid;i<1536;i+=512) ((uint4*)hsb)[i] = ((const uint4*)base)[i];
    int n  = tid;              // gather: this thread owns node n
    int cq = cnt[n];
    float di = deginv[n];
    int4 i0 = *(const int4*)&idx[n*MAXNZ+0];   // prefetch (entries >= cq unused)
    int4 i1 = *(const int4*)&idx[n*MAXNZ+4];
    int4 i2 = *(const int4*)&idx[n*MAXNZ+8];
    __syncthreads();

    for(int layer=0; layer<2; ++layer){
        const uint4* wl = wf + layer*512;
        uint4 wsHiA = wl[      lane], wsLoA = wl[ 64+lane];
        uint4 wsHiB = wl[128 + lane], wsLoB = wl[192+lane];
        uint4 wnHiA = wl[256 + lane], wnLoA = wl[320+lane];
        uint4 wnHiB = wl[384 + lane], wnLoB = wl[448+lane];
        fp Bp = layer ? s1b : s0b;
        float biA[4], biB[4];
        #pragma unroll
        for(int r=0;r<4;++r){
            biA[r] = Bp[(lane>>4)*4 + r];
            int m2 = 16 + (lane>>4)*4 + r;
            biB[r] = (m2 < TT) ? Bp[m2] : 0.f;
        }

        // ---- phase 1: gather t2 (reads hsb), stage into t2s; load B0 frags ----
        float t2[TT];
        #pragma unroll
        for(int l=0;l<TT;++l) t2[l]=0.f;
        GSTEP(0,i0.x) GSTEP(1,i0.y) GSTEP(2,i0.z) GSTEP(3,i0.w)
        GSTEP(4,i1.x) GSTEP(5,i1.y) GSTEP(6,i1.z) GSTEP(7,i1.w)
        GSTEP(8,i2.x) GSTEP(9,i2.y) GSTEP(10,i2.z) GSTEP(11,i2.w)
        for(int j=12;j<cq;++j){ int u=idx[n*MAXNZ+j]; GBODY(u) }
        #pragma unroll
        for(int l=0;l<TT;++l) t2[l]*=di;
        *(uint4*)&t2s[n*12  ] = make_uint4(
            pk2(t2[0],t2[1]),  pk2(t2[2],t2[3]),  pk2(t2[4],t2[5]),  pk2(t2[6],t2[7]));
        *(uint4*)&t2s[n*12+4] = make_uint4(
            pk2(t2[8],t2[9]),  pk2(t2[10],t2[11]),pk2(t2[12],t2[13]),pk2(t2[14],t2[15]));
        *(uint4*)&t2s[n*12+8] = make_uint4(
            pk2(t2[16],t2[17]),pk2(t2[18],t2[19]),pk2(t2[20],t2[21]),pk2(t2[22],t2[23]));

        uint4 b0[4], b1[4];
        #pragma unroll
        for(int i=0;i<4;++i){ b0[i]=make_uint4(0,0,0,0); b1[i]=make_uint4(0,0,0,0); }
        if(lane < 48){
            #pragma unroll
            for(int i=0;i<4;++i){
                int nn_ = wv*64 + i*16 + (lane&15);
                b0[i] = *(const uint4*)&hsb[nn_*12 + ((lane>>4)<<2)];
            }
        }
        __syncthreads();   // t2s ready; all hsb reads complete

        // ---- phase 2: B1 frags, 32 MFMAs, lane-local pack, write-back ----
        if(lane < 48){
            #pragma unroll
            for(int i=0;i<4;++i){
                int nn_ = wv*64 + i*16 + (lane&15);
                b1[i] = *(const uint4*)&t2s[nn_*12 + ((lane>>4)<<2)];
            }
        }
        #pragma unroll
        for(int i=0;i<4;++i){
            f32x4 Da = {biA[0],biA[1],biA[2],biA[3]};
            f32x4 Db = {biB[0],biB[1],biB[2],biB[3]};
            Da = MF(wsHiA, b0[i], Da);
            Da = MF(wsLoA, b0[i], Da);
            Da = MF(wnHiA, b1[i], Da);
            Da = MF(wnLoA, b1[i], Da);
            Db = MF(wsHiB, b0[i], Db);
            Db = MF(wsLoB, b0[i], Db);
            Db = MF(wnHiB, b1[i], Db);
            Db = MF(wnLoB, b1[i], Db);
            int nn_ = wv*64 + i*16 + (lane&15);
            int o = (lane>>4)*2;           // uints {0,2,4,6}: m = 2o..2o+3
            *(uint2*)&hsb[nn_*12 + o] =
                make_uint2(pk2(Da[0],Da[1]), pk2(Da[2],Da[3]));
            if(lane < 32){                 // m = 16..23 -> uints {8,10}
                *(uint2*)&hsb[nn_*12 + 8 + (lane>>4)*2] =
                    make_uint2(pk2(Db[0],Db[1]), pk2(Db[2],Db[3]));
            }
        }
        __syncthreads();   // D visible; t2s reads done -> next layer safe
    }
    for(int i=tid;i<1536;i+=512) ((uint4*)base)[i] = ((const uint4*)hsb)[i];
}

// ---- f1[b,l,n] = sum_c sg(gate)*lk(filt)*w1[c] ; gate fused, HA bf16 input ----
__global__ __launch_bounds__(256) void k_f1(const unsigned* h, fp w1, float* f1){
    int blk = blockIdx.x; int b = blk/16; int n0 = (blk%16)*32;
    int tid = threadIdx.x;
    float acc[3] = {0.f,0.f,0.f};
    const unsigned* fb = h + (size_t)b*CO*NT + n0*12;   // filt ch 0, row n0
    const unsigned* gb = fb + (size_t)CO*(NT/2);        // gate ch 0, row n0
    for(int c=0;c<CO;++c){
        float w = w1[c];
        const unsigned* fu = fb + (size_t)c*(NT/2);
        const unsigned* gu = gb + (size_t)c*(NT/2);
        #pragma unroll
        for(int r=0;r<3;++r){
            int e = tid + 256*r;
            unsigned f = fu[e>>1], g = gu[e>>1];
            float fv = (e&1) ? hi2f(f) : lo2f(f);
            float gv = (e&1) ? hi2f(g) : lo2f(g);
            acc[r] += sg(gv)*lk(fv)*w;
        }
    }
    #pragma unroll
    for(int r=0;r<3;++r){
        int p = tid + 256*r;
        int nl = p/TT, t = p%TT;
        f1[(b*TT+t)*NN + n0+nl] = acc[r];
    }
}

// ---- f2[b,c,l] = sum_n sg(gate)*lk(filt)*w2[n] ; gate fused ----
__global__ __launch_bounds__(256) void k_f2(const unsigned* h, fp w2, float* f2){
    __shared__ float red[256*TT];
    int blk = blockIdx.x; int b = blk/CO; int c = blk%CO;
    int tid = threadIdx.x;
    float acc[TT];
    #pragma unroll
    for(int l=0;l<TT;++l) acc[l]=0.f;
    const unsigned* fb = h + (size_t)b*CO*NT + (size_t)c*(NT/2);
    const unsigned* gb = fb + (size_t)CO*(NT/2);
    for(int n=tid;n<NN;n+=256){
        float w = w2[n];
        #pragma unroll
        for(int k=0;k<3;++k){
            uint4 f = *(const uint4*)(fb + n*12 + 4*k);
            uint4 g = *(const uint4*)(gb + n*12 + 4*k);
            acc[8*k  ] += sg(lo2f(g.x))*lk(lo2f(f.x))*w;
            acc[8*k+1] += sg(hi2f(g.x))*lk(hi2f(f.x))*w;
            acc[8*k+2] += sg(lo2f(g.y))*lk(lo2f(f.y))*w;
            acc[8*k+3] += sg(hi2f(g.y))*lk(hi2f(f.y))*w;
            acc[8*k+4] += sg(lo2f(g.z))*lk(lo2f(f.z))*w;
            acc[8*k+5] += sg(hi2f(g.z))*lk(hi2f(f.z))*w;
            acc[8*k+6] += sg(lo2f(g.w))*lk(lo2f(f.w))*w;
            acc[8*k+7] += sg(hi2f(g.w))*lk(hi2f(f.w))*w;
        }
    }
    #pragma unroll
    for(int l=0;l<TT;++l) red[tid*TT+l]=acc[l];
    __syncthreads();
    for(int s=128;s>0;s>>=1){
        if(tid<s){
            #pragma unroll
            for(int l=0;l<TT;++l) red[tid*TT+l]+=red[(tid+s)*TT+l];
        }
        __syncthreads();
    }
    if(tid<TT) f2[(b*CO+c)*TT+tid] = red[tid];
}

// ---------------- dilated(2) conv over n on f1 ; split 4x over n ----------------
__global__ __launch_bounds__(256) void k_conv_f1(fp f1, fp wd1, float* f1c){
    __shared__ float fs[TT][130];
    __shared__ float w0[TT*TT], w1a[TT*TT];
    int bid = blockIdx.x; int b = bid>>2; int n0 = (bid&3)*128;
    int tid=threadIdx.x;
    for(int i=tid;i<TT*130;i+=256){
        int l=i/130, col=i%130; int n = n0+col-1;
        fs[l][col] = (n>=0 && n<NN) ? f1[(b*TT+l)*NN+n] : 0.f;
    }
    for(int i=tid;i<TT*TT;i+=256){ w0[i]=wd1[i*2]; w1a[i]=wd1[i*2+1]; }
    __syncthreads();
    for(int j=tid;j<TT*128;j+=256){
        int o=j>>7, nn=j&127;
        float acc=0.f;
        #pragma unroll
        for(int i=0;i<TT;++i) acc += fs[i][nn]*w0[o*TT+i] + fs[i][nn+2]*w1a[o*TT+i];
        f1c[(b*TT+o)*NN+n0+nn]=acc;
    }
}

// ---------------- dilated(2) conv over l on f2 ----------------
__global__ __launch_bounds__(256) void k_conv_f2(fp f2, fp wd2, float* f2c){
    __shared__ float fs[CO][TT+2];
    __shared__ float w0[CO*CO], w1a[CO*CO];
    int b = blockIdx.x; int tid=threadIdx.x;
    for(int i=tid;i<CO*TT;i+=256){ int c=i/TT,l=i%TT; fs[c][l+1]=f2[(b*CO+c)*TT+l]; }
    for(int c=tid;c<CO;c+=256){ fs[c][0]=0.f; fs[c][TT+1]=0.f; }
    for(int i=tid;i<CO*CO;i+=256){ w0[i]=wd2[i*2]; w1a[i]=wd2[i*2+1]; }
    __syncthreads();
    for(int j=tid;j<CO*TT;j+=256){
        int o=j/TT, l=j%TT;
        float acc=0.f;
        for(int i=0;i<CO;++i) acc += fs[i][l]*w0[o*CO+i] + fs[i][l+2]*w1a[o*CO+i];
        f2c[(b*CO+o)*TT+l]=acc;
    }
}

// ---------------- g1[b,l,c] = sum_n f1c[b,l,n]*tW[n,c] ----------------
__global__ __launch_bounds__(256) void k_g1(fp f1c, fp tW, float* g1){
    __shared__ float fs[TT*NN];
    int b=blockIdx.x; int tid=threadIdx.x;
    for(int i=tid;i<TT*NN;i+=256) fs[i]=f1c[b*TT*NN+i];
    __syncthreads();
    int c = tid & 63; int lg = tid >> 6;
    float acc[6]={0.f,0.f,0.f,0.f,0.f,0.f};
    for(int n=0;n<NN;++n){
        float w = tW[n*CO + c];
        #pragma unroll
        for(int r=0;r<6;++r) acc[r] += fs[(lg*6+r)*NN + n]*w;
    }
    #pragma unroll
    for(int r=0;r<6;++r) g1[(b*TT + lg*6+r)*CO + c] = acc[r];
}

// ---------------- logits -> sigmoid -> t_v -> BN -> masked softmax -> T_coef ----------------
__global__ __launch_bounds__(1024) void k_logits(fp g1, fp f2c,
        fp tbias, fp tv, fp bng, fp bnb, float* coefs, float* tco){
    __shared__ float sig[B_*TT*TT];
    __shared__ float lg2[B_*TT*TT];
    __shared__ float muq[TT], scq[TT], shq[TT];
    int tid=threadIdx.x;
    for(int j=tid;j<B_*TT*TT;j+=1024){
        int b=j/(TT*TT); int r=j%(TT*TT); int l=r/TT; int q=r%TT;
        float acc = tbias[l*TT+q];
        fp gg = g1 + (b*TT+l)*CO;
        fp ff = f2c + b*CO*TT + q;
        for(int c=0;c<CO;++c) acc += gg[c]*ff[c*TT];
        sig[j] = sg(acc);
    }
    __syncthreads();
    for(int j=tid;j<B_*TT*TT;j+=1024){
        int b=j/(TT*TT); int r=j%(TT*TT); int l=r/TT; int q=r%TT;
        float acc=0.f;
        for(int k=0;k<TT;++k) acc += tv[l*TT+k]*sig[(b*TT+k)*TT+q];
        lg2[j]=acc;
    }
    __syncthreads();
    if(tid<TT){
        int q=tid;
        float s=0.f;
        for(int b=0;b<B_;++b) for(int l=0;l<TT;++l) s += lg2[(b*TT+l)*TT+q];
        float mu = s/192.f;
        float v=0.f;
        for(int b=0;b<B_;++b) for(int l=0;l<TT;++l){ float d = lg2[(b*TT+l)*TT+q]-mu; v += d*d; }
        v = fmaxf(v/192.f, 0.f);
        muq[q]=mu; scq[q]=rsqrtf(v+EPSL)*bng[q]; shq[q]=bnb[q];
    }
    __syncthreads();
    if(tid<192){
        int b=tid/TT, l=tid%TT;
        int base = (l<12)?0:12;
        float z[12];
        float mx=-1e30f;
        #pragma unroll
        for(int r=0;r<12;++r){
            int q=base+r;
            float zv=(lg2[(b*TT+l)*TT+q]-muq[q])*scq[q]+shq[q];
            z[r]=zv; mx = fmaxf(mx,zv);
        }
        float s=0.f;
        #pragma unroll
        for(int r=0;r<12;++r){ z[r]=expf(z[r]-mx); s+=z[r]; }
        float is=1.f/s;
        for(int q=0;q<TT;++q){
            float cf = (q>=base && q<base+12) ? z[q-base]*is : 0.f;
            coefs[(b*TT+l)*TT+q]=cf;
            tco[(b*TT+q)*TT+l]=cf;
        }
    }
}

// ---- x1new = xg @ coefs^T ; y = leaky(x1new)+x_input ; LN stats ----
// xg recomputed inline from packed-bf16 HA (gate fusion; bit-identical values)
__global__ __launch_bounds__(256) void k_apply(const unsigned* h, fp xin, fp coefs,
        float* y, float* stats){
    __shared__ float cf[TT*TT];
    __shared__ float red[256];
    int blk=blockIdx.x; int b=blk>>6; int c=blk&63; int tid=threadIdx.x;
    for(int i=tid;i<TT*TT;i+=256) cf[i]=coefs[b*TT*TT+i];
    __syncthreads();
    float ls=0.f,lsq=0.f;
    const unsigned* fb = h + (size_t)b*CO*NT + (size_t)c*(NT/2);
    const unsigned* gb = fb + (size_t)CO*(NT/2);
    fp xrow = xin + (size_t)(b*CO+c)*NT;
    float* yrow = y + (size_t)(b*CO+c)*NT;
    for(int n=tid;n<NN;n+=256){
        float row[TT], xi[TT], out[TT];
        #pragma unroll
        for(int k=0;k<3;++k){
            uint4 f = *(const uint4*)(fb + n*12 + 4*k);
            uint4 g = *(const uint4*)(gb + n*12 + 4*k);
            row[8*k  ] = sg(lo2f(g.x))*lk(lo2f(f.x));
            row[8*k+1] = sg(hi2f(g.x))*lk(hi2f(f.x));
            row[8*k+2] = sg(lo2f(g.y))*lk(lo2f(f.y));
            row[8*k+3] = sg(hi2f(g.y))*lk(hi2f(f.y));
            row[8*k+4] = sg(lo2f(g.z))*lk(lo2f(f.z));
            row[8*k+5] = sg(hi2f(g.z))*lk(hi2f(f.z));
            row[8*k+6] = sg(lo2f(g.w))*lk(lo2f(f.w));
            row[8*k+7] = sg(hi2f(g.w))*lk(hi2f(f.w));
        }
        #pragma unroll
        for(int k=0;k<6;++k){
            float4 u = *(const float4*)(xrow + n*TT + 4*k);
            xi[4*k]=u.x; xi[4*k+1]=u.y; xi[4*k+2]=u.z; xi[4*k+3]=u.w;
        }
        #pragma unroll
        for(int q=0;q<TT;++q){
            float acc=0.f;
            #pragma unroll
            for(int l=0;l<TT;++l) acc+=row[l]*cf[q*TT+l];
            float yv = lk(acc) + xi[q];
            out[q]=yv;
            ls+=yv; lsq+=yv*yv;
        }
        #pragma unroll
        for(int k=0;k<6;++k)
            *(float4*)(yrow + n*TT + 4*k) = make_float4(out[4*k],out[4*k+1],out[4*k+2],out[4*k+3]);
    }
    red[tid]=ls; __syncthreads();
    for(int s=128;s>0;s>>=1){ if(tid<s) red[tid]+=red[tid+s]; __syncthreads(); }
    float t0=red[0]; __syncthreads();
    red[tid]=lsq; __syncthreads();
    for(int s=128;s>0;s>>=1){ if(tid<s) red[tid]+=red[tid+s]; __syncthreads(); }
    if(tid==0){ atomicAdd(&stats[32+b], t0); atomicAdd(&stats[40+b], red[0]); }
}

// ---------------- final LN apply ----------------
__global__ void k_final(fp y, fp lng, fp lnb, const float* stats, float* out){
    int tot = B_*CO*NT;
    for(int i = blockIdx.x*blockDim.x + threadIdx.x; i<tot; i+=gridDim.x*blockDim.x){
        int b = i/LNCNT; int r = i%LNCNT;
        out[i] = (y[i]-stats[48+b])*stats[56+b]*lng[r]+lnb[r];
    }
}

extern "C" void kernel_launch(void* const* d_in, const int* in_sizes, int n_in,
                              void* d_out, int out_size, void* d_ws, size_t ws_size,
                              hipStream_t stream){
    fp x    = (fp)d_in[0];
    fp adj  = (fp)d_in[1];
    fp w1   = (fp)d_in[2];
    fp b1   = (fp)d_in[3];
    fp wt   = (fp)d_in[4];
    fp bt   = (fp)d_in[5];
    fp lng  = (fp)d_in[6];
    fp lnb  = (fp)d_in[7];
    fp s0ws = (fp)d_in[8];
    fp s0wn = (fp)d_in[9];
    fp s0b  = (fp)d_in[10];
    fp s1ws = (fp)d_in[11];
    fp s1wn = (fp)d_in[12];
    fp s1b  = (fp)d_in[13];
    fp tw1  = (fp)d_in[14];
    fp tw2  = (fp)d_in[15];
    fp twd1 = (fp)d_in[16];
    fp twd2 = (fp)d_in[17];
    fp tW   = (fp)d_in[18];
    fp tbias= (fp)d_in[19];
    fp tv   = (fp)d_in[20];
    fp bng  = (fp)d_in[21];
    fp bnb  = (fp)d_in[22];

    float* W = (float*)d_ws;            // stats [0..63]
    int*   CNTp = (int*)(W+256);        // 512 ints (zeroed each launch)
    float* DEG  = W+768;
    int*   IDXp = (int*)(W+1280);
    float* VALp = W+34048;
    float* F1   = W+66816;
    float* F1C  = W+165120;
    float* F2   = W+263424;
    float* F2C  = W+275712;
    float* G1   = W+288000;
    float* CF   = W+300288;
    float* XIN  = W+304896;
    float* X1   = W+6596352;
    uint4* WFq  = (uint4*)(W+12887808); // weight frags: 1024 uint4 = 16KB (old XG slot)
    unsigned* HA = (unsigned*)(W+19179264);   // packed bf16 h: 6291456 uints
    float* Y    = W+31762176;           // ends 38053632 floats = 152.2 MB

    float* oout   = (float*)d_out;
    float* o_adj  = oout + 6291456;
    float* o_tc   = oout + 6291456 + 262144;

    hipMemsetAsync(W, 0, 768*sizeof(float), stream);   // stats + cnt
    k_csc<<<1024,256,0,stream>>>(adj, CNTp, IDXp, VALp);
    k_deg<<<2,256,0,stream>>>(CNTp, DEG);
    k_wprep<<<1,256,0,stream>>>(s0ws, s0wn, s1ws, s1wn, WFq);
    k_conv<<<1024,256,0,stream>>>(x, w1, b1, wt, bt, XIN, X1, W);
    k_stat<<<1,64,0,stream>>>(W, 0);
    k_hbuild<<<512,256,0,stream>>>(X1, lng, lnb, W, CNTp, IDXp, VALp, HA);
    k_sageF<<<1024,512,0,stream>>>(HA, WFq, s0b, s1b, CNTp, IDXp, DEG);
    k_f1<<<128,256,0,stream>>>(HA, tw1, F1);
    k_f2<<<512,256,0,stream>>>(HA, tw2, F2);
    k_conv_f1<<<32,256,0,stream>>>(F1, twd1, F1C);
    k_conv_f2<<<8,256,0,stream>>>(F2, twd2, F2C);
    k_g1<<<8,256,0,stream>>>(F1C, tW, G1);
    k_logits<<<1,1024,0,stream>>>(G1, F2C, tbias, tv, bng, bnb, CF, o_tc);
    hipMemcpyAsync(o_adj, d_in[1], 262144*sizeof(float), hipMemcpyDeviceToDevice, stream);
    k_apply<<<512,256,0,stream>>>(HA, XIN, CF, Y, W);
    k_stat<<<1,64,0,stream>>>(W, 32);
    k_final<<<2048,256,0,stream>>>(Y, lng, lnb, W, oout);
}

// Round 5
// 456.079 us; speedup vs baseline: 1.0776x; 1.0776x over previous
//
#include <hip/hip_runtime.h>
#include <hip/hip_bf16.h>
#include <math.h>

#define B_    8
#define CIN   32
#define CO    64
#define NN    512
#define TT    24
#define NT    (NN*TT)        /* 12288 */
#define LNCNT (CO*NT)        /* 786432 */
#define EPSL  1e-5f
#define MAXNZ 64
#define HSS   28             /* fp32 LDS row stride (hbuild) */

typedef const float* fp;
static __device__ __forceinline__ float lk(float x){ return x > 0.f ? x : 0.01f*x; }
static __device__ __forceinline__ float sg(float x){
    if(x >= 0.f){ float e = expf(-x); return 1.f/(1.f+e); }
    float e = expf(x); return e/(1.f+e);
}
// bf16 pair pack/unpack (lo = even element, hi = odd element)
static __device__ __forceinline__ unsigned pk2(float a, float b){
    __hip_bfloat16 x = __float2bfloat16(a), y = __float2bfloat16(b);
    unsigned lo = *(unsigned short*)&x, hi = *(unsigned short*)&y;
    return lo | (hi<<16);
}
static __device__ __forceinline__ float lo2f(unsigned u){ return __uint_as_float(u<<16); }
static __device__ __forceinline__ float hi2f(unsigned u){ return __uint_as_float(u & 0xffff0000u); }

// ---------------- CSC build from adj (2% dense), fully parallel ----------------
__global__ __launch_bounds__(256) void k_csc(fp adj, int* cnt, int* idx, float* val){
    int e = blockIdx.x*blockDim.x + threadIdx.x;   // 0 .. NN*NN-1
    if(e >= NN*NN) return;
    float a = adj[e];
    if(a != 0.f){
        int u = e >> 9, q = e & 511;
        int slot = atomicAdd(&cnt[q], 1);
        if(slot < MAXNZ){ idx[q*MAXNZ+slot] = u; val[q*MAXNZ+slot] = a; }
    }
}
__global__ void k_deg(int* cnt, float* deginv){
    int q = blockIdx.x*blockDim.x + threadIdx.x;
    if(q < NN){
        int c = cnt[q];
        deginv[q] = 1.f / (c < 1 ? 1.f : (float)c);
        if(c > MAXNZ) cnt[q] = MAXNZ;
    }
}

// load 8 weights w[m][kb..kb+7] (T=24 bounds -> 0 pad), split hi/lo bf16 frags
static __device__ __forceinline__ void ldw_split(fp w, int m, int kb, uint4* hi, uint4* lo){
    float vh[8], vl[8];
    #pragma unroll
    for(int j=0;j<8;++j){
        float v = (m < TT && (kb+j) < TT) ? w[m*TT + kb + j] : 0.f;
        __hip_bfloat16 hb = __float2bfloat16(v);
        float hf = __bfloat162float(hb);
        vh[j] = hf;
        vl[j] = v - hf;
    }
    *hi = make_uint4(pk2(vh[0],vh[1]),pk2(vh[2],vh[3]),pk2(vh[4],vh[5]),pk2(vh[6],vh[7]));
    *lo = make_uint4(pk2(vl[0],vl[1]),pk2(vl[2],vl[3]),pk2(vl[4],vl[5]),pk2(vl[6],vl[7]));
}

// ---- one-time weight fragment prep: wf[L*512 + g*128 + P*64 + lane] ----
// g: 0=(ws,mA) 1=(ws,mB) 2=(wn,mA) 3=(wn,mB); P: 0=hi 1=lo
__global__ __launch_bounds__(256) void k_wprep(fp s0ws, fp s0wn, fp s1ws, fp s1wn, uint4* wf){
    int t = threadIdx.x;
    int lane = t & 63, g = t >> 6;
    int M = g >> 1, H = g & 1;
    int m  = H*16 + (lane&15);
    int kb = (lane>>4)*8;
    for(int L=0; L<2; ++L){
        fp w = L ? (M ? s1wn : s1ws) : (M ? s0wn : s0ws);
        uint4 hi, lo;
        ldw_split(w, m, kb, &hi, &lo);
        wf[L*512 + g*128 +      lane] = hi;
        wf[L*512 + g*128 + 64 + lane] = lo;
    }
}

// ---- conv1 (1x1) + temporal conv (1x3) + LN stats; block=(b, 4-n tile) ----
// b128 LDS: x rows stride 28 (7x float4), nl-stride 904; weights packed float4.
__global__ __launch_bounds__(256) void k_conv(fp x, fp w1, fp b1, fp wt, fp bt,
        float* xin, float* x1p, float* stats){
    __shared__ float xs[4*904];          // 14.5 KB: [nl][c*28 + t+1]
    __shared__ float wq[CO*33*4];        // 33.8 KB: float4 per (o,c)
    __shared__ float red[256];
    int bid = blockIdx.x; int b = bid>>7; int n0 = (bid&127)*4;
    int tid = threadIdx.x;
    for(int j=tid;j<CIN*4*TT;j+=256){
        int c = j/96; int r = j%96; int nl = r/24; int t = r%24;
        xs[nl*904 + c*28 + t+1] = x[((b*CIN+c)*NN + n0+nl)*TT + t];
    }
    for(int j=tid;j<CIN*4;j+=256){ int c=j>>2; int nl=j&3;
        xs[nl*904+c*28]=0.f; xs[nl*904+c*28+25]=0.f;
        xs[nl*904+c*28+26]=0.f; xs[nl*904+c*28+27]=0.f; }
    for(int j=tid;j<CO*CIN;j+=256){
        int o=j>>5, c=j&31;
        *(float4*)&wq[(o*33+c)*4] = make_float4(w1[j], wt[j*3], wt[j*3+1], wt[j*3+2]);
    }
    __syncthreads();
    int o = tid>>2, nl = tid&3;
    float a0[TT], a1[TT];
    float bb1=b1[o], bbt=bt[o];
    #pragma unroll
    for(int t=0;t<TT;++t){ a0[t]=bb1; a1[t]=bbt; }
    const float* xrow = &xs[nl*904];
    for(int c=0;c<CIN;++c){
        const float4 wv = *(const float4*)&wq[(o*33+c)*4];
        float xr[28];
        const float4* xp = (const float4*)&xrow[c*28];
        #pragma unroll
        for(int t=0;t<7;++t){
            float4 v = xp[t];
            xr[4*t]=v.x; xr[4*t+1]=v.y; xr[4*t+2]=v.z; xr[4*t+3]=v.w;
        }
        #pragma unroll
        for(int t=0;t<TT;++t){
            a0[t] += xr[t+1]*wv.x;
            a1[t] += xr[t]*wv.y + xr[t+1]*wv.z + xr[t+2]*wv.w;
        }
    }
    size_t base = (size_t)(b*CO+o)*NT + (size_t)(n0+nl)*TT;
    #pragma unroll
    for(int k=0;k<6;++k){
        *(float4*)(xin + base + 4*k) = make_float4(a0[4*k],a0[4*k+1],a0[4*k+2],a0[4*k+3]);
        *(float4*)(x1p + base + 4*k) = make_float4(a1[4*k],a1[4*k+1],a1[4*k+2],a1[4*k+3]);
    }
    float ls=0.f, lsq=0.f;
    #pragma unroll
    for(int t=0;t<TT;++t){ ls+=a1[t]; lsq+=a1[t]*a1[t]; }
    red[tid]=ls; __syncthreads();
    for(int s=128;s>0;s>>=1){ if(tid<s) red[tid]+=red[tid+s]; __syncthreads(); }
    float tsum = red[0]; __syncthreads();
    red[tid]=lsq; __syncthreads();
    for(int s=128;s>0;s>>=1){ if(tid<s) red[tid]+=red[tid+s]; __syncthreads(); }
    if(tid==0){ atomicAdd(&stats[b], tsum); atomicAdd(&stats[8+b], red[0]); }
}

// ---------------- finalize per-batch LN stats ----------------
__global__ void k_stat(float* stats, int off){
    int b = threadIdx.x;
    if(b < 8){
        float m = stats[off+b] / (float)LNCNT;
        float v = stats[off+8+b] / (float)LNCNT - m*m;
        v = fmaxf(v, 0.f);
        stats[off+16+b] = m;
        stats[off+24+b] = rsqrtf(v + EPSL);
    }
}

// ---- LN+leaky (fused) then h = stack(4*x1, adj^T x1); h stored packed bf16 ----
__global__ __launch_bounds__(256) void k_hbuild(fp x1p, fp lng, fp lnb,
        const float* stats, const int* cnt, const int* idx, const float* val, unsigned* h){
    __shared__ float xs[NN*HSS];          // 57.3 KB
    int blk = blockIdx.x; int b = blk >> 6; int c = blk & 63;
    int tid = threadIdx.x;
    float m = stats[16+b], inv = stats[24+b];
    fp src = x1p + (size_t)(b*CO + c)*NT;
    for(int i=tid;i<NT;i+=256){
        int n = i/TT, t = i%TT;
        xs[n*HSS + t] = lk((src[i] - m)*inv*lng[c*NT + i] + lnb[c*NT + i]);
    }
    __syncthreads();
    unsigned* h0 = h + (size_t)((b*CO+c)*2 + 0)*(NT/2);
    unsigned* h1 = h0 + NT/2;
    #pragma unroll
    for(int half=0; half<2; ++half){
        int n = tid + half*256;
        float t1[TT], acc[TT];
        const float4* sp = (const float4*)&xs[n*HSS];
        #pragma unroll
        for(int k=0;k<6;++k){
            float4 v = sp[k];
            t1[4*k]=v.x; t1[4*k+1]=v.y; t1[4*k+2]=v.z; t1[4*k+3]=v.w;
        }
        #pragma unroll
        for(int l=0;l<TT;++l) acc[l]=0.f;
        int cq = cnt[n];
        for(int j=0;j<cq;++j){
            int u = idx[n*MAXNZ+j];
            float v = val[n*MAXNZ+j];
            const float4* rp = (const float4*)&xs[u*HSS];
            #pragma unroll
            for(int k=0;k<6;++k){
                float4 w = rp[k];
                acc[4*k]+=v*w.x; acc[4*k+1]+=v*w.y; acc[4*k+2]+=v*w.z; acc[4*k+3]+=v*w.w;
            }
        }
        #pragma unroll
        for(int k=0;k<3;++k){
            *(uint4*)(h0 + n*12 + 4*k) = make_uint4(
                pk2(4.f*t1[8*k],  4.f*t1[8*k+1]), pk2(4.f*t1[8*k+2],4.f*t1[8*k+3]),
                pk2(4.f*t1[8*k+4],4.f*t1[8*k+5]), pk2(4.f*t1[8*k+6],4.f*t1[8*k+7]));
            *(uint4*)(h1 + n*12 + 4*k) = make_uint4(
                pk2(acc[8*k],  acc[8*k+1]), pk2(acc[8*k+2],acc[8*k+3]),
                pk2(acc[8*k+4],acc[8*k+5]), pk2(acc[8*k+6],acc[8*k+7]));
        }
    }
}

// ======================= MFMA-based fused GraphSAGE x2 =======================
// H slab: 512 rows x 12 uints (48B, packed bf16). Raw stride-12 rows put
// b128 accesses at the bank-access floor. K=24..31 zero pad in REGISTERS.
// Weight A-frags precomputed by k_wprep (hi/lo bf16 split; fp32-class error).
// NOTE: launch_bounds min-waves MUST stay <=4 (round-2 spill regression).
typedef __attribute__((ext_vector_type(8))) short bf16x8;
typedef __attribute__((ext_vector_type(4))) float f32x4;

static __device__ __forceinline__ f32x4 MF(uint4 a, uint4 b, f32x4 c){
    union { uint4 u; bf16x8 v; } A, Bv; A.u = a; Bv.u = b;
    return __builtin_amdgcn_mfma_f32_16x16x32_bf16(A.v, Bv.v, c, 0, 0, 0);
}
static __device__ __forceinline__ void acc8(float* t, uint4 q){
    t[0]+=lo2f(q.x); t[1]+=hi2f(q.x); t[2]+=lo2f(q.y); t[3]+=hi2f(q.y);
    t[4]+=lo2f(q.z); t[5]+=hi2f(q.z); t[6]+=lo2f(q.w); t[7]+=hi2f(q.w);
}

#define GBODY(u) { int ro=(u)*12; \
    uint4 q0=*(const uint4*)&hsb[ro]; \
    uint4 q1=*(const uint4*)&hsb[ro+4]; \
    uint4 q2=*(const uint4*)&hsb[ro+8]; \
    acc8(t2,q0); acc8(t2+8,q1); acc8(t2+16,q2); }
#define GSTEP(J,U) if((J)<cq) GBODY(U)

__global__ __launch_bounds__(512, 4) void k_sageF(unsigned* h, const uint4* wf,
        fp s0b, fp s1b, const int* cnt, const int* idx, const float* deginv){
    __shared__ unsigned hsb[NN*12];       // 24 KB
    __shared__ unsigned t2s[NN*12];       // 24 KB
    int tid  = threadIdx.x;
    int lane = tid & 63;
    int wv   = tid >> 6;
    unsigned* base = h + (size_t)blockIdx.x*(NT/2);

    for(int i=tid;i<1536;i+=512) ((uint4*)hsb)[i] = ((const uint4*)base)[i];
    int n  = tid;              // gather: this thread owns node n
    int cq = cnt[n];
    float di = deginv[n];
    int4 i0 = *(const int4*)&idx[n*MAXNZ+0];   // prefetch (entries >= cq unused)
    int4 i1 = *(const int4*)&idx[n*MAXNZ+4];
    int4 i2 = *(const int4*)&idx[n*MAXNZ+8];
    __syncthreads();

    for(int layer=0; layer<2; ++layer){
        const uint4* wl = wf + layer*512;
        uint4 wsHiA = wl[      lane], wsLoA = wl[ 64+lane];
        uint4 wsHiB = wl[128 + lane], wsLoB = wl[192+lane];
        uint4 wnHiA = wl[256 + lane], wnLoA = wl[320+lane];
        uint4 wnHiB = wl[384 + lane], wnLoB = wl[448+lane];
        fp Bp = layer ? s1b : s0b;
        float biA[4], biB[4];
        #pragma unroll
        for(int r=0;r<4;++r){
            biA[r] = Bp[(lane>>4)*4 + r];
            int m2 = 16 + (lane>>4)*4 + r;
            biB[r] = (m2 < TT) ? Bp[m2] : 0.f;
        }

        // ---- phase 1: gather t2 (reads hsb), stage into t2s; load B0 frags ----
        float t2[TT];
        #pragma unroll
        for(int l=0;l<TT;++l) t2[l]=0.f;
        GSTEP(0,i0.x) GSTEP(1,i0.y) GSTEP(2,i0.z) GSTEP(3,i0.w)
        GSTEP(4,i1.x) GSTEP(5,i1.y) GSTEP(6,i1.z) GSTEP(7,i1.w)
        GSTEP(8,i2.x) GSTEP(9,i2.y) GSTEP(10,i2.z) GSTEP(11,i2.w)
        for(int j=12;j<cq;++j){ int u=idx[n*MAXNZ+j]; GBODY(u) }
        #pragma unroll
        for(int l=0;l<TT;++l) t2[l]*=di;
        *(uint4*)&t2s[n*12  ] = make_uint4(
            pk2(t2[0],t2[1]),  pk2(t2[2],t2[3]),  pk2(t2[4],t2[5]),  pk2(t2[6],t2[7]));
        *(uint4*)&t2s[n*12+4] = make_uint4(
            pk2(t2[8],t2[9]),  pk2(t2[10],t2[11]),pk2(t2[12],t2[13]),pk2(t2[14],t2[15]));
        *(uint4*)&t2s[n*12+8] = make_uint4(
            pk2(t2[16],t2[17]),pk2(t2[18],t2[19]),pk2(t2[20],t2[21]),pk2(t2[22],t2[23]));

        uint4 b0[4], b1[4];
        #pragma unroll
        for(int i=0;i<4;++i){ b0[i]=make_uint4(0,0,0,0); b1[i]=make_uint4(0,0,0,0); }
        if(lane < 48){
            #pragma unroll
            for(int i=0;i<4;++i){
                int nn_ = wv*64 + i*16 + (lane&15);
                b0[i] = *(const uint4*)&hsb[nn_*12 + ((lane>>4)<<2)];
            }
        }
        __syncthreads();   // t2s ready; all hsb reads complete

        // ---- phase 2: B1 frags, 32 MFMAs, lane-local pack, write-back ----
        if(lane < 48){
            #pragma unroll
            for(int i=0;i<4;++i){
                int nn_ = wv*64 + i*16 + (lane&15);
                b1[i] = *(const uint4*)&t2s[nn_*12 + ((lane>>4)<<2)];
            }
        }
        #pragma unroll
        for(int i=0;i<4;++i){
            f32x4 Da = {biA[0],biA[1],biA[2],biA[3]};
            f32x4 Db = {biB[0],biB[1],biB[2],biB[3]};
            Da = MF(wsHiA, b0[i], Da);
            Da = MF(wsLoA, b0[i], Da);
            Da = MF(wnHiA, b1[i], Da);
            Da = MF(wnLoA, b1[i], Da);
            Db = MF(wsHiB, b0[i], Db);
            Db = MF(wsLoB, b0[i], Db);
            Db = MF(wnHiB, b1[i], Db);
            Db = MF(wnLoB, b1[i], Db);
            int nn_ = wv*64 + i*16 + (lane&15);
            int o = (lane>>4)*2;           // uints {0,2,4,6}: m = 2o..2o+3
            *(uint2*)&hsb[nn_*12 + o] =
                make_uint2(pk2(Da[0],Da[1]), pk2(Da[2],Da[3]));
            if(lane < 32){                 // m = 16..23 -> uints {8,10}
                *(uint2*)&hsb[nn_*12 + 8 + (lane>>4)*2] =
                    make_uint2(pk2(Db[0],Db[1]), pk2(Db[2],Db[3]));
            }
        }
        __syncthreads();   // D visible; t2s reads done -> next layer safe
    }
    for(int i=tid;i<1536;i+=512) ((uint4*)base)[i] = ((const uint4*)hsb)[i];
}

// ---- f1[b,l,n] = sum_c sg(gate)*lk(filt)*w1[c] ; gate fused, HA bf16 input ----
__global__ __launch_bounds__(256) void k_f1(const unsigned* h, fp w1, float* f1){
    int blk = blockIdx.x; int b = blk/16; int n0 = (blk%16)*32;
    int tid = threadIdx.x;
    float acc[3] = {0.f,0.f,0.f};
    const unsigned* fb = h + (size_t)b*CO*NT + n0*12;   // filt ch 0, row n0
    const unsigned* gb = fb + (size_t)CO*(NT/2);        // gate ch 0, row n0
    for(int c=0;c<CO;++c){
        float w = w1[c];
        const unsigned* fu = fb + (size_t)c*(NT/2);
        const unsigned* gu = gb + (size_t)c*(NT/2);
        #pragma unroll
        for(int r=0;r<3;++r){
            int e = tid + 256*r;
            unsigned f = fu[e>>1], g = gu[e>>1];
            float fv = (e&1) ? hi2f(f) : lo2f(f);
            float gv = (e&1) ? hi2f(g) : lo2f(g);
            acc[r] += sg(gv)*lk(fv)*w;
        }
    }
    #pragma unroll
    for(int r=0;r<3;++r){
        int p = tid + 256*r;
        int nl = p/TT, t = p%TT;
        f1[(b*TT+t)*NN + n0+nl] = acc[r];
    }
}

// ---- f2[b,c,l] = sum_n sg(gate)*lk(filt)*w2[n] ; gate fused ----
__global__ __launch_bounds__(256) void k_f2(const unsigned* h, fp w2, float* f2){
    __shared__ float red[256*TT];
    int blk = blockIdx.x; int b = blk/CO; int c = blk%CO;
    int tid = threadIdx.x;
    float acc[TT];
    #pragma unroll
    for(int l=0;l<TT;++l) acc[l]=0.f;
    const unsigned* fb = h + (size_t)b*CO*NT + (size_t)c*(NT/2);
    const unsigned* gb = fb + (size_t)CO*(NT/2);
    for(int n=tid;n<NN;n+=256){
        float w = w2[n];
        #pragma unroll
        for(int k=0;k<3;++k){
            uint4 f = *(const uint4*)(fb + n*12 + 4*k);
            uint4 g = *(const uint4*)(gb + n*12 + 4*k);
            acc[8*k  ] += sg(lo2f(g.x))*lk(lo2f(f.x))*w;
            acc[8*k+1] += sg(hi2f(g.x))*lk(hi2f(f.x))*w;
            acc[8*k+2] += sg(lo2f(g.y))*lk(lo2f(f.y))*w;
            acc[8*k+3] += sg(hi2f(g.y))*lk(hi2f(f.y))*w;
            acc[8*k+4] += sg(lo2f(g.z))*lk(lo2f(f.z))*w;
            acc[8*k+5] += sg(hi2f(g.z))*lk(hi2f(f.z))*w;
            acc[8*k+6] += sg(lo2f(g.w))*lk(lo2f(f.w))*w;
            acc[8*k+7] += sg(hi2f(g.w))*lk(hi2f(f.w))*w;
        }
    }
    #pragma unroll
    for(int l=0;l<TT;++l) red[tid*TT+l]=acc[l];
    __syncthreads();
    for(int s=128;s>0;s>>=1){
        if(tid<s){
            #pragma unroll
            for(int l=0;l<TT;++l) red[tid*TT+l]+=red[(tid+s)*TT+l];
        }
        __syncthreads();
    }
    if(tid<TT) f2[(b*CO+c)*TT+tid] = red[tid];
}

// ---------------- dilated(2) conv over n on f1 ; split 4x over n ----------------
__global__ __launch_bounds__(256) void k_conv_f1(fp f1, fp wd1, float* f1c){
    __shared__ float fs[TT][130];
    __shared__ float w0[TT*TT], w1a[TT*TT];
    int bid = blockIdx.x; int b = bid>>2; int n0 = (bid&3)*128;
    int tid=threadIdx.x;
    for(int i=tid;i<TT*130;i+=256){
        int l=i/130, col=i%130; int n = n0+col-1;
        fs[l][col] = (n>=0 && n<NN) ? f1[(b*TT+l)*NN+n] : 0.f;
    }
    for(int i=tid;i<TT*TT;i+=256){ w0[i]=wd1[i*2]; w1a[i]=wd1[i*2+1]; }
    __syncthreads();
    for(int j=tid;j<TT*128;j+=256){
        int o=j>>7, nn=j&127;
        float acc=0.f;
        #pragma unroll
        for(int i=0;i<TT;++i) acc += fs[i][nn]*w0[o*TT+i] + fs[i][nn+2]*w1a[o*TT+i];
        f1c[(b*TT+o)*NN+n0+nn]=acc;
    }
}

// ---------------- dilated(2) conv over l on f2 ----------------
__global__ __launch_bounds__(256) void k_conv_f2(fp f2, fp wd2, float* f2c){
    __shared__ float fs[CO][TT+2];
    __shared__ float w0[CO*CO], w1a[CO*CO];
    int b = blockIdx.x; int tid=threadIdx.x;
    for(int i=tid;i<CO*TT;i+=256){ int c=i/TT,l=i%TT; fs[c][l+1]=f2[(b*CO+c)*TT+l]; }
    for(int c=tid;c<CO;c+=256){ fs[c][0]=0.f; fs[c][TT+1]=0.f; }
    for(int i=tid;i<CO*CO;i+=256){ w0[i]=wd2[i*2]; w1a[i]=wd2[i*2+1]; }
    __syncthreads();
    for(int j=tid;j<CO*TT;j+=256){
        int o=j/TT, l=j%TT;
        float acc=0.f;
        for(int i=0;i<CO;++i) acc += fs[i][l]*w0[o*CO+i] + fs[i][l+2]*w1a[o*CO+i];
        f2c[(b*CO+o)*TT+l]=acc;
    }
}

// ---------------- g1[b,l,c] = sum_n f1c[b,l,n]*tW[n,c] ----------------
__global__ __launch_bounds__(256) void k_g1(fp f1c, fp tW, float* g1){
    __shared__ float fs[TT*NN];
    int b=blockIdx.x; int tid=threadIdx.x;
    for(int i=tid;i<TT*NN;i+=256) fs[i]=f1c[b*TT*NN+i];
    __syncthreads();
    int c = tid & 63; int lg = tid >> 6;
    float acc[6]={0.f,0.f,0.f,0.f,0.f,0.f};
    for(int n=0;n<NN;++n){
        float w = tW[n*CO + c];
        #pragma unroll
        for(int r=0;r<6;++r) acc[r] += fs[(lg*6+r)*NN + n]*w;
    }
    #pragma unroll
    for(int r=0;r<6;++r) g1[(b*TT + lg*6+r)*CO + c] = acc[r];
}

// ---------------- logits -> sigmoid -> t_v -> BN -> masked softmax -> T_coef ----------------
__global__ __launch_bounds__(1024) void k_logits(fp g1, fp f2c,
        fp tbias, fp tv, fp bng, fp bnb, float* coefs, float* tco){
    __shared__ float sig[B_*TT*TT];
    __shared__ float lg2[B_*TT*TT];
    __shared__ float muq[TT], scq[TT], shq[TT];
    int tid=threadIdx.x;
    for(int j=tid;j<B_*TT*TT;j+=1024){
        int b=j/(TT*TT); int r=j%(TT*TT); int l=r/TT; int q=r%TT;
        float acc = tbias[l*TT+q];
        fp gg = g1 + (b*TT+l)*CO;
        fp ff = f2c + b*CO*TT + q;
        for(int c=0;c<CO;++c) acc += gg[c]*ff[c*TT];
        sig[j] = sg(acc);
    }
    __syncthreads();
    for(int j=tid;j<B_*TT*TT;j+=1024){
        int b=j/(TT*TT); int r=j%(TT*TT); int l=r/TT; int q=r%TT;
        float acc=0.f;
        for(int k=0;k<TT;++k) acc += tv[l*TT+k]*sig[(b*TT+k)*TT+q];
        lg2[j]=acc;
    }
    __syncthreads();
    if(tid<TT){
        int q=tid;
        float s=0.f;
        for(int b=0;b<B_;++b) for(int l=0;l<TT;++l) s += lg2[(b*TT+l)*TT+q];
        float mu = s/192.f;
        float v=0.f;
        for(int b=0;b<B_;++b) for(int l=0;l<TT;++l){ float d = lg2[(b*TT+l)*TT+q]-mu; v += d*d; }
        v = fmaxf(v/192.f, 0.f);
        muq[q]=mu; scq[q]=rsqrtf(v+EPSL)*bng[q]; shq[q]=bnb[q];
    }
    __syncthreads();
    if(tid<192){
        int b=tid/TT, l=tid%TT;
        int base = (l<12)?0:12;
        float z[12];
        float mx=-1e30f;
        #pragma unroll
        for(int r=0;r<12;++r){
            int q=base+r;
            float zv=(lg2[(b*TT+l)*TT+q]-muq[q])*scq[q]+shq[q];
            z[r]=zv; mx = fmaxf(mx,zv);
        }
        float s=0.f;
        #pragma unroll
        for(int r=0;r<12;++r){ z[r]=expf(z[r]-mx); s+=z[r]; }
        float is=1.f/s;
        for(int q=0;q<TT;++q){
            float cf = (q>=base && q<base+12) ? z[q-base]*is : 0.f;
            coefs[(b*TT+l)*TT+q]=cf;
            tco[(b*TT+q)*TT+l]=cf;
        }
    }
}

// ---- x1new = xg @ coefs^T ; y = leaky(x1new)+x_input ; LN stats ----
// Round 5: occupancy fix. grid=(b,c,half) 1024 blocks, 1 row/thread;
// xi[]/out[] eliminated (q processed in groups of 4, load/store inline);
// launch_bounds(256,4) caps VGPR at 128 (was 256 -> 10% occupancy).
// Per-q FMA order unchanged -> numerics identical (stats atomics already
// order-nondeterministic).
__global__ __launch_bounds__(256, 4) void k_apply(const unsigned* h, fp xin, fp coefs,
        float* y, float* stats){
    __shared__ float cf[TT*TT];
    __shared__ float red[256];
    int blk=blockIdx.x; int b=blk>>7; int c=(blk>>1)&63; int half=blk&1;
    int tid=threadIdx.x;
    for(int i=tid;i<TT*TT;i+=256) cf[i]=coefs[b*TT*TT+i];
    __syncthreads();
    int n = half*256 + tid;
    const unsigned* fb = h + (size_t)b*CO*NT + (size_t)c*(NT/2) + n*12;
    const unsigned* gb = fb + (size_t)CO*(NT/2);
    fp xrow = xin + (size_t)(b*CO+c)*NT + n*TT;
    float* yrow = y + (size_t)(b*CO+c)*NT + n*TT;
    float row[TT];
    #pragma unroll
    for(int k=0;k<3;++k){
        uint4 f = *(const uint4*)(fb + 4*k);
        uint4 g = *(const uint4*)(gb + 4*k);
        row[8*k  ] = sg(lo2f(g.x))*lk(lo2f(f.x));
        row[8*k+1] = sg(hi2f(g.x))*lk(hi2f(f.x));
        row[8*k+2] = sg(lo2f(g.y))*lk(lo2f(f.y));
        row[8*k+3] = sg(hi2f(g.y))*lk(hi2f(f.y));
        row[8*k+4] = sg(lo2f(g.z))*lk(lo2f(f.z));
        row[8*k+5] = sg(hi2f(g.z))*lk(hi2f(f.z));
        row[8*k+6] = sg(lo2f(g.w))*lk(lo2f(f.w));
        row[8*k+7] = sg(hi2f(g.w))*lk(hi2f(f.w));
    }
    float ls=0.f, lsq=0.f;
    #pragma unroll
    for(int k=0;k<6;++k){
        float4 u = *(const float4*)(xrow + 4*k);
        float a0=0.f, a1=0.f, a2=0.f, a3=0.f;
        #pragma unroll
        for(int l=0;l<TT;++l){
            float r = row[l];
            a0 += r*cf[(4*k  )*TT+l];
            a1 += r*cf[(4*k+1)*TT+l];
            a2 += r*cf[(4*k+2)*TT+l];
            a3 += r*cf[(4*k+3)*TT+l];
        }
        float y0 = lk(a0)+u.x, y1 = lk(a1)+u.y, y2 = lk(a2)+u.z, y3 = lk(a3)+u.w;
        *(float4*)(yrow + 4*k) = make_float4(y0,y1,y2,y3);
        ls  += y0+y1+y2+y3;
        lsq += y0*y0+y1*y1+y2*y2+y3*y3;
    }
    red[tid]=ls; __syncthreads();
    for(int s=128;s>0;s>>=1){ if(tid<s) red[tid]+=red[tid+s]; __syncthreads(); }
    float t0=red[0]; __syncthreads();
    red[tid]=lsq; __syncthreads();
    for(int s=128;s>0;s>>=1){ if(tid<s) red[tid]+=red[tid+s]; __syncthreads(); }
    if(tid==0){ atomicAdd(&stats[32+b], t0); atomicAdd(&stats[40+b], red[0]); }
}

// ---------------- final LN apply ----------------
__global__ void k_final(fp y, fp lng, fp lnb, const float* stats, float* out){
    int tot = B_*CO*NT;
    for(int i = blockIdx.x*blockDim.x + threadIdx.x; i<tot; i+=gridDim.x*blockDim.x){
        int b = i/LNCNT; int r = i%LNCNT;
        out[i] = (y[i]-stats[48+b])*stats[56+b]*lng[r]+lnb[r];
    }
}

extern "C" void kernel_launch(void* const* d_in, const int* in_sizes, int n_in,
                              void* d_out, int out_size, void* d_ws, size_t ws_size,
                              hipStream_t stream){
    fp x    = (fp)d_in[0];
    fp adj  = (fp)d_in[1];
    fp w1   = (fp)d_in[2];
    fp b1   = (fp)d_in[3];
    fp wt   = (fp)d_in[4];
    fp bt   = (fp)d_in[5];
    fp lng  = (fp)d_in[6];
    fp lnb  = (fp)d_in[7];
    fp s0ws = (fp)d_in[8];
    fp s0wn = (fp)d_in[9];
    fp s0b  = (fp)d_in[10];
    fp s1ws = (fp)d_in[11];
    fp s1wn = (fp)d_in[12];
    fp s1b  = (fp)d_in[13];
    fp tw1  = (fp)d_in[14];
    fp tw2  = (fp)d_in[15];
    fp twd1 = (fp)d_in[16];
    fp twd2 = (fp)d_in[17];
    fp tW   = (fp)d_in[18];
    fp tbias= (fp)d_in[19];
    fp tv   = (fp)d_in[20];
    fp bng  = (fp)d_in[21];
    fp bnb  = (fp)d_in[22];

    float* W = (float*)d_ws;            // stats [0..63]
    int*   CNTp = (int*)(W+256);        // 512 ints (zeroed each launch)
    float* DEG  = W+768;
    int*   IDXp = (int*)(W+1280);
    float* VALp = W+34048;
    float* F1   = W+66816;
    float* F1C  = W+165120;
    float* F2   = W+263424;
    float* F2C  = W+275712;
    float* G1   = W+288000;
    float* CF   = W+300288;
    float* XIN  = W+304896;
    float* X1   = W+6596352;
    uint4* WFq  = (uint4*)(W+12887808); // weight frags: 1024 uint4 = 16KB (old XG slot)
    unsigned* HA = (unsigned*)(W+19179264);   // packed bf16 h: 6291456 uints
    float* Y    = W+31762176;           // ends 38053632 floats = 152.2 MB

    float* oout   = (float*)d_out;
    float* o_adj  = oout + 6291456;
    float* o_tc   = oout + 6291456 + 262144;

    hipMemsetAsync(W, 0, 768*sizeof(float), stream);   // stats + cnt
    k_csc<<<1024,256,0,stream>>>(adj, CNTp, IDXp, VALp);
    k_deg<<<2,256,0,stream>>>(CNTp, DEG);
    k_wprep<<<1,256,0,stream>>>(s0ws, s0wn, s1ws, s1wn, WFq);
    k_conv<<<1024,256,0,stream>>>(x, w1, b1, wt, bt, XIN, X1, W);
    k_stat<<<1,64,0,stream>>>(W, 0);
    k_hbuild<<<512,256,0,stream>>>(X1, lng, lnb, W, CNTp, IDXp, VALp, HA);
    k_sageF<<<1024,512,0,stream>>>(HA, WFq, s0b, s1b, CNTp, IDXp, DEG);
    k_f1<<<128,256,0,stream>>>(HA, tw1, F1);
    k_f2<<<512,256,0,stream>>>(HA, tw2, F2);
    k_conv_f1<<<32,256,0,stream>>>(F1, twd1, F1C);
    k_conv_f2<<<8,256,0,stream>>>(F2, twd2, F2C);
    k_g1<<<8,256,0,stream>>>(F1C, tW, G1);
    k_logits<<<1,1024,0,stream>>>(G1, F2C, tbias, tv, bng, bnb, CF, o_tc);
    hipMemcpyAsync(o_adj, d_in[1], 262144*sizeof(float), hipMemcpyDeviceToDevice, stream);
    k_apply<<<1024,256,0,stream>>>(HA, XIN, CF, Y, W);
    k_stat<<<1,64,0,stream>>>(W, 32);
    k_final<<<2048,256,0,stream>>>(Y, lng, lnb, W, oout);
}

// Round 6
// 436.567 us; speedup vs baseline: 1.1257x; 1.0447x over previous
//
#include <hip/hip_runtime.h>
#include <hip/hip_bf16.h>
#include <math.h>

#define B_    8
#define CIN   32
#define CO    64
#define NN    512
#define TT    24
#define NT    (NN*TT)        /* 12288 */
#define LNCNT (CO*NT)        /* 786432 */
#define EPSL  1e-5f
#define MAXNZ 64
#define HSS   28             /* fp32 LDS row stride (hbuild) */

typedef const float* fp;
static __device__ __forceinline__ float lk(float x){ return x > 0.f ? x : 0.01f*x; }
static __device__ __forceinline__ float sg(float x){
    if(x >= 0.f){ float e = expf(-x); return 1.f/(1.f+e); }
    float e = expf(x); return e/(1.f+e);
}
// bf16 pair pack/unpack (lo = even element, hi = odd element)
static __device__ __forceinline__ unsigned pk2(float a, float b){
    __hip_bfloat16 x = __float2bfloat16(a), y = __float2bfloat16(b);
    unsigned lo = *(unsigned short*)&x, hi = *(unsigned short*)&y;
    return lo | (hi<<16);
}
static __device__ __forceinline__ float lo2f(unsigned u){ return __uint_as_float(u<<16); }
static __device__ __forceinline__ float hi2f(unsigned u){ return __uint_as_float(u & 0xffff0000u); }

// ---------------- CSC build from adj (2% dense), fully parallel ----------------
__global__ __launch_bounds__(256) void k_csc(fp adj, int* cnt, int* idx, float* val){
    int e = blockIdx.x*blockDim.x + threadIdx.x;   // 0 .. NN*NN-1
    if(e >= NN*NN) return;
    float a = adj[e];
    if(a != 0.f){
        int u = e >> 9, q = e & 511;
        int slot = atomicAdd(&cnt[q], 1);
        if(slot < MAXNZ){ idx[q*MAXNZ+slot] = u; val[q*MAXNZ+slot] = a; }
    }
}
__global__ void k_deg(int* cnt, float* deginv){
    int q = blockIdx.x*blockDim.x + threadIdx.x;
    if(q < NN){
        int c = cnt[q];
        deginv[q] = 1.f / (c < 1 ? 1.f : (float)c);
        if(c > MAXNZ) cnt[q] = MAXNZ;
    }
}

// load 8 weights w[m][kb..kb+7] (T=24 bounds -> 0 pad), split hi/lo bf16 frags
static __device__ __forceinline__ void ldw_split(fp w, int m, int kb, uint4* hi, uint4* lo){
    float vh[8], vl[8];
    #pragma unroll
    for(int j=0;j<8;++j){
        float v = (m < TT && (kb+j) < TT) ? w[m*TT + kb + j] : 0.f;
        __hip_bfloat16 hb = __float2bfloat16(v);
        float hf = __bfloat162float(hb);
        vh[j] = hf;
        vl[j] = v - hf;
    }
    *hi = make_uint4(pk2(vh[0],vh[1]),pk2(vh[2],vh[3]),pk2(vh[4],vh[5]),pk2(vh[6],vh[7]));
    *lo = make_uint4(pk2(vl[0],vl[1]),pk2(vl[2],vl[3]),pk2(vl[4],vl[5]),pk2(vl[6],vl[7]));
}

// ---- one-time weight fragment prep: wf[L*512 + g*128 + P*64 + lane] ----
// g: 0=(ws,mA) 1=(ws,mB) 2=(wn,mA) 3=(wn,mB); P: 0=hi 1=lo
__global__ __launch_bounds__(256) void k_wprep(fp s0ws, fp s0wn, fp s1ws, fp s1wn, uint4* wf){
    int t = threadIdx.x;
    int lane = t & 63, g = t >> 6;
    int M = g >> 1, H = g & 1;
    int m  = H*16 + (lane&15);
    int kb = (lane>>4)*8;
    for(int L=0; L<2; ++L){
        fp w = L ? (M ? s1wn : s1ws) : (M ? s0wn : s0ws);
        uint4 hi, lo;
        ldw_split(w, m, kb, &hi, &lo);
        wf[L*512 + g*128 +      lane] = hi;
        wf[L*512 + g*128 + 64 + lane] = lo;
    }
}

// ---- conv weight frag prep: wcf[ot*512 + g*128 + P*64 + lane] ----
// ot = o-tile 0..3; g: 0=w1, 1..3=wt tap g-1; P: 0=hi 1=lo.
// A-frag layout: lane holds W[ot*16 + (lane&15)][kb..kb+7], kb=(lane>>4)*8.
__global__ __launch_bounds__(256) void k_wcprep(fp w1, fp wt, uint4* wcf){
    int t = threadIdx.x;
    int lane = t & 63, g = t >> 6;
    int kb = (lane>>4)*8;
    for(int ot=0; ot<4; ++ot){
        int m = ot*16 + (lane&15);
        float vh[8], vl[8];
        #pragma unroll
        for(int j=0;j<8;++j){
            int c = kb+j;
            float v = (g==0) ? w1[m*CIN+c] : wt[(m*CIN+c)*3 + (g-1)];
            __hip_bfloat16 hb = __float2bfloat16(v);
            float hf = __bfloat162float(hb);
            vh[j]=hf; vl[j]=v-hf;
        }
        wcf[ot*512 + g*128 +      lane] = make_uint4(
            pk2(vh[0],vh[1]),pk2(vh[2],vh[3]),pk2(vh[4],vh[5]),pk2(vh[6],vh[7]));
        wcf[ot*512 + g*128 + 64 + lane] = make_uint4(
            pk2(vl[0],vl[1]),pk2(vl[2],vl[3]),pk2(vl[4],vl[5]),pk2(vl[6],vl[7]));
    }
}

typedef __attribute__((ext_vector_type(8))) short bf16x8;
typedef __attribute__((ext_vector_type(4))) float f32x4;

static __device__ __forceinline__ f32x4 MF(uint4 a, uint4 b, f32x4 c){
    union { uint4 u; bf16x8 v; } A, Bv; A.u = a; Bv.u = b;
    return __builtin_amdgcn_mfma_f32_16x16x32_bf16(A.v, Bv.v, c, 0, 0, 0);
}

// ======================= MFMA conv1 + temporal conv + LN stats ================
// block = (b, 8 nodes). x staged hi/lo bf16 in LDS rows [node*26 + t+1] (rows
// t=-1,24 zeroed = conv padding), 32 c-pairs/row, row stride 20 uints (16
// consecutive rows -> 8 bank-quads, 2-way free). Wave w owns o-tile w.
// D[o][p] = sum_c W[o][c]*X[p][c] via mfma 16x16x32 (K=32=CIN exactly).
// hi/lo split both sides (drop lo*lo) -> fp32-class error ~2^-17.
#define XST 20
__global__ __launch_bounds__(256, 4) void k_conv(fp x, const uint4* wcf, fp b1, fp bt,
        float* xin, float* x1p, float* stats){
    __shared__ __attribute__((aligned(16))) unsigned xh[208*XST];
    __shared__ __attribute__((aligned(16))) unsigned xl[208*XST];
    __shared__ float red[256];
    int bid = blockIdx.x; int b = bid>>6; int n0 = (bid&63)*8;
    int tid = threadIdx.x; int lane = tid&63; int w = tid>>6;
    // ---- stage: 16 c-pairs x 8 nodes x 24 t = 3072 uints per array ----
    for(int i=tid;i<3072;i+=256){
        int cp = i/192; int r = i-cp*192; int node = r/24; int t = r-node*24;
        const float* xp = x + ((size_t)(b*CIN + 2*cp)*NN + n0+node)*TT + t;
        float a = xp[0], b2 = xp[NT];
        __hip_bfloat16 ab = __float2bfloat16(a), bb = __float2bfloat16(b2);
        float ah = __bfloat162float(ab), bh = __bfloat162float(bb);
        int row = node*26 + t + 1;
        xh[row*XST+cp] = pk2(ah, bh);
        xl[row*XST+cp] = pk2(a-ah, b2-bh);
    }
    {   // zero guard rows (t=-1 and t=24 per node): 8*2*16 = 256 slots
        int node = tid>>5; int which = (tid>>4)&1; int j = tid&15;
        int row = node*26 + which*25;
        xh[row*XST+j]=0; xl[row*XST+j]=0;
    }
    // ---- A-frags (weights) ----
    const uint4* wb = wcf + w*512;
    uint4 h1 = wb[      lane], l1 = wb[ 64+lane];
    uint4 ht0= wb[128 + lane], lt0= wb[192+lane];
    uint4 ht1= wb[256 + lane], lt1= wb[320+lane];
    uint4 ht2= wb[384 + lane], lt2= wb[448+lane];
    int mrow = (lane>>4)*4;
    float bi0[4], bi1[4];
    #pragma unroll
    for(int r2=0;r2<4;++r2){
        int o = w*16 + mrow + r2;
        bi0[r2]=b1[o]; bi1[r2]=bt[o];
    }
    __syncthreads();
    float ls=0.f, lsq=0.f;
    int kb4 = (lane>>4)*4;
    for(int pt=0; pt<12; ++pt){
        int p = pt*16 + (lane&15);
        int node = p/24, t = p-node*24;
        int rc = (node*26 + t + 1)*XST;
        uint4 Bhm = *(const uint4*)&xh[rc - XST + kb4];
        uint4 Blm = *(const uint4*)&xl[rc - XST + kb4];
        uint4 Bhc = *(const uint4*)&xh[rc       + kb4];
        uint4 Blc = *(const uint4*)&xl[rc       + kb4];
        uint4 Bhp = *(const uint4*)&xh[rc + XST + kb4];
        uint4 Blp = *(const uint4*)&xl[rc + XST + kb4];
        f32x4 D0 = {bi0[0],bi0[1],bi0[2],bi0[3]};
        f32x4 D1 = {bi1[0],bi1[1],bi1[2],bi1[3]};
        D0 = MF(h1, Bhc, D0); D0 = MF(l1, Bhc, D0); D0 = MF(h1, Blc, D0);
        D1 = MF(ht0,Bhm, D1); D1 = MF(lt0,Bhm, D1); D1 = MF(ht0,Blm, D1);
        D1 = MF(ht1,Bhc, D1); D1 = MF(lt1,Bhc, D1); D1 = MF(ht1,Blc, D1);
        D1 = MF(ht2,Bhp, D1); D1 = MF(lt2,Bhp, D1); D1 = MF(ht2,Blp, D1);
        size_t gbase = ((size_t)(b*CO + w*16 + mrow)*NN + n0+node)*TT + t;
        #pragma unroll
        for(int r2=0;r2<4;++r2){
            xin[gbase + (size_t)r2*NT] = D0[r2];
            x1p[gbase + (size_t)r2*NT] = D1[r2];
            ls  += D1[r2];
            lsq += D1[r2]*D1[r2];
        }
    }
    red[tid]=ls; __syncthreads();
    for(int s=128;s>0;s>>=1){ if(tid<s) red[tid]+=red[tid+s]; __syncthreads(); }
    float tsum = red[0]; __syncthreads();
    red[tid]=lsq; __syncthreads();
    for(int s=128;s>0;s>>=1){ if(tid<s) red[tid]+=red[tid+s]; __syncthreads(); }
    if(tid==0){ atomicAdd(&stats[b], tsum); atomicAdd(&stats[8+b], red[0]); }
}

// ---------------- finalize per-batch LN stats ----------------
__global__ void k_stat(float* stats, int off){
    int b = threadIdx.x;
    if(b < 8){
        float m = stats[off+b] / (float)LNCNT;
        float v = stats[off+8+b] / (float)LNCNT - m*m;
        v = fmaxf(v, 0.f);
        stats[off+16+b] = m;
        stats[off+24+b] = rsqrtf(v + EPSL);
    }
}

// ---- LN+leaky (fused) then h = stack(4*x1, adj^T x1); h stored packed bf16 ----
__global__ __launch_bounds__(256) void k_hbuild(fp x1p, fp lng, fp lnb,
        const float* stats, const int* cnt, const int* idx, const float* val, unsigned* h){
    __shared__ float xs[NN*HSS];          // 57.3 KB
    int blk = blockIdx.x; int b = blk >> 6; int c = blk & 63;
    int tid = threadIdx.x;
    float m = stats[16+b], inv = stats[24+b];
    fp src = x1p + (size_t)(b*CO + c)*NT;
    for(int i=tid;i<NT;i+=256){
        int n = i/TT, t = i%TT;
        xs[n*HSS + t] = lk((src[i] - m)*inv*lng[c*NT + i] + lnb[c*NT + i]);
    }
    __syncthreads();
    unsigned* h0 = h + (size_t)((b*CO+c)*2 + 0)*(NT/2);
    unsigned* h1 = h0 + NT/2;
    #pragma unroll
    for(int half=0; half<2; ++half){
        int n = tid + half*256;
        float t1[TT], acc[TT];
        const float4* sp = (const float4*)&xs[n*HSS];
        #pragma unroll
        for(int k=0;k<6;++k){
            float4 v = sp[k];
            t1[4*k]=v.x; t1[4*k+1]=v.y; t1[4*k+2]=v.z; t1[4*k+3]=v.w;
        }
        #pragma unroll
        for(int l=0;l<TT;++l) acc[l]=0.f;
        int cq = cnt[n];
        for(int j=0;j<cq;++j){
            int u = idx[n*MAXNZ+j];
            float v = val[n*MAXNZ+j];
            const float4* rp = (const float4*)&xs[u*HSS];
            #pragma unroll
            for(int k=0;k<6;++k){
                float4 w = rp[k];
                acc[4*k]+=v*w.x; acc[4*k+1]+=v*w.y; acc[4*k+2]+=v*w.z; acc[4*k+3]+=v*w.w;
            }
        }
        #pragma unroll
        for(int k=0;k<3;++k){
            *(uint4*)(h0 + n*12 + 4*k) = make_uint4(
                pk2(4.f*t1[8*k],  4.f*t1[8*k+1]), pk2(4.f*t1[8*k+2],4.f*t1[8*k+3]),
                pk2(4.f*t1[8*k+4],4.f*t1[8*k+5]), pk2(4.f*t1[8*k+6],4.f*t1[8*k+7]));
            *(uint4*)(h1 + n*12 + 4*k) = make_uint4(
                pk2(acc[8*k],  acc[8*k+1]), pk2(acc[8*k+2],acc[8*k+3]),
                pk2(acc[8*k+4],acc[8*k+5]), pk2(acc[8*k+6],acc[8*k+7]));
        }
    }
}

// ======================= MFMA-based fused GraphSAGE x2 =======================
// H slab: 512 rows x 12 uints (48B, packed bf16). Raw stride-12 rows put
// b128 accesses at the bank-access floor. K=24..31 zero pad in REGISTERS.
// Weight A-frags precomputed by k_wprep (hi/lo bf16 split; fp32-class error).
// NOTE: launch_bounds min-waves MUST stay <=4 (round-2 spill regression).
static __device__ __forceinline__ void acc8(float* t, uint4 q){
    t[0]+=lo2f(q.x); t[1]+=hi2f(q.x); t[2]+=lo2f(q.y); t[3]+=hi2f(q.y);
    t[4]+=lo2f(q.z); t[5]+=hi2f(q.z); t[6]+=lo2f(q.w); t[7]+=hi2f(q.w);
}

#define GBODY(u) { int ro=(u)*12; \
    uint4 q0=*(const uint4*)&hsb[ro]; \
    uint4 q1=*(const uint4*)&hsb[ro+4]; \
    uint4 q2=*(const uint4*)&hsb[ro+8]; \
    acc8(t2,q0); acc8(t2+8,q1); acc8(t2+16,q2); }
#define GSTEP(J,U) if((J)<cq) GBODY(U)

__global__ __launch_bounds__(512, 4) void k_sageF(unsigned* h, const uint4* wf,
        fp s0b, fp s1b, const int* cnt, const int* idx, const float* deginv){
    __shared__ unsigned hsb[NN*12];       // 24 KB
    __shared__ unsigned t2s[NN*12];       // 24 KB
    int tid  = threadIdx.x;
    int lane = tid & 63;
    int wv   = tid >> 6;
    unsigned* base = h + (size_t)blockIdx.x*(NT/2);

    for(int i=tid;i<1536;i+=512) ((uint4*)hsb)[i] = ((const uint4*)base)[i];
    int n  = tid;              // gather: this thread owns node n
    int cq = cnt[n];
    float di = deginv[n];
    int4 i0 = *(const int4*)&idx[n*MAXNZ+0];   // prefetch (entries >= cq unused)
    int4 i1 = *(const int4*)&idx[n*MAXNZ+4];
    int4 i2 = *(const int4*)&idx[n*MAXNZ+8];
    __syncthreads();

    for(int layer=0; layer<2; ++layer){
        const uint4* wl = wf + layer*512;
        uint4 wsHiA = wl[      lane], wsLoA = wl[ 64+lane];
        uint4 wsHiB = wl[128 + lane], wsLoB = wl[192+lane];
        uint4 wnHiA = wl[256 + lane], wnLoA = wl[320+lane];
        uint4 wnHiB = wl[384 + lane], wnLoB = wl[448+lane];
        fp Bp = layer ? s1b : s0b;
        float biA[4], biB[4];
        #pragma unroll
        for(int r=0;r<4;++r){
            biA[r] = Bp[(lane>>4)*4 + r];
            int m2 = 16 + (lane>>4)*4 + r;
            biB[r] = (m2 < TT) ? Bp[m2] : 0.f;
        }

        // ---- phase 1: gather t2 (reads hsb), stage into t2s; load B0 frags ----
        float t2[TT];
        #pragma unroll
        for(int l=0;l<TT;++l) t2[l]=0.f;
        GSTEP(0,i0.x) GSTEP(1,i0.y) GSTEP(2,i0.z) GSTEP(3,i0.w)
        GSTEP(4,i1.x) GSTEP(5,i1.y) GSTEP(6,i1.z) GSTEP(7,i1.w)
        GSTEP(8,i2.x) GSTEP(9,i2.y) GSTEP(10,i2.z) GSTEP(11,i2.w)
        for(int j=12;j<cq;++j){ int u=idx[n*MAXNZ+j]; GBODY(u) }
        #pragma unroll
        for(int l=0;l<TT;++l) t2[l]*=di;
        *(uint4*)&t2s[n*12  ] = make_uint4(
            pk2(t2[0],t2[1]),  pk2(t2[2],t2[3]),  pk2(t2[4],t2[5]),  pk2(t2[6],t2[7]));
        *(uint4*)&t2s[n*12+4] = make_uint4(
            pk2(t2[8],t2[9]),  pk2(t2[10],t2[11]),pk2(t2[12],t2[13]),pk2(t2[14],t2[15]));
        *(uint4*)&t2s[n*12+8] = make_uint4(
            pk2(t2[16],t2[17]),pk2(t2[18],t2[19]),pk2(t2[20],t2[21]),pk2(t2[22],t2[23]));

        uint4 b0[4], b1[4];
        #pragma unroll
        for(int i=0;i<4;++i){ b0[i]=make_uint4(0,0,0,0); b1[i]=make_uint4(0,0,0,0); }
        if(lane < 48){
            #pragma unroll
            for(int i=0;i<4;++i){
                int nn_ = wv*64 + i*16 + (lane&15);
                b0[i] = *(const uint4*)&hsb[nn_*12 + ((lane>>4)<<2)];
            }
        }
        __syncthreads();   // t2s ready; all hsb reads complete

        // ---- phase 2: B1 frags, 32 MFMAs, lane-local pack, write-back ----
        if(lane < 48){
            #pragma unroll
            for(int i=0;i<4;++i){
                int nn_ = wv*64 + i*16 + (lane&15);
                b1[i] = *(const uint4*)&t2s[nn_*12 + ((lane>>4)<<2)];
            }
        }
        #pragma unroll
        for(int i=0;i<4;++i){
            f32x4 Da = {biA[0],biA[1],biA[2],biA[3]};
            f32x4 Db = {biB[0],biB[1],biB[2],biB[3]};
            Da = MF(wsHiA, b0[i], Da);
            Da = MF(wsLoA, b0[i], Da);
            Da = MF(wnHiA, b1[i], Da);
            Da = MF(wnLoA, b1[i], Da);
            Db = MF(wsHiB, b0[i], Db);
            Db = MF(wsLoB, b0[i], Db);
            Db = MF(wnHiB, b1[i], Db);
            Db = MF(wnLoB, b1[i], Db);
            int nn_ = wv*64 + i*16 + (lane&15);
            int o = (lane>>4)*2;           // uints {0,2,4,6}: m = 2o..2o+3
            *(uint2*)&hsb[nn_*12 + o] =
                make_uint2(pk2(Da[0],Da[1]), pk2(Da[2],Da[3]));
            if(lane < 32){                 // m = 16..23 -> uints {8,10}
                *(uint2*)&hsb[nn_*12 + 8 + (lane>>4)*2] =
                    make_uint2(pk2(Db[0],Db[1]), pk2(Db[2],Db[3]));
            }
        }
        __syncthreads();   // D visible; t2s reads done -> next layer safe
    }
    for(int i=tid;i<1536;i+=512) ((uint4*)base)[i] = ((const uint4*)hsb)[i];
}

// ---- f1[b,l,n] = sum_c sg(gate)*lk(filt)*w1[c] ; gate fused, HA bf16 input ----
__global__ __launch_bounds__(256) void k_f1(const unsigned* h, fp w1, float* f1){
    int blk = blockIdx.x; int b = blk/16; int n0 = (blk%16)*32;
    int tid = threadIdx.x;
    float acc[3] = {0.f,0.f,0.f};
    const unsigned* fb = h + (size_t)b*CO*NT + n0*12;   // filt ch 0, row n0
    const unsigned* gb = fb + (size_t)CO*(NT/2);        // gate ch 0, row n0
    for(int c=0;c<CO;++c){
        float w = w1[c];
        const unsigned* fu = fb + (size_t)c*(NT/2);
        const unsigned* gu = gb + (size_t)c*(NT/2);
        #pragma unroll
        for(int r=0;r<3;++r){
            int e = tid + 256*r;
            unsigned f = fu[e>>1], g = gu[e>>1];
            float fv = (e&1) ? hi2f(f) : lo2f(f);
            float gv = (e&1) ? hi2f(g) : lo2f(g);
            acc[r] += sg(gv)*lk(fv)*w;
        }
    }
    #pragma unroll
    for(int r=0;r<3;++r){
        int p = tid + 256*r;
        int nl = p/TT, t = p%TT;
        f1[(b*TT+t)*NN + n0+nl] = acc[r];
    }
}

// ---- f2[b,c,l] = sum_n sg(gate)*lk(filt)*w2[n] ; gate fused ----
__global__ __launch_bounds__(256) void k_f2(const unsigned* h, fp w2, float* f2){
    __shared__ float red[256*TT];
    int blk = blockIdx.x; int b = blk/CO; int c = blk%CO;
    int tid = threadIdx.x;
    float acc[TT];
    #pragma unroll
    for(int l=0;l<TT;++l) acc[l]=0.f;
    const unsigned* fb = h + (size_t)b*CO*NT + (size_t)c*(NT/2);
    const unsigned* gb = fb + (size_t)CO*(NT/2);
    for(int n=tid;n<NN;n+=256){
        float w = w2[n];
        #pragma unroll
        for(int k=0;k<3;++k){
            uint4 f = *(const uint4*)(fb + n*12 + 4*k);
            uint4 g = *(const uint4*)(gb + n*12 + 4*k);
            acc[8*k  ] += sg(lo2f(g.x))*lk(lo2f(f.x))*w;
            acc[8*k+1] += sg(hi2f(g.x))*lk(hi2f(f.x))*w;
            acc[8*k+2] += sg(lo2f(g.y))*lk(lo2f(f.y))*w;
            acc[8*k+3] += sg(hi2f(g.y))*lk(hi2f(f.y))*w;
            acc[8*k+4] += sg(lo2f(g.z))*lk(lo2f(f.z))*w;
            acc[8*k+5] += sg(hi2f(g.z))*lk(hi2f(f.z))*w;
            acc[8*k+6] += sg(lo2f(g.w))*lk(lo2f(f.w))*w;
            acc[8*k+7] += sg(hi2f(g.w))*lk(hi2f(f.w))*w;
        }
    }
    #pragma unroll
    for(int l=0;l<TT;++l) red[tid*TT+l]=acc[l];
    __syncthreads();
    for(int s=128;s>0;s>>=1){
        if(tid<s){
            #pragma unroll
            for(int l=0;l<TT;++l) red[tid*TT+l]+=red[(tid+s)*TT+l];
        }
        __syncthreads();
    }
    if(tid<TT) f2[(b*CO+c)*TT+tid] = red[tid];
}

// ---------------- dilated(2) conv over n on f1 ; split 4x over n ----------------
__global__ __launch_bounds__(256) void k_conv_f1(fp f1, fp wd1, float* f1c){
    __shared__ float fs[TT][130];
    __shared__ float w0[TT*TT], w1a[TT*TT];
    int bid = blockIdx.x; int b = bid>>2; int n0 = (bid&3)*128;
    int tid=threadIdx.x;
    for(int i=tid;i<TT*130;i+=256){
        int l=i/130, col=i%130; int n = n0+col-1;
        fs[l][col] = (n>=0 && n<NN) ? f1[(b*TT+l)*NN+n] : 0.f;
    }
    for(int i=tid;i<TT*TT;i+=256){ w0[i]=wd1[i*2]; w1a[i]=wd1[i*2+1]; }
    __syncthreads();
    for(int j=tid;j<TT*128;j+=256){
        int o=j>>7, nn=j&127;
        float acc=0.f;
        #pragma unroll
        for(int i=0;i<TT;++i) acc += fs[i][nn]*w0[o*TT+i] + fs[i][nn+2]*w1a[o*TT+i];
        f1c[(b*TT+o)*NN+n0+nn]=acc;
    }
}

// ---------------- dilated(2) conv over l on f2 ----------------
__global__ __launch_bounds__(256) void k_conv_f2(fp f2, fp wd2, float* f2c){
    __shared__ float fs[CO][TT+2];
    __shared__ float w0[CO*CO], w1a[CO*CO];
    int b = blockIdx.x; int tid=threadIdx.x;
    for(int i=tid;i<CO*TT;i+=256){ int c=i/TT,l=i%TT; fs[c][l+1]=f2[(b*CO+c)*TT+l]; }
    for(int c=tid;c<CO;c+=256){ fs[c][0]=0.f; fs[c][TT+1]=0.f; }
    for(int i=tid;i<CO*CO;i+=256){ w0[i]=wd2[i*2]; w1a[i]=wd2[i*2+1]; }
    __syncthreads();
    for(int j=tid;j<CO*TT;j+=256){
        int o=j/TT, l=j%TT;
        float acc=0.f;
        for(int i=0;i<CO;++i) acc += fs[i][l]*w0[o*CO+i] + fs[i][l+2]*w1a[o*CO+i];
        f2c[(b*CO+o)*TT+l]=acc;
    }
}

// ---------------- g1[b,l,c] = sum_n f1c[b,l,n]*tW[n,c] ----------------
__global__ __launch_bounds__(256) void k_g1(fp f1c, fp tW, float* g1){
    __shared__ float fs[TT*NN];
    int b=blockIdx.x; int tid=threadIdx.x;
    for(int i=tid;i<TT*NN;i+=256) fs[i]=f1c[b*TT*NN+i];
    __syncthreads();
    int c = tid & 63; int lg = tid >> 6;
    float acc[6]={0.f,0.f,0.f,0.f,0.f,0.f};
    for(int n=0;n<NN;++n){
        float w = tW[n*CO + c];
        #pragma unroll
        for(int r=0;r<6;++r) acc[r] += fs[(lg*6+r)*NN + n]*w;
    }
    #pragma unroll
    for(int r=0;r<6;++r) g1[(b*TT + lg*6+r)*CO + c] = acc[r];
}

// ---------------- logits -> sigmoid -> t_v -> BN -> masked softmax -> T_coef ----------------
__global__ __launch_bounds__(1024) void k_logits(fp g1, fp f2c,
        fp tbias, fp tv, fp bng, fp bnb, float* coefs, float* tco){
    __shared__ float sig[B_*TT*TT];
    __shared__ float lg2[B_*TT*TT];
    __shared__ float muq[TT], scq[TT], shq[TT];
    int tid=threadIdx.x;
    for(int j=tid;j<B_*TT*TT;j+=1024){
        int b=j/(TT*TT); int r=j%(TT*TT); int l=r/TT; int q=r%TT;
        float acc = tbias[l*TT+q];
        fp gg = g1 + (b*TT+l)*CO;
        fp ff = f2c + b*CO*TT + q;
        for(int c=0;c<CO;++c) acc += gg[c]*ff[c*TT];
        sig[j] = sg(acc);
    }
    __syncthreads();
    for(int j=tid;j<B_*TT*TT;j+=1024){
        int b=j/(TT*TT); int r=j%(TT*TT); int l=r/TT; int q=r%TT;
        float acc=0.f;
        for(int k=0;k<TT;++k) acc += tv[l*TT+k]*sig[(b*TT+k)*TT+q];
        lg2[j]=acc;
    }
    __syncthreads();
    if(tid<TT){
        int q=tid;
        float s=0.f;
        for(int b=0;b<B_;++b) for(int l=0;l<TT;++l) s += lg2[(b*TT+l)*TT+q];
        float mu = s/192.f;
        float v=0.f;
        for(int b=0;b<B_;++b) for(int l=0;l<TT;++l){ float d = lg2[(b*TT+l)*TT+q]-mu; v += d*d; }
        v = fmaxf(v/192.f, 0.f);
        muq[q]=mu; scq[q]=rsqrtf(v+EPSL)*bng[q]; shq[q]=bnb[q];
    }
    __syncthreads();
    if(tid<192){
        int b=tid/TT, l=tid%TT;
        int base = (l<12)?0:12;
        float z[12];
        float mx=-1e30f;
        #pragma unroll
        for(int r=0;r<12;++r){
            int q=base+r;
            float zv=(lg2[(b*TT+l)*TT+q]-muq[q])*scq[q]+shq[q];
            z[r]=zv; mx = fmaxf(mx,zv);
        }
        float s=0.f;
        #pragma unroll
        for(int r=0;r<12;++r){ z[r]=expf(z[r]-mx); s+=z[r]; }
        float is=1.f/s;
        for(int q=0;q<TT;++q){
            float cf = (q>=base && q<base+12) ? z[q-base]*is : 0.f;
            coefs[(b*TT+l)*TT+q]=cf;
            tco[(b*TT+q)*TT+l]=cf;
        }
    }
}

// ---- x1new = xg @ coefs^T ; y = leaky(x1new)+x_input ; LN stats ----
__global__ __launch_bounds__(256, 4) void k_apply(const unsigned* h, fp xin, fp coefs,
        float* y, float* stats){
    __shared__ float cf[TT*TT];
    __shared__ float red[256];
    int blk=blockIdx.x; int b=blk>>7; int c=(blk>>1)&63; int half=blk&1;
    int tid=threadIdx.x;
    for(int i=tid;i<TT*TT;i+=256) cf[i]=coefs[b*TT*TT+i];
    __syncthreads();
    int n = half*256 + tid;
    const unsigned* fb = h + (size_t)b*CO*NT + (size_t)c*(NT/2) + n*12;
    const unsigned* gb = fb + (size_t)CO*(NT/2);
    fp xrow = xin + (size_t)(b*CO+c)*NT + n*TT;
    float* yrow = y + (size_t)(b*CO+c)*NT + n*TT;
    float row[TT];
    #pragma unroll
    for(int k=0;k<3;++k){
        uint4 f = *(const uint4*)(fb + 4*k);
        uint4 g = *(const uint4*)(gb + 4*k);
        row[8*k  ] = sg(lo2f(g.x))*lk(lo2f(f.x));
        row[8*k+1] = sg(hi2f(g.x))*lk(hi2f(f.x));
        row[8*k+2] = sg(lo2f(g.y))*lk(lo2f(f.y));
        row[8*k+3] = sg(hi2f(g.y))*lk(hi2f(f.y));
        row[8*k+4] = sg(lo2f(g.z))*lk(lo2f(f.z));
        row[8*k+5] = sg(hi2f(g.z))*lk(hi2f(f.z));
        row[8*k+6] = sg(lo2f(g.w))*lk(lo2f(f.w));
        row[8*k+7] = sg(hi2f(g.w))*lk(hi2f(f.w));
    }
    float ls=0.f, lsq=0.f;
    #pragma unroll
    for(int k=0;k<6;++k){
        float4 u = *(const float4*)(xrow + 4*k);
        float a0=0.f, a1=0.f, a2=0.f, a3=0.f;
        #pragma unroll
        for(int l=0;l<TT;++l){
            float r = row[l];
            a0 += r*cf[(4*k  )*TT+l];
            a1 += r*cf[(4*k+1)*TT+l];
            a2 += r*cf[(4*k+2)*TT+l];
            a3 += r*cf[(4*k+3)*TT+l];
        }
        float y0 = lk(a0)+u.x, y1 = lk(a1)+u.y, y2 = lk(a2)+u.z, y3 = lk(a3)+u.w;
        *(float4*)(yrow + 4*k) = make_float4(y0,y1,y2,y3);
        ls  += y0+y1+y2+y3;
        lsq += y0*y0+y1*y1+y2*y2+y3*y3;
    }
    red[tid]=ls; __syncthreads();
    for(int s=128;s>0;s>>=1){ if(tid<s) red[tid]+=red[tid+s]; __syncthreads(); }
    float t0=red[0]; __syncthreads();
    red[tid]=lsq; __syncthreads();
    for(int s=128;s>0;s>>=1){ if(tid<s) red[tid]+=red[tid+s]; __syncthreads(); }
    if(tid==0){ atomicAdd(&stats[32+b], t0); atomicAdd(&stats[40+b], red[0]); }
}

// ---------------- final LN apply ----------------
__global__ void k_final(fp y, fp lng, fp lnb, const float* stats, float* out){
    int tot = B_*CO*NT;
    for(int i = blockIdx.x*blockDim.x + threadIdx.x; i<tot; i+=gridDim.x*blockDim.x){
        int b = i/LNCNT; int r = i%LNCNT;
        out[i] = (y[i]-stats[48+b])*stats[56+b]*lng[r]+lnb[r];
    }
}

extern "C" void kernel_launch(void* const* d_in, const int* in_sizes, int n_in,
                              void* d_out, int out_size, void* d_ws, size_t ws_size,
                              hipStream_t stream){
    fp x    = (fp)d_in[0];
    fp adj  = (fp)d_in[1];
    fp w1   = (fp)d_in[2];
    fp b1   = (fp)d_in[3];
    fp wt   = (fp)d_in[4];
    fp bt   = (fp)d_in[5];
    fp lng  = (fp)d_in[6];
    fp lnb  = (fp)d_in[7];
    fp s0ws = (fp)d_in[8];
    fp s0wn = (fp)d_in[9];
    fp s0b  = (fp)d_in[10];
    fp s1ws = (fp)d_in[11];
    fp s1wn = (fp)d_in[12];
    fp s1b  = (fp)d_in[13];
    fp tw1  = (fp)d_in[14];
    fp tw2  = (fp)d_in[15];
    fp twd1 = (fp)d_in[16];
    fp twd2 = (fp)d_in[17];
    fp tW   = (fp)d_in[18];
    fp tbias= (fp)d_in[19];
    fp tv   = (fp)d_in[20];
    fp bng  = (fp)d_in[21];
    fp bnb  = (fp)d_in[22];

    float* W = (float*)d_ws;            // stats [0..63]
    int*   CNTp = (int*)(W+256);        // 512 ints (zeroed each launch)
    float* DEG  = W+768;
    int*   IDXp = (int*)(W+1280);
    float* VALp = W+34048;
    float* F1   = W+66816;
    float* F1C  = W+165120;
    float* F2   = W+263424;
    float* F2C  = W+275712;
    float* G1   = W+288000;
    float* CF   = W+300288;
    float* XIN  = W+304896;
    float* X1   = W+6596352;
    uint4* WFq  = (uint4*)(W+12887808); // sage weight frags: 1024 uint4 = 16KB
    uint4* WCF  = (uint4*)(W+12891904); // conv weight frags: 2048 uint4 = 32KB
    unsigned* HA = (unsigned*)(W+19179264);   // packed bf16 h: 6291456 uints
    float* Y    = W+31762176;           // ends 38053632 floats = 152.2 MB

    float* oout   = (float*)d_out;
    float* o_adj  = oout + 6291456;
    float* o_tc   = oout + 6291456 + 262144;

    hipMemsetAsync(W, 0, 768*sizeof(float), stream);   // stats + cnt
    k_csc<<<1024,256,0,stream>>>(adj, CNTp, IDXp, VALp);
    k_deg<<<2,256,0,stream>>>(CNTp, DEG);
    k_wprep<<<1,256,0,stream>>>(s0ws, s0wn, s1ws, s1wn, WFq);
    k_wcprep<<<1,256,0,stream>>>(w1, wt, WCF);
    k_conv<<<512,256,0,stream>>>(x, WCF, b1, bt, XIN, X1, W);
    k_stat<<<1,64,0,stream>>>(W, 0);
    k_hbuild<<<512,256,0,stream>>>(X1, lng, lnb, W, CNTp, IDXp, VALp, HA);
    k_sageF<<<1024,512,0,stream>>>(HA, WFq, s0b, s1b, CNTp, IDXp, DEG);
    k_f1<<<128,256,0,stream>>>(HA, tw1, F1);
    k_f2<<<512,256,0,stream>>>(HA, tw2, F2);
    k_conv_f1<<<32,256,0,stream>>>(F1, twd1, F1C);
    k_conv_f2<<<8,256,0,stream>>>(F2, twd2, F2C);
    k_g1<<<8,256,0,stream>>>(F1C, tW, G1);
    k_logits<<<1,1024,0,stream>>>(G1, F2C, tbias, tv, bng, bnb, CF, o_tc);
    hipMemcpyAsync(o_adj, d_in[1], 262144*sizeof(float), hipMemcpyDeviceToDevice, stream);
    k_apply<<<1024,256,0,stream>>>(HA, XIN, CF, Y, W);
    k_stat<<<1,64,0,stream>>>(W, 32);
    k_final<<<2048,256,0,stream>>>(Y, lng, lnb, W, oout);
}

// Round 7
// 396.566 us; speedup vs baseline: 1.2393x; 1.1009x over previous
//
#include <hip/hip_runtime.h>
#include <hip/hip_bf16.h>
#include <math.h>

#define B_    8
#define CIN   32
#define CO    64
#define NN    512
#define TT    24
#define NT    (NN*TT)        /* 12288 */
#define LNCNT (CO*NT)        /* 786432 */
#define EPSL  1e-5f
#define MAXNZ 64
#define HSS   28             /* fp32 LDS row stride (hbuild) */

typedef const float* fp;
static __device__ __forceinline__ float lk(float x){ return x > 0.f ? x : 0.01f*x; }
static __device__ __forceinline__ float sg(float x){
    if(x >= 0.f){ float e = expf(-x); return 1.f/(1.f+e); }
    float e = expf(x); return e/(1.f+e);
}
// bf16 pair pack/unpack (lo = even element, hi = odd element)
static __device__ __forceinline__ unsigned pk2(float a, float b){
    __hip_bfloat16 x = __float2bfloat16(a), y = __float2bfloat16(b);
    unsigned lo = *(unsigned short*)&x, hi = *(unsigned short*)&y;
    return lo | (hi<<16);
}
static __device__ __forceinline__ float lo2f(unsigned u){ return __uint_as_float(u<<16); }
static __device__ __forceinline__ float hi2f(unsigned u){ return __uint_as_float(u & 0xffff0000u); }

// ---------------- CSC build from adj (2% dense), fully parallel ----------------
__global__ __launch_bounds__(256) void k_csc(fp adj, int* cnt, int* idx, float* val){
    int e = blockIdx.x*blockDim.x + threadIdx.x;   // 0 .. NN*NN-1
    if(e >= NN*NN) return;
    float a = adj[e];
    if(a != 0.f){
        int u = e >> 9, q = e & 511;
        int slot = atomicAdd(&cnt[q], 1);
        if(slot < MAXNZ){ idx[q*MAXNZ+slot] = u; val[q*MAXNZ+slot] = a; }
    }
}
__global__ void k_deg(int* cnt, float* deginv){
    int q = blockIdx.x*blockDim.x + threadIdx.x;
    if(q < NN){
        int c = cnt[q];
        deginv[q] = 1.f / (c < 1 ? 1.f : (float)c);
        if(c > MAXNZ) cnt[q] = MAXNZ;
    }
}

// load 8 weights w[m][kb..kb+7] (T=24 bounds -> 0 pad), split hi/lo bf16 frags
static __device__ __forceinline__ void ldw_split(fp w, int m, int kb, uint4* hi, uint4* lo){
    float vh[8], vl[8];
    #pragma unroll
    for(int j=0;j<8;++j){
        float v = (m < TT && (kb+j) < TT) ? w[m*TT + kb + j] : 0.f;
        __hip_bfloat16 hb = __float2bfloat16(v);
        float hf = __bfloat162float(hb);
        vh[j] = hf;
        vl[j] = v - hf;
    }
    *hi = make_uint4(pk2(vh[0],vh[1]),pk2(vh[2],vh[3]),pk2(vh[4],vh[5]),pk2(vh[6],vh[7]));
    *lo = make_uint4(pk2(vl[0],vl[1]),pk2(vl[2],vl[3]),pk2(vl[4],vl[5]),pk2(vl[6],vl[7]));
}

// ---- one-time weight fragment prep: wf[L*512 + g*128 + P*64 + lane] ----
// g: 0=(ws,mA) 1=(ws,mB) 2=(wn,mA) 3=(wn,mB); P: 0=hi 1=lo
__global__ __launch_bounds__(256) void k_wprep(fp s0ws, fp s0wn, fp s1ws, fp s1wn, uint4* wf){
    int t = threadIdx.x;
    int lane = t & 63, g = t >> 6;
    int M = g >> 1, H = g & 1;
    int m  = H*16 + (lane&15);
    int kb = (lane>>4)*8;
    for(int L=0; L<2; ++L){
        fp w = L ? (M ? s1wn : s1ws) : (M ? s0wn : s0ws);
        uint4 hi, lo;
        ldw_split(w, m, kb, &hi, &lo);
        wf[L*512 + g*128 +      lane] = hi;
        wf[L*512 + g*128 + 64 + lane] = lo;
    }
}

// ---- conv weight frag prep: wcf[ot*512 + g*128 + P*64 + lane] ----
// ot = o-tile 0..3; g: 0=w1, 1..3=wt tap g-1; P: 0=hi 1=lo.
__global__ __launch_bounds__(256) void k_wcprep(fp w1, fp wt, uint4* wcf){
    int t = threadIdx.x;
    int lane = t & 63, g = t >> 6;
    int kb = (lane>>4)*8;
    for(int ot=0; ot<4; ++ot){
        int m = ot*16 + (lane&15);
        float vh[8], vl[8];
        #pragma unroll
        for(int j=0;j<8;++j){
            int c = kb+j;
            float v = (g==0) ? w1[m*CIN+c] : wt[(m*CIN+c)*3 + (g-1)];
            __hip_bfloat16 hb = __float2bfloat16(v);
            float hf = __bfloat162float(hb);
            vh[j]=hf; vl[j]=v-hf;
        }
        wcf[ot*512 + g*128 +      lane] = make_uint4(
            pk2(vh[0],vh[1]),pk2(vh[2],vh[3]),pk2(vh[4],vh[5]),pk2(vh[6],vh[7]));
        wcf[ot*512 + g*128 + 64 + lane] = make_uint4(
            pk2(vl[0],vl[1]),pk2(vl[2],vl[3]),pk2(vl[4],vl[5]),pk2(vl[6],vl[7]));
    }
}

typedef __attribute__((ext_vector_type(8))) short bf16x8;
typedef __attribute__((ext_vector_type(4))) float f32x4;

static __device__ __forceinline__ f32x4 MF(uint4 a, uint4 b, f32x4 c){
    union { uint4 u; bf16x8 v; } A, Bv; A.u = a; Bv.u = b;
    return __builtin_amdgcn_mfma_f32_16x16x32_bf16(A.v, Bv.v, c, 0, 0, 0);
}

// ======================= MFMA conv1 + temporal conv + LN stats ================
#define XST 20
__global__ __launch_bounds__(256, 4) void k_conv(fp x, const uint4* wcf, fp b1, fp bt,
        float* xin, float* x1p, float* stats){
    __shared__ __attribute__((aligned(16))) unsigned xh[208*XST];
    __shared__ __attribute__((aligned(16))) unsigned xl[208*XST];
    __shared__ float red[256];
    int bid = blockIdx.x; int b = bid>>6; int n0 = (bid&63)*8;
    int tid = threadIdx.x; int lane = tid&63; int w = tid>>6;
    for(int i=tid;i<3072;i+=256){
        int cp = i/192; int r = i-cp*192; int node = r/24; int t = r-node*24;
        const float* xp = x + ((size_t)(b*CIN + 2*cp)*NN + n0+node)*TT + t;
        float a = xp[0], b2 = xp[NT];
        __hip_bfloat16 ab = __float2bfloat16(a), bb = __float2bfloat16(b2);
        float ah = __bfloat162float(ab), bh = __bfloat162float(bb);
        int row = node*26 + t + 1;
        xh[row*XST+cp] = pk2(ah, bh);
        xl[row*XST+cp] = pk2(a-ah, b2-bh);
    }
    {   // zero guard rows (t=-1 and t=24 per node): 8*2*16 = 256 slots
        int node = tid>>5; int which = (tid>>4)&1; int j = tid&15;
        int row = node*26 + which*25;
        xh[row*XST+j]=0; xl[row*XST+j]=0;
    }
    const uint4* wb = wcf + w*512;
    uint4 h1 = wb[      lane], l1 = wb[ 64+lane];
    uint4 ht0= wb[128 + lane], lt0= wb[192+lane];
    uint4 ht1= wb[256 + lane], lt1= wb[320+lane];
    uint4 ht2= wb[384 + lane], lt2= wb[448+lane];
    int mrow = (lane>>4)*4;
    float bi0[4], bi1[4];
    #pragma unroll
    for(int r2=0;r2<4;++r2){
        int o = w*16 + mrow + r2;
        bi0[r2]=b1[o]; bi1[r2]=bt[o];
    }
    __syncthreads();
    float ls=0.f, lsq=0.f;
    int kb4 = (lane>>4)*4;
    for(int pt=0; pt<12; ++pt){
        int p = pt*16 + (lane&15);
        int node = p/24, t = p-node*24;
        int rc = (node*26 + t + 1)*XST;
        uint4 Bhm = *(const uint4*)&xh[rc - XST + kb4];
        uint4 Blm = *(const uint4*)&xl[rc - XST + kb4];
        uint4 Bhc = *(const uint4*)&xh[rc       + kb4];
        uint4 Blc = *(const uint4*)&xl[rc       + kb4];
        uint4 Bhp = *(const uint4*)&xh[rc + XST + kb4];
        uint4 Blp = *(const uint4*)&xl[rc + XST + kb4];
        f32x4 D0 = {bi0[0],bi0[1],bi0[2],bi0[3]};
        f32x4 D1 = {bi1[0],bi1[1],bi1[2],bi1[3]};
        D0 = MF(h1, Bhc, D0); D0 = MF(l1, Bhc, D0); D0 = MF(h1, Blc, D0);
        D1 = MF(ht0,Bhm, D1); D1 = MF(lt0,Bhm, D1); D1 = MF(ht0,Blm, D1);
        D1 = MF(ht1,Bhc, D1); D1 = MF(lt1,Bhc, D1); D1 = MF(ht1,Blc, D1);
        D1 = MF(ht2,Bhp, D1); D1 = MF(lt2,Bhp, D1); D1 = MF(ht2,Blp, D1);
        size_t gbase = ((size_t)(b*CO + w*16 + mrow)*NN + n0+node)*TT + t;
        #pragma unroll
        for(int r2=0;r2<4;++r2){
            xin[gbase + (size_t)r2*NT] = D0[r2];
            x1p[gbase + (size_t)r2*NT] = D1[r2];
            ls  += D1[r2];
            lsq += D1[r2]*D1[r2];
        }
    }
    red[tid]=ls; __syncthreads();
    for(int s=128;s>0;s>>=1){ if(tid<s) red[tid]+=red[tid+s]; __syncthreads(); }
    float tsum = red[0]; __syncthreads();
    red[tid]=lsq; __syncthreads();
    for(int s=128;s>0;s>>=1){ if(tid<s) red[tid]+=red[tid+s]; __syncthreads(); }
    if(tid==0){ atomicAdd(&stats[b], tsum); atomicAdd(&stats[8+b], red[0]); }
}

// ---------------- finalize per-batch LN stats ----------------
__global__ void k_stat(float* stats, int off){
    int b = threadIdx.x;
    if(b < 8){
        float m = stats[off+b] / (float)LNCNT;
        float v = stats[off+8+b] / (float)LNCNT - m*m;
        v = fmaxf(v, 0.f);
        stats[off+16+b] = m;
        stats[off+24+b] = rsqrtf(v + EPSL);
    }
}

// ---- LN+leaky (fused) then h = stack(4*x1, adj^T x1); h stored packed bf16 ----
__global__ __launch_bounds__(256) void k_hbuild(fp x1p, fp lng, fp lnb,
        const float* stats, const int* cnt, const int* idx, const float* val, unsigned* h){
    __shared__ float xs[NN*HSS];          // 57.3 KB
    int blk = blockIdx.x; int b = blk >> 6; int c = blk & 63;
    int tid = threadIdx.x;
    float m = stats[16+b], inv = stats[24+b];
    fp src = x1p + (size_t)(b*CO + c)*NT;
    for(int i=tid;i<NT;i+=256){
        int n = i/TT, t = i%TT;
        xs[n*HSS + t] = lk((src[i] - m)*inv*lng[c*NT + i] + lnb[c*NT + i]);
    }
    __syncthreads();
    unsigned* h0 = h + (size_t)((b*CO+c)*2 + 0)*(NT/2);
    unsigned* h1 = h0 + NT/2;
    #pragma unroll
    for(int half=0; half<2; ++half){
        int n = tid + half*256;
        float t1[TT], acc[TT];
        const float4* sp = (const float4*)&xs[n*HSS];
        #pragma unroll
        for(int k=0;k<6;++k){
            float4 v = sp[k];
            t1[4*k]=v.x; t1[4*k+1]=v.y; t1[4*k+2]=v.z; t1[4*k+3]=v.w;
        }
        #pragma unroll
        for(int l=0;l<TT;++l) acc[l]=0.f;
        int cq = cnt[n];
        for(int j=0;j<cq;++j){
            int u = idx[n*MAXNZ+j];
            float v = val[n*MAXNZ+j];
            const float4* rp = (const float4*)&xs[u*HSS];
            #pragma unroll
            for(int k=0;k<6;++k){
                float4 w = rp[k];
                acc[4*k]+=v*w.x; acc[4*k+1]+=v*w.y; acc[4*k+2]+=v*w.z; acc[4*k+3]+=v*w.w;
            }
        }
        #pragma unroll
        for(int k=0;k<3;++k){
            *(uint4*)(h0 + n*12 + 4*k) = make_uint4(
                pk2(4.f*t1[8*k],  4.f*t1[8*k+1]), pk2(4.f*t1[8*k+2],4.f*t1[8*k+3]),
                pk2(4.f*t1[8*k+4],4.f*t1[8*k+5]), pk2(4.f*t1[8*k+6],4.f*t1[8*k+7]));
            *(uint4*)(h1 + n*12 + 4*k) = make_uint4(
                pk2(acc[8*k],  acc[8*k+1]), pk2(acc[8*k+2],acc[8*k+3]),
                pk2(acc[8*k+4],acc[8*k+5]), pk2(acc[8*k+6],acc[8*k+7]));
        }
    }
}

// ======================= MFMA-based fused GraphSAGE x2 =======================
// Round 7: t2s buffer ELIMINATED. After the post-gather barrier every LDS
// access is wave-private (t2-pack write: thread n -> row n; B1 reads and D
// writes: wave wv touches only rows wv*64..wv*64+63). So t2 is written into
// hsb itself (input slab is dead once gather+B0 complete). LDS 48->24 KB ->
// 4 blocks/CU (32 waves, full) and grid 1024 = 256x4 runs in ONE pass
// (was 3/CU -> 768+256 tail). Extra 2 barriers/layer are noise.
// NOTE: launch_bounds min-waves MUST stay <=4 (round-2 spill regression);
// t2 now lives across one barrier -> VGPR ~100-115, still under the 128 cap.
static __device__ __forceinline__ void acc8(float* t, uint4 q){
    t[0]+=lo2f(q.x); t[1]+=hi2f(q.x); t[2]+=lo2f(q.y); t[3]+=hi2f(q.y);
    t[4]+=lo2f(q.z); t[5]+=hi2f(q.z); t[6]+=lo2f(q.w); t[7]+=hi2f(q.w);
}

#define GBODY(u) { int ro=(u)*12; \
    uint4 q0=*(const uint4*)&hsb[ro]; \
    uint4 q1=*(const uint4*)&hsb[ro+4]; \
    uint4 q2=*(const uint4*)&hsb[ro+8]; \
    acc8(t2,q0); acc8(t2+8,q1); acc8(t2+16,q2); }
#define GSTEP(J,U) if((J)<cq) GBODY(U)

__global__ __launch_bounds__(512, 4) void k_sageF(unsigned* h, const uint4* wf,
        fp s0b, fp s1b, const int* cnt, const int* idx, const float* deginv){
    __shared__ unsigned hsb[NN*12];       // 24 KB, the ONLY buffer
    int tid  = threadIdx.x;
    int lane = tid & 63;
    int wv   = tid >> 6;
    unsigned* base = h + (size_t)blockIdx.x*(NT/2);

    for(int i=tid;i<1536;i+=512) ((uint4*)hsb)[i] = ((const uint4*)base)[i];
    int n  = tid;              // gather: this thread owns node n
    int cq = cnt[n];
    float di = deginv[n];
    int4 i0 = *(const int4*)&idx[n*MAXNZ+0];   // prefetch (entries >= cq unused)
    int4 i1 = *(const int4*)&idx[n*MAXNZ+4];
    int4 i2 = *(const int4*)&idx[n*MAXNZ+8];
    __syncthreads();

    for(int layer=0; layer<2; ++layer){
        const uint4* wl = wf + layer*512;
        uint4 wsHiA = wl[      lane], wsLoA = wl[ 64+lane];
        uint4 wsHiB = wl[128 + lane], wsLoB = wl[192+lane];
        uint4 wnHiA = wl[256 + lane], wnLoA = wl[320+lane];
        uint4 wnHiB = wl[384 + lane], wnLoB = wl[448+lane];
        fp Bp = layer ? s1b : s0b;
        float biA[4], biB[4];
        #pragma unroll
        for(int r=0;r<4;++r){
            biA[r] = Bp[(lane>>4)*4 + r];
            int m2 = 16 + (lane>>4)*4 + r;
            biB[r] = (m2 < TT) ? Bp[m2] : 0.f;
        }

        // ---- phase 1: gather t2 (reads hsb); load B0 frags (own rows) ----
        float t2[TT];
        #pragma unroll
        for(int l=0;l<TT;++l) t2[l]=0.f;
        GSTEP(0,i0.x) GSTEP(1,i0.y) GSTEP(2,i0.z) GSTEP(3,i0.w)
        GSTEP(4,i1.x) GSTEP(5,i1.y) GSTEP(6,i1.z) GSTEP(7,i1.w)
        GSTEP(8,i2.x) GSTEP(9,i2.y) GSTEP(10,i2.z) GSTEP(11,i2.w)
        for(int j=12;j<cq;++j){ int u=idx[n*MAXNZ+j]; GBODY(u) }
        #pragma unroll
        for(int l=0;l<TT;++l) t2[l]*=di;

        uint4 b0[4];
        #pragma unroll
        for(int i=0;i<4;++i) b0[i]=make_uint4(0,0,0,0);
        if(lane < 48){
            #pragma unroll
            for(int i=0;i<4;++i){
                int nn_ = wv*64 + i*16 + (lane&15);
                b0[i] = *(const uint4*)&hsb[nn_*12 + ((lane>>4)<<2)];
            }
        }
        __syncthreads();   // ALL hsb reads (gather + B0, all waves) complete

        // ---- t2 pack -> own hsb row (input slab now dead) ----
        *(uint4*)&hsb[n*12  ] = make_uint4(
            pk2(t2[0],t2[1]),  pk2(t2[2],t2[3]),  pk2(t2[4],t2[5]),  pk2(t2[6],t2[7]));
        *(uint4*)&hsb[n*12+4] = make_uint4(
            pk2(t2[8],t2[9]),  pk2(t2[10],t2[11]),pk2(t2[12],t2[13]),pk2(t2[14],t2[15]));
        *(uint4*)&hsb[n*12+8] = make_uint4(
            pk2(t2[16],t2[17]),pk2(t2[18],t2[19]),pk2(t2[20],t2[21]),pk2(t2[22],t2[23]));
        __syncthreads();   // t2 rows visible

        // ---- phase 2: B1 frags (own rows), 32 MFMAs, D -> own rows ----
        uint4 b1[4];
        #pragma unroll
        for(int i=0;i<4;++i) b1[i]=make_uint4(0,0,0,0);
        if(lane < 48){
            #pragma unroll
            for(int i=0;i<4;++i){
                int nn_ = wv*64 + i*16 + (lane&15);
                b1[i] = *(const uint4*)&hsb[nn_*12 + ((lane>>4)<<2)];
            }
        }
        f32x4 Da[4], Db[4];
        #pragma unroll
        for(int i=0;i<4;++i){
            Da[i] = (f32x4){biA[0],biA[1],biA[2],biA[3]};
            Db[i] = (f32x4){biB[0],biB[1],biB[2],biB[3]};
            Da[i] = MF(wsHiA, b0[i], Da[i]);
            Da[i] = MF(wsLoA, b0[i], Da[i]);
            Da[i] = MF(wnHiA, b1[i], Da[i]);
            Da[i] = MF(wnLoA, b1[i], Da[i]);
            Db[i] = MF(wsHiB, b0[i], Db[i]);
            Db[i] = MF(wsLoB, b0[i], Db[i]);
            Db[i] = MF(wnHiB, b1[i], Db[i]);
            Db[i] = MF(wnLoB, b1[i], Db[i]);
        }
        __syncthreads();   // all B1 reads done before D overwrites rows
        #pragma unroll
        for(int i=0;i<4;++i){
            int nn_ = wv*64 + i*16 + (lane&15);
            int o = (lane>>4)*2;           // uints {0,2,4,6}: m = 2o..2o+3
            *(uint2*)&hsb[nn_*12 + o] =
                make_uint2(pk2(Da[i][0],Da[i][1]), pk2(Da[i][2],Da[i][3]));
            if(lane < 32){                 // m = 16..23 -> uints {8,10}
                *(uint2*)&hsb[nn_*12 + 8 + (lane>>4)*2] =
                    make_uint2(pk2(Db[i][0],Db[i][1]), pk2(Db[i][2],Db[i][3]));
            }
        }
        __syncthreads();   // D visible for next layer's gather / writeback
    }
    for(int i=tid;i<1536;i+=512) ((uint4*)base)[i] = ((const uint4*)hsb)[i];
}

// ---- f1[b,l,n] = sum_c sg(gate)*lk(filt)*w1[c] ; gate fused, HA bf16 input ----
// Round 7: grid 512 x 192 thr (was 128 blocks = half-idle GPU). Same math.
__global__ __launch_bounds__(192) void k_f1(const unsigned* h, fp w1, float* f1){
    int blk = blockIdx.x; int b = blk>>6; int n0 = (blk&63)*8;
    int tid = threadIdx.x;
    float acc = 0.f;
    const unsigned* fb = h + (size_t)b*CO*NT + n0*12;   // filt ch 0, row n0
    const unsigned* gb = fb + (size_t)CO*(NT/2);        // gate ch 0, row n0
    int e = tid;                                        // 0..191 = 8 nodes x 24 t
    for(int c=0;c<CO;++c){
        float w = w1[c];
        unsigned f = fb[(size_t)c*(NT/2) + (e>>1)];
        unsigned g = gb[(size_t)c*(NT/2) + (e>>1)];
        float fv = (e&1) ? hi2f(f) : lo2f(f);
        float gv = (e&1) ? hi2f(g) : lo2f(g);
        acc += sg(gv)*lk(fv)*w;
    }
    int nl = e/TT, t = e%TT;
    f1[(b*TT+t)*NN + n0+nl] = acc;
}

// ---- f2[b,c,l] = sum_n sg(gate)*lk(filt)*w2[n] ; gate fused ----
__global__ __launch_bounds__(256) void k_f2(const unsigned* h, fp w2, float* f2){
    __shared__ float red[256*TT];
    int blk = blockIdx.x; int b = blk/CO; int c = blk%CO;
    int tid = threadIdx.x;
    float acc[TT];
    #pragma unroll
    for(int l=0;l<TT;++l) acc[l]=0.f;
    const unsigned* fb = h + (size_t)b*CO*NT + (size_t)c*(NT/2);
    const unsigned* gb = fb + (size_t)CO*(NT/2);
    for(int n=tid;n<NN;n+=256){
        float w = w2[n];
        #pragma unroll
        for(int k=0;k<3;++k){
            uint4 f = *(const uint4*)(fb + n*12 + 4*k);
            uint4 g = *(const uint4*)(gb + n*12 + 4*k);
            acc[8*k  ] += sg(lo2f(g.x))*lk(lo2f(f.x))*w;
            acc[8*k+1] += sg(hi2f(g.x))*lk(hi2f(f.x))*w;
            acc[8*k+2] += sg(lo2f(g.y))*lk(lo2f(f.y))*w;
            acc[8*k+3] += sg(hi2f(g.y))*lk(hi2f(f.y))*w;
            acc[8*k+4] += sg(lo2f(g.z))*lk(lo2f(f.z))*w;
            acc[8*k+5] += sg(hi2f(g.z))*lk(hi2f(f.z))*w;
            acc[8*k+6] += sg(lo2f(g.w))*lk(lo2f(f.w))*w;
            acc[8*k+7] += sg(hi2f(g.w))*lk(hi2f(f.w))*w;
        }
    }
    #pragma unroll
    for(int l=0;l<TT;++l) red[tid*TT+l]=acc[l];
    __syncthreads();
    for(int s=128;s>0;s>>=1){
        if(tid<s){
            #pragma unroll
            for(int l=0;l<TT;++l) red[tid*TT+l]+=red[(tid+s)*TT+l];
        }
        __syncthreads();
    }
    if(tid<TT) f2[(b*CO+c)*TT+tid] = red[tid];
}

// ---------------- dilated(2) conv over n on f1 ; split 4x over n ----------------
__global__ __launch_bounds__(256) void k_conv_f1(fp f1, fp wd1, float* f1c){
    __shared__ float fs[TT][130];
    __shared__ float w0[TT*TT], w1a[TT*TT];
    int bid = blockIdx.x; int b = bid>>2; int n0 = (bid&3)*128;
    int tid=threadIdx.x;
    for(int i=tid;i<TT*130;i+=256){
        int l=i/130, col=i%130; int n = n0+col-1;
        fs[l][col] = (n>=0 && n<NN) ? f1[(b*TT+l)*NN+n] : 0.f;
    }
    for(int i=tid;i<TT*TT;i+=256){ w0[i]=wd1[i*2]; w1a[i]=wd1[i*2+1]; }
    __syncthreads();
    for(int j=tid;j<TT*128;j+=256){
        int o=j>>7, nn=j&127;
        float acc=0.f;
        #pragma unroll
        for(int i=0;i<TT;++i) acc += fs[i][nn]*w0[o*TT+i] + fs[i][nn+2]*w1a[o*TT+i];
        f1c[(b*TT+o)*NN+n0+nn]=acc;
    }
}

// ---------------- dilated(2) conv over l on f2 ----------------
__global__ __launch_bounds__(256) void k_conv_f2(fp f2, fp wd2, float* f2c){
    __shared__ float fs[CO][TT+2];
    __shared__ float w0[CO*CO], w1a[CO*CO];
    int b = blockIdx.x; int tid=threadIdx.x;
    for(int i=tid;i<CO*TT;i+=256){ int c=i/TT,l=i%TT; fs[c][l+1]=f2[(b*CO+c)*TT+l]; }
    for(int c=tid;c<CO;c+=256){ fs[c][0]=0.f; fs[c][TT+1]=0.f; }
    for(int i=tid;i<CO*CO;i+=256){ w0[i]=wd2[i*2]; w1a[i]=wd2[i*2+1]; }
    __syncthreads();
    for(int j=tid;j<CO*TT;j+=256){
        int o=j/TT, l=j%TT;
        float acc=0.f;
        for(int i=0;i<CO;++i) acc += fs[i][l]*w0[o*CO+i] + fs[i][l+2]*w1a[o*CO+i];
        f2c[(b*CO+o)*TT+l]=acc;
    }
}

// ---------------- g1[b,l,c] = sum_n f1c[b,l,n]*tW[n,c] ----------------
// Round 7: grid 32 x 384 thr (was 8 blocks = 3% of GPU), 12KB LDS.
__global__ __launch_bounds__(384) void k_g1(fp f1c, fp tW, float* g1){
    __shared__ float fs[6*NN];
    int blk=blockIdx.x; int b=blk>>2; int part=blk&3;
    int tid=threadIdx.x;
    for(int i=tid;i<6*NN;i+=384) fs[i]=f1c[b*TT*NN + part*6*NN + i];
    __syncthreads();
    int c = tid & 63; int r = tid >> 6;   // r = 0..5
    float acc=0.f;
    for(int n=0;n<NN;++n) acc += fs[r*NN + n]*tW[n*CO + c];
    g1[(b*TT + part*6 + r)*CO + c] = acc;
}

// ---------------- logits -> sigmoid -> t_v -> BN -> masked softmax -> T_coef ----------------
__global__ __launch_bounds__(1024) void k_logits(fp g1, fp f2c,
        fp tbias, fp tv, fp bng, fp bnb, float* coefs, float* tco){
    __shared__ float sig[B_*TT*TT];
    __shared__ float lg2[B_*TT*TT];
    __shared__ float muq[TT], scq[TT], shq[TT];
    int tid=threadIdx.x;
    for(int j=tid;j<B_*TT*TT;j+=1024){
        int b=j/(TT*TT); int r=j%(TT*TT); int l=r/TT; int q=r%TT;
        float acc = tbias[l*TT+q];
        fp gg = g1 + (b*TT+l)*CO;
        fp ff = f2c + b*CO*TT + q;
        for(int c=0;c<CO;++c) acc += gg[c]*ff[c*TT];
        sig[j] = sg(acc);
    }
    __syncthreads();
    for(int j=tid;j<B_*TT*TT;j+=1024){
        int b=j/(TT*TT); int r=j%(TT*TT); int l=r/TT; int q=r%TT;
        float acc=0.f;
        for(int k=0;k<TT;++k) acc += tv[l*TT+k]*sig[(b*TT+k)*TT+q];
        lg2[j]=acc;
    }
    __syncthreads();
    if(tid<TT){
        int q=tid;
        float s=0.f;
        for(int b=0;b<B_;++b) for(int l=0;l<TT;++l) s += lg2[(b*TT+l)*TT+q];
        float mu = s/192.f;
        float v=0.f;
        for(int b=0;b<B_;++b) for(int l=0;l<TT;++l){ float d = lg2[(b*TT+l)*TT+q]-mu; v += d*d; }
        v = fmaxf(v/192.f, 0.f);
        muq[q]=mu; scq[q]=rsqrtf(v+EPSL)*bng[q]; shq[q]=bnb[q];
    }
    __syncthreads();
    if(tid<192){
        int b=tid/TT, l=tid%TT;
        int base = (l<12)?0:12;
        float z[12];
        float mx=-1e30f;
        #pragma unroll
        for(int r=0;r<12;++r){
            int q=base+r;
            float zv=(lg2[(b*TT+l)*TT+q]-muq[q])*scq[q]+shq[q];
            z[r]=zv; mx = fmaxf(mx,zv);
        }
        float s=0.f;
        #pragma unroll
        for(int r=0;r<12;++r){ z[r]=expf(z[r]-mx); s+=z[r]; }
        float is=1.f/s;
        for(int q=0;q<TT;++q){
            float cf = (q>=base && q<base+12) ? z[q-base]*is : 0.f;
            coefs[(b*TT+l)*TT+q]=cf;
            tco[(b*TT+q)*TT+l]=cf;
        }
    }
}

// ---- x1new = xg @ coefs^T ; y = leaky(x1new)+x_input ; LN stats ----
__global__ __launch_bounds__(256, 4) void k_apply(const unsigned* h, fp xin, fp coefs,
        float* y, float* stats){
    __shared__ float cf[TT*TT];
    __shared__ float red[256];
    int blk=blockIdx.x; int b=blk>>7; int c=(blk>>1)&63; int half=blk&1;
    int tid=threadIdx.x;
    for(int i=tid;i<TT*TT;i+=256) cf[i]=coefs[b*TT*TT+i];
    __syncthreads();
    int n = half*256 + tid;
    const unsigned* fb = h + (size_t)b*CO*NT + (size_t)c*(NT/2) + n*12;
    const unsigned* gb = fb + (size_t)CO*(NT/2);
    fp xrow = xin + (size_t)(b*CO+c)*NT + n*TT;
    float* yrow = y + (size_t)(b*CO+c)*NT + n*TT;
    float row[TT];
    #pragma unroll
    for(int k=0;k<3;++k){
        uint4 f = *(const uint4*)(fb + 4*k);
        uint4 g = *(const uint4*)(gb + 4*k);
        row[8*k  ] = sg(lo2f(g.x))*lk(lo2f(f.x));
        row[8*k+1] = sg(hi2f(g.x))*lk(hi2f(f.x));
        row[8*k+2] = sg(lo2f(g.y))*lk(lo2f(f.y));
        row[8*k+3] = sg(hi2f(g.y))*lk(hi2f(f.y));
        row[8*k+4] = sg(lo2f(g.z))*lk(lo2f(f.z));
        row[8*k+5] = sg(hi2f(g.z))*lk(hi2f(f.z));
        row[8*k+6] = sg(lo2f(g.w))*lk(lo2f(f.w));
        row[8*k+7] = sg(hi2f(g.w))*lk(hi2f(f.w));
    }
    float ls=0.f, lsq=0.f;
    #pragma unroll
    for(int k=0;k<6;++k){
        float4 u = *(const float4*)(xrow + 4*k);
        float a0=0.f, a1=0.f, a2=0.f, a3=0.f;
        #pragma unroll
        for(int l=0;l<TT;++l){
            float r = row[l];
            a0 += r*cf[(4*k  )*TT+l];
            a1 += r*cf[(4*k+1)*TT+l];
            a2 += r*cf[(4*k+2)*TT+l];
            a3 += r*cf[(4*k+3)*TT+l];
        }
        float y0 = lk(a0)+u.x, y1 = lk(a1)+u.y, y2 = lk(a2)+u.z, y3 = lk(a3)+u.w;
        *(float4*)(yrow + 4*k) = make_float4(y0,y1,y2,y3);
        ls  += y0+y1+y2+y3;
        lsq += y0*y0+y1*y1+y2*y2+y3*y3;
    }
    red[tid]=ls; __syncthreads();
    for(int s=128;s>0;s>>=1){ if(tid<s) red[tid]+=red[tid+s]; __syncthreads(); }
    float t0=red[0]; __syncthreads();
    red[tid]=lsq; __syncthreads();
    for(int s=128;s>0;s>>=1){ if(tid<s) red[tid]+=red[tid+s]; __syncthreads(); }
    if(tid==0){ atomicAdd(&stats[32+b], t0); atomicAdd(&stats[40+b], red[0]); }
}

// ---------------- final LN apply ----------------
__global__ void k_final(fp y, fp lng, fp lnb, const float* stats, float* out){
    int tot = B_*CO*NT;
    for(int i = blockIdx.x*blockDim.x + threadIdx.x; i<tot; i+=gridDim.x*blockDim.x){
        int b = i/LNCNT; int r = i%LNCNT;
        out[i] = (y[i]-stats[48+b])*stats[56+b]*lng[r]+lnb[r];
    }
}

extern "C" void kernel_launch(void* const* d_in, const int* in_sizes, int n_in,
                              void* d_out, int out_size, void* d_ws, size_t ws_size,
                              hipStream_t stream){
    fp x    = (fp)d_in[0];
    fp adj  = (fp)d_in[1];
    fp w1   = (fp)d_in[2];
    fp b1   = (fp)d_in[3];
    fp wt   = (fp)d_in[4];
    fp bt   = (fp)d_in[5];
    fp lng  = (fp)d_in[6];
    fp lnb  = (fp)d_in[7];
    fp s0ws = (fp)d_in[8];
    fp s0wn = (fp)d_in[9];
    fp s0b  = (fp)d_in[10];
    fp s1ws = (fp)d_in[11];
    fp s1wn = (fp)d_in[12];
    fp s1b  = (fp)d_in[13];
    fp tw1  = (fp)d_in[14];
    fp tw2  = (fp)d_in[15];
    fp twd1 = (fp)d_in[16];
    fp twd2 = (fp)d_in[17];
    fp tW   = (fp)d_in[18];
    fp tbias= (fp)d_in[19];
    fp tv   = (fp)d_in[20];
    fp bng  = (fp)d_in[21];
    fp bnb  = (fp)d_in[22];

    float* W = (float*)d_ws;            // stats [0..63]
    int*   CNTp = (int*)(W+256);        // 512 ints (zeroed each launch)
    float* DEG  = W+768;
    int*   IDXp = (int*)(W+1280);
    float* VALp = W+34048;
    float* F1   = W+66816;
    float* F1C  = W+165120;
    float* F2   = W+263424;
    float* F2C  = W+275712;
    float* G1   = W+288000;
    float* CF   = W+300288;
    float* XIN  = W+304896;
    float* X1   = W+6596352;
    uint4* WFq  = (uint4*)(W+12887808); // sage weight frags: 1024 uint4 = 16KB
    uint4* WCF  = (uint4*)(W+12891904); // conv weight frags: 2048 uint4 = 32KB
    unsigned* HA = (unsigned*)(W+19179264);   // packed bf16 h: 6291456 uints
    float* Y    = W+31762176;           // ends 38053632 floats = 152.2 MB

    float* oout   = (float*)d_out;
    float* o_adj  = oout + 6291456;
    float* o_tc   = oout + 6291456 + 262144;

    hipMemsetAsync(W, 0, 768*sizeof(float), stream);   // stats + cnt
    k_csc<<<1024,256,0,stream>>>(adj, CNTp, IDXp, VALp);
    k_deg<<<2,256,0,stream>>>(CNTp, DEG);
    k_wprep<<<1,256,0,stream>>>(s0ws, s0wn, s1ws, s1wn, WFq);
    k_wcprep<<<1,256,0,stream>>>(w1, wt, WCF);
    k_conv<<<512,256,0,stream>>>(x, WCF, b1, bt, XIN, X1, W);
    k_stat<<<1,64,0,stream>>>(W, 0);
    k_hbuild<<<512,256,0,stream>>>(X1, lng, lnb, W, CNTp, IDXp, VALp, HA);
    k_sageF<<<1024,512,0,stream>>>(HA, WFq, s0b, s1b, CNTp, IDXp, DEG);
    k_f1<<<512,192,0,stream>>>(HA, tw1, F1);
    k_f2<<<512,256,0,stream>>>(HA, tw2, F2);
    k_conv_f1<<<32,256,0,stream>>>(F1, twd1, F1C);
    k_conv_f2<<<8,256,0,stream>>>(F2, twd2, F2C);
    k_g1<<<32,384,0,stream>>>(F1C, tW, G1);
    k_logits<<<1,1024,0,stream>>>(G1, F2C, tbias, tv, bng, bnb, CF, o_tc);
    hipMemcpyAsync(o_adj, d_in[1], 262144*sizeof(float), hipMemcpyDeviceToDevice, stream);
    k_apply<<<1024,256,0,stream>>>(HA, XIN, CF, Y, W);
    k_stat<<<1,64,0,stream>>>(W, 32);
    k_final<<<2048,256,0,stream>>>(Y, lng, lnb, W, oout);
}

// Round 8
// 393.667 us; speedup vs baseline: 1.2484x; 1.0074x over previous
//
#include <hip/hip_runtime.h>
#include <hip/hip_bf16.h>
#include <math.h>

#define B_    8
#define CIN   32
#define CO    64
#define NN    512
#define TT    24
#define NT    (NN*TT)        /* 12288 */
#define LNCNT (CO*NT)        /* 786432 */
#define EPSL  1e-5f
#define MAXNZ 64
#define HSS   28             /* fp32 LDS row stride (hbuild) */

typedef const float* fp;
static __device__ __forceinline__ float lk(float x){ return x > 0.f ? x : 0.01f*x; }
static __device__ __forceinline__ float sg(float x){
    if(x >= 0.f){ float e = expf(-x); return 1.f/(1.f+e); }
    float e = expf(x); return e/(1.f+e);
}
// bf16 pair pack/unpack (lo = even element, hi = odd element)
static __device__ __forceinline__ unsigned pk2(float a, float b){
    __hip_bfloat16 x = __float2bfloat16(a), y = __float2bfloat16(b);
    unsigned lo = *(unsigned short*)&x, hi = *(unsigned short*)&y;
    return lo | (hi<<16);
}
static __device__ __forceinline__ float lo2f(unsigned u){ return __uint_as_float(u<<16); }
static __device__ __forceinline__ float hi2f(unsigned u){ return __uint_as_float(u & 0xffff0000u); }

// ---------------- CSC build from adj (2% dense), fully parallel ----------------
__global__ __launch_bounds__(256) void k_csc(fp adj, int* cnt, int* idx, float* val){
    int e = blockIdx.x*blockDim.x + threadIdx.x;   // 0 .. NN*NN-1
    if(e >= NN*NN) return;
    float a = adj[e];
    if(a != 0.f){
        int u = e >> 9, q = e & 511;
        int slot = atomicAdd(&cnt[q], 1);
        if(slot < MAXNZ){ idx[q*MAXNZ+slot] = u; val[q*MAXNZ+slot] = a; }
    }
}
__global__ void k_deg(int* cnt, float* deginv){
    int q = blockIdx.x*blockDim.x + threadIdx.x;
    if(q < NN){
        int c = cnt[q];
        deginv[q] = 1.f / (c < 1 ? 1.f : (float)c);
        if(c > MAXNZ) cnt[q] = MAXNZ;
    }
}

// load 8 weights w[m][kb..kb+7] (T=24 bounds -> 0 pad), split hi/lo bf16 frags
static __device__ __forceinline__ void ldw_split(fp w, int m, int kb, uint4* hi, uint4* lo){
    float vh[8], vl[8];
    #pragma unroll
    for(int j=0;j<8;++j){
        float v = (m < TT && (kb+j) < TT) ? w[m*TT + kb + j] : 0.f;
        __hip_bfloat16 hb = __float2bfloat16(v);
        float hf = __bfloat162float(hb);
        vh[j] = hf;
        vl[j] = v - hf;
    }
    *hi = make_uint4(pk2(vh[0],vh[1]),pk2(vh[2],vh[3]),pk2(vh[4],vh[5]),pk2(vh[6],vh[7]));
    *lo = make_uint4(pk2(vl[0],vl[1]),pk2(vl[2],vl[3]),pk2(vl[4],vl[5]),pk2(vl[6],vl[7]));
}

// ---- one-time weight fragment prep: wf[L*512 + g*128 + P*64 + lane] ----
// g: 0=(ws,mA) 1=(ws,mB) 2=(wn,mA) 3=(wn,mB); P: 0=hi 1=lo
__global__ __launch_bounds__(256) void k_wprep(fp s0ws, fp s0wn, fp s1ws, fp s1wn, uint4* wf){
    int t = threadIdx.x;
    int lane = t & 63, g = t >> 6;
    int M = g >> 1, H = g & 1;
    int m  = H*16 + (lane&15);
    int kb = (lane>>4)*8;
    for(int L=0; L<2; ++L){
        fp w = L ? (M ? s1wn : s1ws) : (M ? s0wn : s0ws);
        uint4 hi, lo;
        ldw_split(w, m, kb, &hi, &lo);
        wf[L*512 + g*128 +      lane] = hi;
        wf[L*512 + g*128 + 64 + lane] = lo;
    }
}

// ---- conv weight frag prep: wcf[ot*512 + g*128 + P*64 + lane] ----
// ot = o-tile 0..3; g: 0=w1, 1..3=wt tap g-1; P: 0=hi 1=lo.
__global__ __launch_bounds__(256) void k_wcprep(fp w1, fp wt, uint4* wcf){
    int t = threadIdx.x;
    int lane = t & 63, g = t >> 6;
    int kb = (lane>>4)*8;
    for(int ot=0; ot<4; ++ot){
        int m = ot*16 + (lane&15);
        float vh[8], vl[8];
        #pragma unroll
        for(int j=0;j<8;++j){
            int c = kb+j;
            float v = (g==0) ? w1[m*CIN+c] : wt[(m*CIN+c)*3 + (g-1)];
            __hip_bfloat16 hb = __float2bfloat16(v);
            float hf = __bfloat162float(hb);
            vh[j]=hf; vl[j]=v-hf;
        }
        wcf[ot*512 + g*128 +      lane] = make_uint4(
            pk2(vh[0],vh[1]),pk2(vh[2],vh[3]),pk2(vh[4],vh[5]),pk2(vh[6],vh[7]));
        wcf[ot*512 + g*128 + 64 + lane] = make_uint4(
            pk2(vl[0],vl[1]),pk2(vl[2],vl[3]),pk2(vl[4],vl[5]),pk2(vl[6],vl[7]));
    }
}

typedef __attribute__((ext_vector_type(8))) short bf16x8;
typedef __attribute__((ext_vector_type(4))) float f32x4;
typedef __attribute__((ext_vector_type(2))) float f32x2;

static __device__ __forceinline__ f32x4 MF(uint4 a, uint4 b, f32x4 c){
    union { uint4 u; bf16x8 v; } A, Bv; A.u = a; Bv.u = b;
    return __builtin_amdgcn_mfma_f32_16x16x32_bf16(A.v, Bv.v, c, 0, 0, 0);
}

// ======================= MFMA conv1 + temporal conv + LN stats ================
#define XST 20
__global__ __launch_bounds__(256, 4) void k_conv(fp x, const uint4* wcf, fp b1, fp bt,
        float* xin, float* x1p, float* stats){
    __shared__ __attribute__((aligned(16))) unsigned xh[208*XST];
    __shared__ __attribute__((aligned(16))) unsigned xl[208*XST];
    __shared__ float red[256];
    int bid = blockIdx.x; int b = bid>>6; int n0 = (bid&63)*8;
    int tid = threadIdx.x; int lane = tid&63; int w = tid>>6;
    for(int i=tid;i<3072;i+=256){
        int cp = i/192; int r = i-cp*192; int node = r/24; int t = r-node*24;
        const float* xp = x + ((size_t)(b*CIN + 2*cp)*NN + n0+node)*TT + t;
        float a = xp[0], b2 = xp[NT];
        __hip_bfloat16 ab = __float2bfloat16(a), bb = __float2bfloat16(b2);
        float ah = __bfloat162float(ab), bh = __bfloat162float(bb);
        int row = node*26 + t + 1;
        xh[row*XST+cp] = pk2(ah, bh);
        xl[row*XST+cp] = pk2(a-ah, b2-bh);
    }
    {   // zero guard rows (t=-1 and t=24 per node): 8*2*16 = 256 slots
        int node = tid>>5; int which = (tid>>4)&1; int j = tid&15;
        int row = node*26 + which*25;
        xh[row*XST+j]=0; xl[row*XST+j]=0;
    }
    const uint4* wb = wcf + w*512;
    uint4 h1 = wb[      lane], l1 = wb[ 64+lane];
    uint4 ht0= wb[128 + lane], lt0= wb[192+lane];
    uint4 ht1= wb[256 + lane], lt1= wb[320+lane];
    uint4 ht2= wb[384 + lane], lt2= wb[448+lane];
    int mrow = (lane>>4)*4;
    float bi0[4], bi1[4];
    #pragma unroll
    for(int r2=0;r2<4;++r2){
        int o = w*16 + mrow + r2;
        bi0[r2]=b1[o]; bi1[r2]=bt[o];
    }
    __syncthreads();
    float ls=0.f, lsq=0.f;
    int kb4 = (lane>>4)*4;
    for(int pt=0; pt<12; ++pt){
        int p = pt*16 + (lane&15);
        int node = p/24, t = p-node*24;
        int rc = (node*26 + t + 1)*XST;
        uint4 Bhm = *(const uint4*)&xh[rc - XST + kb4];
        uint4 Blm = *(const uint4*)&xl[rc - XST + kb4];
        uint4 Bhc = *(const uint4*)&xh[rc       + kb4];
        uint4 Blc = *(const uint4*)&xl[rc       + kb4];
        uint4 Bhp = *(const uint4*)&xh[rc + XST + kb4];
        uint4 Blp = *(const uint4*)&xl[rc + XST + kb4];
        f32x4 D0 = {bi0[0],bi0[1],bi0[2],bi0[3]};
        f32x4 D1 = {bi1[0],bi1[1],bi1[2],bi1[3]};
        D0 = MF(h1, Bhc, D0); D0 = MF(l1, Bhc, D0); D0 = MF(h1, Blc, D0);
        D1 = MF(ht0,Bhm, D1); D1 = MF(lt0,Bhm, D1); D1 = MF(ht0,Blm, D1);
        D1 = MF(ht1,Bhc, D1); D1 = MF(lt1,Bhc, D1); D1 = MF(ht1,Blc, D1);
        D1 = MF(ht2,Bhp, D1); D1 = MF(lt2,Bhp, D1); D1 = MF(ht2,Blp, D1);
        size_t gbase = ((size_t)(b*CO + w*16 + mrow)*NN + n0+node)*TT + t;
        #pragma unroll
        for(int r2=0;r2<4;++r2){
            xin[gbase + (size_t)r2*NT] = D0[r2];
            x1p[gbase + (size_t)r2*NT] = D1[r2];
            ls  += D1[r2];
            lsq += D1[r2]*D1[r2];
        }
    }
    red[tid]=ls; __syncthreads();
    for(int s=128;s>0;s>>=1){ if(tid<s) red[tid]+=red[tid+s]; __syncthreads(); }
    float tsum = red[0]; __syncthreads();
    red[tid]=lsq; __syncthreads();
    for(int s=128;s>0;s>>=1){ if(tid<s) red[tid]+=red[tid+s]; __syncthreads(); }
    if(tid==0){ atomicAdd(&stats[b], tsum); atomicAdd(&stats[8+b], red[0]); }
}

// ---------------- finalize per-batch LN stats ----------------
__global__ void k_stat(float* stats, int off){
    int b = threadIdx.x;
    if(b < 8){
        float m = stats[off+b] / (float)LNCNT;
        float v = stats[off+8+b] / (float)LNCNT - m*m;
        v = fmaxf(v, 0.f);
        stats[off+16+b] = m;
        stats[off+24+b] = rsqrtf(v + EPSL);
    }
}

// ---- LN+leaky (fused) then h = stack(4*x1, adj^T x1); h stored packed bf16 ----
// Round 8: 512 threads (1 node/thread), float4-vectorized LN staging, idx/val
// prefetch. Same per-element FMA order -> bit-identical output.
__global__ __launch_bounds__(512, 4) void k_hbuild(fp x1p, fp lng, fp lnb,
        const float* stats, const int* cnt, const int* idx, const float* val, unsigned* h){
    __shared__ float xs[NN*HSS];          // 57.3 KB
    int blk = blockIdx.x; int b = blk >> 6; int c = blk & 63;
    int tid = threadIdx.x;
    float m = stats[16+b], inv = stats[24+b];
    fp src  = x1p + (size_t)(b*CO + c)*NT;
    fp gsrc = lng + (size_t)c*NT;
    fp bsrc = lnb + (size_t)c*NT;
    for(int i4=tid;i4<NT/4;i4+=512){
        int i = i4*4;
        int n = i/TT, t = i-n*TT;
        float4 s  = *(const float4*)(src + i);
        float4 g  = *(const float4*)(gsrc + i);
        float4 bb = *(const float4*)(bsrc + i);
        *(float4*)&xs[n*HSS + t] = make_float4(
            lk((s.x-m)*inv*g.x+bb.x), lk((s.y-m)*inv*g.y+bb.y),
            lk((s.z-m)*inv*g.z+bb.z), lk((s.w-m)*inv*g.w+bb.w));
    }
    int n = tid;
    int cq = cnt[n];
    int4 j0 = *(const int4*)&idx[n*MAXNZ+0];   // prefetch (entries >= cq unused)
    int4 j1 = *(const int4*)&idx[n*MAXNZ+4];
    int4 j2 = *(const int4*)&idx[n*MAXNZ+8];
    float4 v0 = *(const float4*)&val[n*MAXNZ+0];
    float4 v1 = *(const float4*)&val[n*MAXNZ+4];
    float4 v2 = *(const float4*)&val[n*MAXNZ+8];
    __syncthreads();
    float acc[TT];
    #pragma unroll
    for(int l=0;l<TT;++l) acc[l]=0.f;
#define HB(J,U,V) if((J)<cq){ const float4* rp=(const float4*)&xs[(U)*HSS]; \
    _Pragma("unroll") for(int k=0;k<6;++k){ float4 wv=rp[k]; \
        acc[4*k]+=(V)*wv.x; acc[4*k+1]+=(V)*wv.y; acc[4*k+2]+=(V)*wv.z; acc[4*k+3]+=(V)*wv.w; } }
    HB(0,j0.x,v0.x) HB(1,j0.y,v0.y) HB(2,j0.z,v0.z) HB(3,j0.w,v0.w)
    HB(4,j1.x,v1.x) HB(5,j1.y,v1.y) HB(6,j1.z,v1.z) HB(7,j1.w,v1.w)
    HB(8,j2.x,v2.x) HB(9,j2.y,v2.y) HB(10,j2.z,v2.z) HB(11,j2.w,v2.w)
    for(int j=12;j<cq;++j){
        int u = idx[n*MAXNZ+j]; float v = val[n*MAXNZ+j];
        const float4* rp = (const float4*)&xs[u*HSS];
        #pragma unroll
        for(int k=0;k<6;++k){ float4 wv=rp[k];
            acc[4*k]+=v*wv.x; acc[4*k+1]+=v*wv.y; acc[4*k+2]+=v*wv.z; acc[4*k+3]+=v*wv.w; }
    }
    float t1[TT];
    const float4* sp = (const float4*)&xs[n*HSS];
    #pragma unroll
    for(int k=0;k<6;++k){
        float4 v = sp[k];
        t1[4*k]=v.x; t1[4*k+1]=v.y; t1[4*k+2]=v.z; t1[4*k+3]=v.w;
    }
    unsigned* h0 = h + (size_t)((b*CO+c)*2)*(NT/2);
    unsigned* h1 = h0 + NT/2;
    #pragma unroll
    for(int k=0;k<3;++k){
        *(uint4*)(h0 + n*12 + 4*k) = make_uint4(
            pk2(4.f*t1[8*k],  4.f*t1[8*k+1]), pk2(4.f*t1[8*k+2],4.f*t1[8*k+3]),
            pk2(4.f*t1[8*k+4],4.f*t1[8*k+5]), pk2(4.f*t1[8*k+6],4.f*t1[8*k+7]));
        *(uint4*)(h1 + n*12 + 4*k) = make_uint4(
            pk2(acc[8*k],  acc[8*k+1]), pk2(acc[8*k+2],acc[8*k+3]),
            pk2(acc[8*k+4],acc[8*k+5]), pk2(acc[8*k+6],acc[8*k+7]));
    }
}

// ======================= MFMA-based fused GraphSAGE x2 =======================
// Round 8: gather accumulates as packed f32x2 (v_pk_add_f32 candidate), and
// D results are PACKED to uint2 BEFORE the barrier (12 live VGPRs instead of
// 32 f32x4 -> kills the scratch spill seen as +18MB WRITE_SIZE in round 7).
// NOTE: launch_bounds min-waves MUST stay <=4 (round-2 spill regression).
static __device__ __forceinline__ void acc8v(f32x2* t, uint4 q){
    t[0] += (f32x2){lo2f(q.x), hi2f(q.x)};
    t[1] += (f32x2){lo2f(q.y), hi2f(q.y)};
    t[2] += (f32x2){lo2f(q.z), hi2f(q.z)};
    t[3] += (f32x2){lo2f(q.w), hi2f(q.w)};
}

#define GBODY(u) { int ro=(u)*12; \
    uint4 q0=*(const uint4*)&hsb[ro]; \
    uint4 q1=*(const uint4*)&hsb[ro+4]; \
    uint4 q2=*(const uint4*)&hsb[ro+8]; \
    acc8v(t2v,q0); acc8v(t2v+4,q1); acc8v(t2v+8,q2); }
#define GSTEP(J,U) if((J)<cq) GBODY(U)

__global__ __launch_bounds__(512, 4) void k_sageF(unsigned* h, const uint4* wf,
        fp s0b, fp s1b, const int* cnt, const int* idx, const float* deginv){
    __shared__ unsigned hsb[NN*12];       // 24 KB, the ONLY buffer
    int tid  = threadIdx.x;
    int lane = tid & 63;
    int wv   = tid >> 6;
    unsigned* base = h + (size_t)blockIdx.x*(NT/2);

    for(int i=tid;i<1536;i+=512) ((uint4*)hsb)[i] = ((const uint4*)base)[i];
    int n  = tid;              // gather: this thread owns node n
    int cq = cnt[n];
    float di = deginv[n];
    int4 i0 = *(const int4*)&idx[n*MAXNZ+0];   // prefetch (entries >= cq unused)
    int4 i1 = *(const int4*)&idx[n*MAXNZ+4];
    int4 i2 = *(const int4*)&idx[n*MAXNZ+8];
    __syncthreads();

    for(int layer=0; layer<2; ++layer){
        const uint4* wl = wf + layer*512;
        uint4 wsHiA = wl[      lane], wsLoA = wl[ 64+lane];
        uint4 wsHiB = wl[128 + lane], wsLoB = wl[192+lane];
        uint4 wnHiA = wl[256 + lane], wnLoA = wl[320+lane];
        uint4 wnHiB = wl[384 + lane], wnLoB = wl[448+lane];
        fp Bp = layer ? s1b : s0b;
        float biA[4], biB[4];
        #pragma unroll
        for(int r=0;r<4;++r){
            biA[r] = Bp[(lane>>4)*4 + r];
            int m2 = 16 + (lane>>4)*4 + r;
            biB[r] = (m2 < TT) ? Bp[m2] : 0.f;
        }

        // ---- phase 1: gather t2 (reads hsb); load B0 frags (own rows) ----
        f32x2 t2v[12];
        #pragma unroll
        for(int l=0;l<12;++l) t2v[l] = (f32x2){0.f,0.f};
        GSTEP(0,i0.x) GSTEP(1,i0.y) GSTEP(2,i0.z) GSTEP(3,i0.w)
        GSTEP(4,i1.x) GSTEP(5,i1.y) GSTEP(6,i1.z) GSTEP(7,i1.w)
        GSTEP(8,i2.x) GSTEP(9,i2.y) GSTEP(10,i2.z) GSTEP(11,i2.w)
        for(int j=12;j<cq;++j){ int u=idx[n*MAXNZ+j]; GBODY(u) }
        #pragma unroll
        for(int l=0;l<12;++l) t2v[l] *= di;

        uint4 b0[4];
        #pragma unroll
        for(int i=0;i<4;++i) b0[i]=make_uint4(0,0,0,0);
        if(lane < 48){
            #pragma unroll
            for(int i=0;i<4;++i){
                int nn_ = wv*64 + i*16 + (lane&15);
                b0[i] = *(const uint4*)&hsb[nn_*12 + ((lane>>4)<<2)];
            }
        }
        __syncthreads();   // ALL hsb reads (gather + B0, all waves) complete

        // ---- t2 pack -> own hsb row (input slab now dead) ----
        *(uint4*)&hsb[n*12  ] = make_uint4(
            pk2(t2v[0].x,t2v[0].y), pk2(t2v[1].x,t2v[1].y),
            pk2(t2v[2].x,t2v[2].y), pk2(t2v[3].x,t2v[3].y));
        *(uint4*)&hsb[n*12+4] = make_uint4(
            pk2(t2v[4].x,t2v[4].y), pk2(t2v[5].x,t2v[5].y),
            pk2(t2v[6].x,t2v[6].y), pk2(t2v[7].x,t2v[7].y));
        *(uint4*)&hsb[n*12+8] = make_uint4(
            pk2(t2v[8].x,t2v[8].y), pk2(t2v[9].x,t2v[9].y),
            pk2(t2v[10].x,t2v[10].y), pk2(t2v[11].x,t2v[11].y));
        __syncthreads();   // t2 rows visible

        // ---- phase 2: B1 frags (own rows), 32 MFMAs, pack, D -> own rows ----
        uint4 b1[4];
        #pragma unroll
        for(int i=0;i<4;++i) b1[i]=make_uint4(0,0,0,0);
        if(lane < 48){
            #pragma unroll
            for(int i=0;i<4;++i){
                int nn_ = wv*64 + i*16 + (lane&15);
                b1[i] = *(const uint4*)&hsb[nn_*12 + ((lane>>4)<<2)];
            }
        }
        uint2 pa[4], pb[4];
        #pragma unroll
        for(int i=0;i<4;++i){
            f32x4 Da = {biA[0],biA[1],biA[2],biA[3]};
            f32x4 Db = {biB[0],biB[1],biB[2],biB[3]};
            Da = MF(wsHiA, b0[i], Da);
            Da = MF(wsLoA, b0[i], Da);
            Da = MF(wnHiA, b1[i], Da);
            Da = MF(wnLoA, b1[i], Da);
            Db = MF(wsHiB, b0[i], Db);
            Db = MF(wsLoB, b0[i], Db);
            Db = MF(wnHiB, b1[i], Db);
            Db = MF(wnLoB, b1[i], Db);
            pa[i] = make_uint2(pk2(Da[0],Da[1]), pk2(Da[2],Da[3]));
            pb[i] = make_uint2(pk2(Db[0],Db[1]), pk2(Db[2],Db[3]));
        }
        __syncthreads();   // all B1 reads done before D overwrites rows
        #pragma unroll
        for(int i=0;i<4;++i){
            int nn_ = wv*64 + i*16 + (lane&15);
            int o = (lane>>4)*2;           // uints {0,2,4,6}: m = 2o..2o+3
            *(uint2*)&hsb[nn_*12 + o] = pa[i];
            if(lane < 32){                 // m = 16..23 -> uints {8,10}
                *(uint2*)&hsb[nn_*12 + 8 + (lane>>4)*2] = pb[i];
            }
        }
        __syncthreads();   // D visible for next layer's gather / writeback
    }
    for(int i=tid;i<1536;i+=512) ((uint4*)base)[i] = ((const uint4*)hsb)[i];
}

// ---- f1[b,l,n] = sum_c sg(gate)*lk(filt)*w1[c] ; gate fused, HA bf16 input ----
__global__ __launch_bounds__(192) void k_f1(const unsigned* h, fp w1, float* f1){
    int blk = blockIdx.x; int b = blk>>6; int n0 = (blk&63)*8;
    int tid = threadIdx.x;
    float acc = 0.f;
    const unsigned* fb = h + (size_t)b*CO*NT + n0*12;   // filt ch 0, row n0
    const unsigned* gb = fb + (size_t)CO*(NT/2);        // gate ch 0, row n0
    int e = tid;                                        // 0..191 = 8 nodes x 24 t
    for(int c=0;c<CO;++c){
        float w = w1[c];
        unsigned f = fb[(size_t)c*(NT/2) + (e>>1)];
        unsigned g = gb[(size_t)c*(NT/2) + (e>>1)];
        float fv = (e&1) ? hi2f(f) : lo2f(f);
        float gv = (e&1) ? hi2f(g) : lo2f(g);
        acc += sg(gv)*lk(fv)*w;
    }
    int nl = e/TT, t = e%TT;
    f1[(b*TT+t)*NN + n0+nl] = acc;
}

// ---- f2[b,c,l] = sum_n sg(gate)*lk(filt)*w2[n] ; gate fused ----
// Round 8: reduce buffer stride 24 -> 25 (stride-24 had bank period 4 =>
// 16-way conflicts on every tree step; 25 is odd => full 32-bank walk).
#define F2S 25
__global__ __launch_bounds__(256) void k_f2(const unsigned* h, fp w2, float* f2){
    __shared__ float red[256*F2S];
    int blk = blockIdx.x; int b = blk/CO; int c = blk%CO;
    int tid = threadIdx.x;
    float acc[TT];
    #pragma unroll
    for(int l=0;l<TT;++l) acc[l]=0.f;
    const unsigned* fb = h + (size_t)b*CO*NT + (size_t)c*(NT/2);
    const unsigned* gb = fb + (size_t)CO*(NT/2);
    for(int n=tid;n<NN;n+=256){
        float w = w2[n];
        #pragma unroll
        for(int k=0;k<3;++k){
            uint4 f = *(const uint4*)(fb + n*12 + 4*k);
            uint4 g = *(const uint4*)(gb + n*12 + 4*k);
            acc[8*k  ] += sg(lo2f(g.x))*lk(lo2f(f.x))*w;
            acc[8*k+1] += sg(hi2f(g.x))*lk(hi2f(f.x))*w;
            acc[8*k+2] += sg(lo2f(g.y))*lk(lo2f(f.y))*w;
            acc[8*k+3] += sg(hi2f(g.y))*lk(hi2f(f.y))*w;
            acc[8*k+4] += sg(lo2f(g.z))*lk(lo2f(f.z))*w;
            acc[8*k+5] += sg(hi2f(g.z))*lk(hi2f(f.z))*w;
            acc[8*k+6] += sg(lo2f(g.w))*lk(lo2f(f.w))*w;
            acc[8*k+7] += sg(hi2f(g.w))*lk(hi2f(f.w))*w;
        }
    }
    #pragma unroll
    for(int l=0;l<TT;++l) red[tid*F2S+l]=acc[l];
    __syncthreads();
    for(int s=128;s>0;s>>=1){
        if(tid<s){
            #pragma unroll
            for(int l=0;l<TT;++l) red[tid*F2S+l]+=red[(tid+s)*F2S+l];
        }
        __syncthreads();
    }
    if(tid<TT) f2[(b*CO+c)*TT+tid] = red[tid];
}

// ---------------- dilated(2) conv over n on f1 ; split 4x over n ----------------
__global__ __launch_bounds__(256) void k_conv_f1(fp f1, fp wd1, float* f1c){
    __shared__ float fs[TT][130];
    __shared__ float w0[TT*TT], w1a[TT*TT];
    int bid = blockIdx.x; int b = bid>>2; int n0 = (bid&3)*128;
    int tid=threadIdx.x;
    for(int i=tid;i<TT*130;i+=256){
        int l=i/130, col=i%130; int n = n0+col-1;
        fs[l][col] = (n>=0 && n<NN) ? f1[(b*TT+l)*NN+n] : 0.f;
    }
    for(int i=tid;i<TT*TT;i+=256){ w0[i]=wd1[i*2]; w1a[i]=wd1[i*2+1]; }
    __syncthreads();
    for(int j=tid;j<TT*128;j+=256){
        int o=j>>7, nn=j&127;
        float acc=0.f;
        #pragma unroll
        for(int i=0;i<TT;++i) acc += fs[i][nn]*w0[o*TT+i] + fs[i][nn+2]*w1a[o*TT+i];
        f1c[(b*TT+o)*NN+n0+nn]=acc;
    }
}

// ---------------- dilated(2) conv over l on f2 ----------------
__global__ __launch_bounds__(256) void k_conv_f2(fp f2, fp wd2, float* f2c){
    __shared__ float fs[CO][TT+2];
    __shared__ float w0[CO*CO], w1a[CO*CO];
    int b = blockIdx.x; int tid=threadIdx.x;
    for(int i=tid;i<CO*TT;i+=256){ int c=i/TT,l=i%TT; fs[c][l+1]=f2[(b*CO+c)*TT+l]; }
    for(int c=tid;c<CO;c+=256){ fs[c][0]=0.f; fs[c][TT+1]=0.f; }
    for(int i=tid;i<CO*CO;i+=256){ w0[i]=wd2[i*2]; w1a[i]=wd2[i*2+1]; }
    __syncthreads();
    for(int j=tid;j<CO*TT;j+=256){
        int o=j/TT, l=j%TT;
        float acc=0.f;
        for(int i=0;i<CO;++i) acc += fs[i][l]*w0[o*CO+i] + fs[i][l+2]*w1a[o*CO+i];
        f2c[(b*CO+o)*TT+l]=acc;
    }
}

// ---------------- g1[b,l,c] = sum_n f1c[b,l,n]*tW[n,c] ----------------
__global__ __launch_bounds__(384) void k_g1(fp f1c, fp tW, float* g1){
    __shared__ float fs[6*NN];
    int blk=blockIdx.x; int b=blk>>2; int part=blk&3;
    int tid=threadIdx.x;
    for(int i=tid;i<6*NN;i+=384) fs[i]=f1c[b*TT*NN + part*6*NN + i];
    __syncthreads();
    int c = tid & 63; int r = tid >> 6;   // r = 0..5
    float acc=0.f;
    for(int n=0;n<NN;++n) acc += fs[r*NN + n]*tW[n*CO + c];
    g1[(b*TT + part*6 + r)*CO + c] = acc;
}

// ---------------- logits -> sigmoid -> t_v -> BN -> masked softmax -> T_coef ----------------
__global__ __launch_bounds__(1024) void k_logits(fp g1, fp f2c,
        fp tbias, fp tv, fp bng, fp bnb, float* coefs, float* tco){
    __shared__ float sig[B_*TT*TT];
    __shared__ float lg2[B_*TT*TT];
    __shared__ float muq[TT], scq[TT], shq[TT];
    int tid=threadIdx.x;
    for(int j=tid;j<B_*TT*TT;j+=1024){
        int b=j/(TT*TT); int r=j%(TT*TT); int l=r/TT; int q=r%TT;
        float acc = tbias[l*TT+q];
        fp gg = g1 + (b*TT+l)*CO;
        fp ff = f2c + b*CO*TT + q;
        for(int c=0;c<CO;++c) acc += gg[c]*ff[c*TT];
        sig[j] = sg(acc);
    }
    __syncthreads();
    for(int j=tid;j<B_*TT*TT;j+=1024){
        int b=j/(TT*TT); int r=j%(TT*TT); int l=r/TT; int q=r%TT;
        float acc=0.f;
        for(int k=0;k<TT;++k) acc += tv[l*TT+k]*sig[(b*TT+k)*TT+q];
        lg2[j]=acc;
    }
    __syncthreads();
    if(tid<TT){
        int q=tid;
        float s=0.f;
        for(int b=0;b<B_;++b) for(int l=0;l<TT;++l) s += lg2[(b*TT+l)*TT+q];
        float mu = s/192.f;
        float v=0.f;
        for(int b=0;b<B_;++b) for(int l=0;l<TT;++l){ float d = lg2[(b*TT+l)*TT+q]-mu; v += d*d; }
        v = fmaxf(v/192.f, 0.f);
        muq[q]=mu; scq[q]=rsqrtf(v+EPSL)*bng[q]; shq[q]=bnb[q];
    }
    __syncthreads();
    if(tid<192){
        int b=tid/TT, l=tid%TT;
        int base = (l<12)?0:12;
        float z[12];
        float mx=-1e30f;
        #pragma unroll
        for(int r=0;r<12;++r){
            int q=base+r;
            float zv=(lg2[(b*TT+l)*TT+q]-muq[q])*scq[q]+shq[q];
            z[r]=zv; mx = fmaxf(mx,zv);
        }
        float s=0.f;
        #pragma unroll
        for(int r=0;r<12;++r){ z[r]=expf(z[r]-mx); s+=z[r]; }
        float is=1.f/s;
        for(int q=0;q<TT;++q){
            float cf = (q>=base && q<base+12) ? z[q-base]*is : 0.f;
            coefs[(b*TT+l)*TT+q]=cf;
            tco[(b*TT+q)*TT+l]=cf;
        }
    }
}

// ---- x1new = xg @ coefs^T ; y = leaky(x1new)+x_input ; LN stats ----
__global__ __launch_bounds__(256, 4) void k_apply(const unsigned* h, fp xin, fp coefs,
        float* y, float* stats){
    __shared__ float cf[TT*TT];
    __shared__ float red[256];
    int blk=blockIdx.x; int b=blk>>7; int c=(blk>>1)&63; int half=blk&1;
    int tid=threadIdx.x;
    for(int i=tid;i<TT*TT;i+=256) cf[i]=coefs[b*TT*TT+i];
    __syncthreads();
    int n = half*256 + tid;
    const unsigned* fb = h + (size_t)b*CO*NT + (size_t)c*(NT/2) + n*12;
    const unsigned* gb = fb + (size_t)CO*(NT/2);
    fp xrow = xin + (size_t)(b*CO+c)*NT + n*TT;
    float* yrow = y + (size_t)(b*CO+c)*NT + n*TT;
    float row[TT];
    #pragma unroll
    for(int k=0;k<3;++k){
        uint4 f = *(const uint4*)(fb + 4*k);
        uint4 g = *(const uint4*)(gb + 4*k);
        row[8*k  ] = sg(lo2f(g.x))*lk(lo2f(f.x));
        row[8*k+1] = sg(hi2f(g.x))*lk(hi2f(f.x));
        row[8*k+2] = sg(lo2f(g.y))*lk(lo2f(f.y));
        row[8*k+3] = sg(hi2f(g.y))*lk(hi2f(f.y));
        row[8*k+4] = sg(lo2f(g.z))*lk(lo2f(f.z));
        row[8*k+5] = sg(hi2f(g.z))*lk(hi2f(f.z));
        row[8*k+6] = sg(lo2f(g.w))*lk(lo2f(f.w));
        row[8*k+7] = sg(hi2f(g.w))*lk(hi2f(f.w));
    }
    float ls=0.f, lsq=0.f;
    #pragma unroll
    for(int k=0;k<6;++k){
        float4 u = *(const float4*)(xrow + 4*k);
        float a0=0.f, a1=0.f, a2=0.f, a3=0.f;
        #pragma unroll
        for(int l=0;l<TT;++l){
            float r = row[l];
            a0 += r*cf[(4*k  )*TT+l];
            a1 += r*cf[(4*k+1)*TT+l];
            a2 += r*cf[(4*k+2)*TT+l];
            a3 += r*cf[(4*k+3)*TT+l];
        }
        float y0 = lk(a0)+u.x, y1 = lk(a1)+u.y, y2 = lk(a2)+u.z, y3 = lk(a3)+u.w;
        *(float4*)(yrow + 4*k) = make_float4(y0,y1,y2,y3);
        ls  += y0+y1+y2+y3;
        lsq += y0*y0+y1*y1+y2*y2+y3*y3;
    }
    red[tid]=ls; __syncthreads();
    for(int s=128;s>0;s>>=1){ if(tid<s) red[tid]+=red[tid+s]; __syncthreads(); }
    float t0=red[0]; __syncthreads();
    red[tid]=lsq; __syncthreads();
    for(int s=128;s>0;s>>=1){ if(tid<s) red[tid]+=red[tid+s]; __syncthreads(); }
    if(tid==0){ atomicAdd(&stats[32+b], t0); atomicAdd(&stats[40+b], red[0]); }
}

// ---------------- final LN apply ----------------
__global__ void k_final(fp y, fp lng, fp lnb, const float* stats, float* out){
    int tot = B_*CO*NT;
    for(int i = blockIdx.x*blockDim.x + threadIdx.x; i<tot; i+=gridDim.x*blockDim.x){
        int b = i/LNCNT; int r = i%LNCNT;
        out[i] = (y[i]-stats[48+b])*stats[56+b]*lng[r]+lnb[r];
    }
}

extern "C" void kernel_launch(void* const* d_in, const int* in_sizes, int n_in,
                              void* d_out, int out_size, void* d_ws, size_t ws_size,
                              hipStream_t stream){
    fp x    = (fp)d_in[0];
    fp adj  = (fp)d_in[1];
    fp w1   = (fp)d_in[2];
    fp b1   = (fp)d_in[3];
    fp wt   = (fp)d_in[4];
    fp bt   = (fp)d_in[5];
    fp lng  = (fp)d_in[6];
    fp lnb  = (fp)d_in[7];
    fp s0ws = (fp)d_in[8];
    fp s0wn = (fp)d_in[9];
    fp s0b  = (fp)d_in[10];
    fp s1ws = (fp)d_in[11];
    fp s1wn = (fp)d_in[12];
    fp s1b  = (fp)d_in[13];
    fp tw1  = (fp)d_in[14];
    fp tw2  = (fp)d_in[15];
    fp twd1 = (fp)d_in[16];
    fp twd2 = (fp)d_in[17];
    fp tW   = (fp)d_in[18];
    fp tbias= (fp)d_in[19];
    fp tv   = (fp)d_in[20];
    fp bng  = (fp)d_in[21];
    fp bnb  = (fp)d_in[22];

    float* W = (float*)d_ws;            // stats [0..63]
    int*   CNTp = (int*)(W+256);        // 512 ints (zeroed each launch)
    float* DEG  = W+768;
    int*   IDXp = (int*)(W+1280);
    float* VALp = W+34048;
    float* F1   = W+66816;
    float* F1C  = W+165120;
    float* F2   = W+263424;
    float* F2C  = W+275712;
    float* G1   = W+288000;
    float* CF   = W+300288;
    float* XIN  = W+304896;
    float* X1   = W+6596352;
    uint4* WFq  = (uint4*)(W+12887808); // sage weight frags: 1024 uint4 = 16KB
    uint4* WCF  = (uint4*)(W+12891904); // conv weight frags: 2048 uint4 = 32KB
    unsigned* HA = (unsigned*)(W+19179264);   // packed bf16 h: 6291456 uints
    float* Y    = W+31762176;           // ends 38053632 floats = 152.2 MB

    float* oout   = (float*)d_out;
    float* o_adj  = oout + 6291456;
    float* o_tc   = oout + 6291456 + 262144;

    hipMemsetAsync(W, 0, 768*sizeof(float), stream);   // stats + cnt
    k_csc<<<1024,256,0,stream>>>(adj, CNTp, IDXp, VALp);
    k_deg<<<2,256,0,stream>>>(CNTp, DEG);
    k_wprep<<<1,256,0,stream>>>(s0ws, s0wn, s1ws, s1wn, WFq);
    k_wcprep<<<1,256,0,stream>>>(w1, wt, WCF);
    k_conv<<<512,256,0,stream>>>(x, WCF, b1, bt, XIN, X1, W);
    k_stat<<<1,64,0,stream>>>(W, 0);
    k_hbuild<<<512,512,0,stream>>>(X1, lng, lnb, W, CNTp, IDXp, VALp, HA);
    k_sageF<<<1024,512,0,stream>>>(HA, WFq, s0b, s1b, CNTp, IDXp, DEG);
    k_f1<<<512,192,0,stream>>>(HA, tw1, F1);
    k_f2<<<512,256,0,stream>>>(HA, tw2, F2);
    k_conv_f1<<<32,256,0,stream>>>(F1, twd1, F1C);
    k_conv_f2<<<8,256,0,stream>>>(F2, twd2, F2C);
    k_g1<<<32,384,0,stream>>>(F1C, tW, G1);
    k_logits<<<1,1024,0,stream>>>(G1, F2C, tbias, tv, bng, bnb, CF, o_tc);
    hipMemcpyAsync(o_adj, d_in[1], 262144*sizeof(float), hipMemcpyDeviceToDevice, stream);
    k_apply<<<1024,256,0,stream>>>(HA, XIN, CF, Y, W);
    k_stat<<<1,64,0,stream>>>(W, 32);
    k_final<<<2048,256,0,stream>>>(Y, lng, lnb, W, oout);
}

// Round 9
// 357.055 us; speedup vs baseline: 1.3764x; 1.1025x over previous
//
#include <hip/hip_runtime.h>
#include <hip/hip_bf16.h>
#include <math.h>

#define B_    8
#define CIN   32
#define CO    64
#define NN    512
#define TT    24
#define NT    (NN*TT)        /* 12288 */
#define LNCNT (CO*NT)        /* 786432 */
#define EPSL  1e-5f
#define MAXNZ 64
#define HSS   28             /* fp32 LDS row stride (hbuild) */

typedef const float* fp;
static __device__ __forceinline__ float lk(float x){ return x > 0.f ? x : 0.01f*x; }
static __device__ __forceinline__ float sg(float x){
    if(x >= 0.f){ float e = expf(-x); return 1.f/(1.f+e); }
    float e = expf(x); return e/(1.f+e);
}
// bf16 pair pack/unpack (lo = even element, hi = odd element)
static __device__ __forceinline__ unsigned pk2(float a, float b){
    __hip_bfloat16 x = __float2bfloat16(a), y = __float2bfloat16(b);
    unsigned lo = *(unsigned short*)&x, hi = *(unsigned short*)&y;
    return lo | (hi<<16);
}
static __device__ __forceinline__ float lo2f(unsigned u){ return __uint_as_float(u<<16); }
static __device__ __forceinline__ float hi2f(unsigned u){ return __uint_as_float(u & 0xffff0000u); }

// ---- CSC build from adj (2% dense), fully parallel; also emits o_adj copy ----
__global__ __launch_bounds__(256) void k_csc(fp adj, int* cnt, int* idx, float* val,
        float* o_adj){
    int e = blockIdx.x*blockDim.x + threadIdx.x;   // 0 .. NN*NN-1
    if(e >= NN*NN) return;
    float a = adj[e];
    o_adj[e] = a;                                  // replaces the D2D memcpy launch
    if(a != 0.f){
        int u = e >> 9, q = e & 511;
        int slot = atomicAdd(&cnt[q], 1);
        if(slot < MAXNZ){ idx[q*MAXNZ+slot] = u; val[q*MAXNZ+slot] = a; }
    }
}

// load 8 weights w[m][kb..kb+7] (T=24 bounds -> 0 pad), split hi/lo bf16 frags
static __device__ __forceinline__ void ldw_split(fp w, int m, int kb, uint4* hi, uint4* lo){
    float vh[8], vl[8];
    #pragma unroll
    for(int j=0;j<8;++j){
        float v = (m < TT && (kb+j) < TT) ? w[m*TT + kb + j] : 0.f;
        __hip_bfloat16 hb = __float2bfloat16(v);
        float hf = __bfloat162float(hb);
        vh[j] = hf;
        vl[j] = v - hf;
    }
    *hi = make_uint4(pk2(vh[0],vh[1]),pk2(vh[2],vh[3]),pk2(vh[4],vh[5]),pk2(vh[6],vh[7]));
    *lo = make_uint4(pk2(vl[0],vl[1]),pk2(vl[2],vl[3]),pk2(vl[4],vl[5]),pk2(vl[6],vl[7]));
}

// ---- merged one-time weight fragment prep (sage + conv) ----
// sage: wf[L*512 + g*128 + P*64 + lane]; conv: wcf[ot*512 + g*128 + P*64 + lane]
__global__ __launch_bounds__(256) void k_wprep(fp s0ws, fp s0wn, fp s1ws, fp s1wn, uint4* wf,
        fp w1, fp wt, uint4* wcf){
    int t = threadIdx.x;
    int lane = t & 63, g = t >> 6;
    {   // sage weights
        int M = g >> 1, H = g & 1;
        int m  = H*16 + (lane&15);
        int kb = (lane>>4)*8;
        for(int L=0; L<2; ++L){
            fp w = L ? (M ? s1wn : s1ws) : (M ? s0wn : s0ws);
            uint4 hi, lo;
            ldw_split(w, m, kb, &hi, &lo);
            wf[L*512 + g*128 +      lane] = hi;
            wf[L*512 + g*128 + 64 + lane] = lo;
        }
    }
    {   // conv weights
        int kb = (lane>>4)*8;
        for(int ot=0; ot<4; ++ot){
            int m = ot*16 + (lane&15);
            float vh[8], vl[8];
            #pragma unroll
            for(int j=0;j<8;++j){
                int c = kb+j;
                float v = (g==0) ? w1[m*CIN+c] : wt[(m*CIN+c)*3 + (g-1)];
                __hip_bfloat16 hb = __float2bfloat16(v);
                float hf = __bfloat162float(hb);
                vh[j]=hf; vl[j]=v-hf;
            }
            wcf[ot*512 + g*128 +      lane] = make_uint4(
                pk2(vh[0],vh[1]),pk2(vh[2],vh[3]),pk2(vh[4],vh[5]),pk2(vh[6],vh[7]));
            wcf[ot*512 + g*128 + 64 + lane] = make_uint4(
                pk2(vl[0],vl[1]),pk2(vl[2],vl[3]),pk2(vl[4],vl[5]),pk2(vl[6],vl[7]));
        }
    }
}

typedef __attribute__((ext_vector_type(8))) short bf16x8;
typedef __attribute__((ext_vector_type(4))) float f32x4;
typedef __attribute__((ext_vector_type(2))) float f32x2;

static __device__ __forceinline__ f32x4 MF(uint4 a, uint4 b, f32x4 c){
    union { uint4 u; bf16x8 v; } A, Bv; A.u = a; Bv.u = b;
    return __builtin_amdgcn_mfma_f32_16x16x32_bf16(A.v, Bv.v, c, 0, 0, 0);
}

// ======================= MFMA conv1 + temporal conv + LN stats ================
#define XST 20
__global__ __launch_bounds__(256, 4) void k_conv(fp x, const uint4* wcf, fp b1, fp bt,
        float* xin, float* x1p, float* stats){
    __shared__ __attribute__((aligned(16))) unsigned xh[208*XST];
    __shared__ __attribute__((aligned(16))) unsigned xl[208*XST];
    __shared__ float red[256];
    int bid = blockIdx.x; int b = bid>>6; int n0 = (bid&63)*8;
    int tid = threadIdx.x; int lane = tid&63; int w = tid>>6;
    for(int i=tid;i<3072;i+=256){
        int cp = i/192; int r = i-cp*192; int node = r/24; int t = r-node*24;
        const float* xp = x + ((size_t)(b*CIN + 2*cp)*NN + n0+node)*TT + t;
        float a = xp[0], b2 = xp[NT];
        __hip_bfloat16 ab = __float2bfloat16(a), bb = __float2bfloat16(b2);
        float ah = __bfloat162float(ab), bh = __bfloat162float(bb);
        int row = node*26 + t + 1;
        xh[row*XST+cp] = pk2(ah, bh);
        xl[row*XST+cp] = pk2(a-ah, b2-bh);
    }
    {   // zero guard rows (t=-1 and t=24 per node): 8*2*16 = 256 slots
        int node = tid>>5; int which = (tid>>4)&1; int j = tid&15;
        int row = node*26 + which*25;
        xh[row*XST+j]=0; xl[row*XST+j]=0;
    }
    const uint4* wb = wcf + w*512;
    uint4 h1 = wb[      lane], l1 = wb[ 64+lane];
    uint4 ht0= wb[128 + lane], lt0= wb[192+lane];
    uint4 ht1= wb[256 + lane], lt1= wb[320+lane];
    uint4 ht2= wb[384 + lane], lt2= wb[448+lane];
    int mrow = (lane>>4)*4;
    float bi0[4], bi1[4];
    #pragma unroll
    for(int r2=0;r2<4;++r2){
        int o = w*16 + mrow + r2;
        bi0[r2]=b1[o]; bi1[r2]=bt[o];
    }
    __syncthreads();
    float ls=0.f, lsq=0.f;
    int kb4 = (lane>>4)*4;
    for(int pt=0; pt<12; ++pt){
        int p = pt*16 + (lane&15);
        int node = p/24, t = p-node*24;
        int rc = (node*26 + t + 1)*XST;
        uint4 Bhm = *(const uint4*)&xh[rc - XST + kb4];
        uint4 Blm = *(const uint4*)&xl[rc - XST + kb4];
        uint4 Bhc = *(const uint4*)&xh[rc       + kb4];
        uint4 Blc = *(const uint4*)&xl[rc       + kb4];
        uint4 Bhp = *(const uint4*)&xh[rc + XST + kb4];
        uint4 Blp = *(const uint4*)&xl[rc + XST + kb4];
        f32x4 D0 = {bi0[0],bi0[1],bi0[2],bi0[3]};
        f32x4 D1 = {bi1[0],bi1[1],bi1[2],bi1[3]};
        D0 = MF(h1, Bhc, D0); D0 = MF(l1, Bhc, D0); D0 = MF(h1, Blc, D0);
        D1 = MF(ht0,Bhm, D1); D1 = MF(lt0,Bhm, D1); D1 = MF(ht0,Blm, D1);
        D1 = MF(ht1,Bhc, D1); D1 = MF(lt1,Bhc, D1); D1 = MF(ht1,Blc, D1);
        D1 = MF(ht2,Bhp, D1); D1 = MF(lt2,Bhp, D1); D1 = MF(ht2,Blp, D1);
        size_t gbase = ((size_t)(b*CO + w*16 + mrow)*NN + n0+node)*TT + t;
        #pragma unroll
        for(int r2=0;r2<4;++r2){
            xin[gbase + (size_t)r2*NT] = D0[r2];
            x1p[gbase + (size_t)r2*NT] = D1[r2];
            ls  += D1[r2];
            lsq += D1[r2]*D1[r2];
        }
    }
    red[tid]=ls; __syncthreads();
    for(int s=128;s>0;s>>=1){ if(tid<s) red[tid]+=red[tid+s]; __syncthreads(); }
    float tsum = red[0]; __syncthreads();
    red[tid]=lsq; __syncthreads();
    for(int s=128;s>0;s>>=1){ if(tid<s) red[tid]+=red[tid+s]; __syncthreads(); }
    if(tid==0){ atomicAdd(&stats[b], tsum); atomicAdd(&stats[8+b], red[0]); }
}

// ---- LN+leaky (fused) then h = stack(4*x1, adj^T x1); h stored packed bf16 ----
// Round 9: LN stats finalize inlined (k_stat launch dropped); cnt clamp inlined
// (k_deg launch dropped). Same arithmetic as k_stat -> bit-identical.
__global__ __launch_bounds__(512, 4) void k_hbuild(fp x1p, fp lng, fp lnb,
        const float* stats, const int* cnt, const int* idx, const float* val, unsigned* h){
    __shared__ float xs[NN*HSS];          // 57.3 KB
    int blk = blockIdx.x; int b = blk >> 6; int c = blk & 63;
    int tid = threadIdx.x;
    float mm = stats[b] / (float)LNCNT;
    float vv = fmaxf(stats[8+b] / (float)LNCNT - mm*mm, 0.f);
    float m = mm, inv = rsqrtf(vv + EPSL);
    fp src  = x1p + (size_t)(b*CO + c)*NT;
    fp gsrc = lng + (size_t)c*NT;
    fp bsrc = lnb + (size_t)c*NT;
    for(int i4=tid;i4<NT/4;i4+=512){
        int i = i4*4;
        int n = i/TT, t = i-n*TT;
        float4 s  = *(const float4*)(src + i);
        float4 g  = *(const float4*)(gsrc + i);
        float4 bb = *(const float4*)(bsrc + i);
        *(float4*)&xs[n*HSS + t] = make_float4(
            lk((s.x-m)*inv*g.x+bb.x), lk((s.y-m)*inv*g.y+bb.y),
            lk((s.z-m)*inv*g.z+bb.z), lk((s.w-m)*inv*g.w+bb.w));
    }
    int n = tid;
    int c0 = cnt[n];
    int cq = c0 > MAXNZ ? MAXNZ : c0;
    int4 j0 = *(const int4*)&idx[n*MAXNZ+0];   // prefetch (entries >= cq unused)
    int4 j1 = *(const int4*)&idx[n*MAXNZ+4];
    int4 j2 = *(const int4*)&idx[n*MAXNZ+8];
    float4 v0 = *(const float4*)&val[n*MAXNZ+0];
    float4 v1 = *(const float4*)&val[n*MAXNZ+4];
    float4 v2 = *(const float4*)&val[n*MAXNZ+8];
    __syncthreads();
    float acc[TT];
    #pragma unroll
    for(int l=0;l<TT;++l) acc[l]=0.f;
#define HB(J,U,V) if((J)<cq){ const float4* rp=(const float4*)&xs[(U)*HSS]; \
    _Pragma("unroll") for(int k=0;k<6;++k){ float4 wv=rp[k]; \
        acc[4*k]+=(V)*wv.x; acc[4*k+1]+=(V)*wv.y; acc[4*k+2]+=(V)*wv.z; acc[4*k+3]+=(V)*wv.w; } }
    HB(0,j0.x,v0.x) HB(1,j0.y,v0.y) HB(2,j0.z,v0.z) HB(3,j0.w,v0.w)
    HB(4,j1.x,v1.x) HB(5,j1.y,v1.y) HB(6,j1.z,v1.z) HB(7,j1.w,v1.w)
    HB(8,j2.x,v2.x) HB(9,j2.y,v2.y) HB(10,j2.z,v2.z) HB(11,j2.w,v2.w)
    for(int j=12;j<cq;++j){
        int u = idx[n*MAXNZ+j]; float v = val[n*MAXNZ+j];
        const float4* rp = (const float4*)&xs[u*HSS];
        #pragma unroll
        for(int k=0;k<6;++k){ float4 wv=rp[k];
            acc[4*k]+=v*wv.x; acc[4*k+1]+=v*wv.y; acc[4*k+2]+=v*wv.z; acc[4*k+3]+=v*wv.w; }
    }
    float t1[TT];
    const float4* sp = (const float4*)&xs[n*HSS];
    #pragma unroll
    for(int k=0;k<6;++k){
        float4 v = sp[k];
        t1[4*k]=v.x; t1[4*k+1]=v.y; t1[4*k+2]=v.z; t1[4*k+3]=v.w;
    }
    unsigned* h0 = h + (size_t)((b*CO+c)*2)*(NT/2);
    unsigned* h1 = h0 + NT/2;
    #pragma unroll
    for(int k=0;k<3;++k){
        *(uint4*)(h0 + n*12 + 4*k) = make_uint4(
            pk2(4.f*t1[8*k],  4.f*t1[8*k+1]), pk2(4.f*t1[8*k+2],4.f*t1[8*k+3]),
            pk2(4.f*t1[8*k+4],4.f*t1[8*k+5]), pk2(4.f*t1[8*k+6],4.f*t1[8*k+7]));
        *(uint4*)(h1 + n*12 + 4*k) = make_uint4(
            pk2(acc[8*k],  acc[8*k+1]), pk2(acc[8*k+2],acc[8*k+3]),
            pk2(acc[8*k+4],acc[8*k+5]), pk2(acc[8*k+6],acc[8*k+7]));
    }
}

// ======================= MFMA-based fused GraphSAGE x2 =======================
// Round 9: deginv computed inline from cnt (k_deg launch dropped; same ops).
static __device__ __forceinline__ void acc8v(f32x2* t, uint4 q){
    t[0] += (f32x2){lo2f(q.x), hi2f(q.x)};
    t[1] += (f32x2){lo2f(q.y), hi2f(q.y)};
    t[2] += (f32x2){lo2f(q.z), hi2f(q.z)};
    t[3] += (f32x2){lo2f(q.w), hi2f(q.w)};
}

#define GBODY(u) { int ro=(u)*12; \
    uint4 q0=*(const uint4*)&hsb[ro]; \
    uint4 q1=*(const uint4*)&hsb[ro+4]; \
    uint4 q2=*(const uint4*)&hsb[ro+8]; \
    acc8v(t2v,q0); acc8v(t2v+4,q1); acc8v(t2v+8,q2); }
#define GSTEP(J,U) if((J)<cq) GBODY(U)

__global__ __launch_bounds__(512, 4) void k_sageF(unsigned* h, const uint4* wf,
        fp s0b, fp s1b, const int* cnt, const int* idx){
    __shared__ unsigned hsb[NN*12];       // 24 KB, the ONLY buffer
    int tid  = threadIdx.x;
    int lane = tid & 63;
    int wv   = tid >> 6;
    unsigned* base = h + (size_t)blockIdx.x*(NT/2);

    for(int i=tid;i<1536;i+=512) ((uint4*)hsb)[i] = ((const uint4*)base)[i];
    int n  = tid;              // gather: this thread owns node n
    int c0 = cnt[n];
    float di = 1.f / (float)(c0 < 1 ? 1 : c0);
    int cq = c0 > MAXNZ ? MAXNZ : c0;
    int4 i0 = *(const int4*)&idx[n*MAXNZ+0];   // prefetch (entries >= cq unused)
    int4 i1 = *(const int4*)&idx[n*MAXNZ+4];
    int4 i2 = *(const int4*)&idx[n*MAXNZ+8];
    __syncthreads();

    for(int layer=0; layer<2; ++layer){
        const uint4* wl = wf + layer*512;
        uint4 wsHiA = wl[      lane], wsLoA = wl[ 64+lane];
        uint4 wsHiB = wl[128 + lane], wsLoB = wl[192+lane];
        uint4 wnHiA = wl[256 + lane], wnLoA = wl[320+lane];
        uint4 wnHiB = wl[384 + lane], wnLoB = wl[448+lane];
        fp Bp = layer ? s1b : s0b;
        float biA[4], biB[4];
        #pragma unroll
        for(int r=0;r<4;++r){
            biA[r] = Bp[(lane>>4)*4 + r];
            int m2 = 16 + (lane>>4)*4 + r;
            biB[r] = (m2 < TT) ? Bp[m2] : 0.f;
        }

        // ---- phase 1: gather t2 (reads hsb); load B0 frags (own rows) ----
        f32x2 t2v[12];
        #pragma unroll
        for(int l=0;l<12;++l) t2v[l] = (f32x2){0.f,0.f};
        GSTEP(0,i0.x) GSTEP(1,i0.y) GSTEP(2,i0.z) GSTEP(3,i0.w)
        GSTEP(4,i1.x) GSTEP(5,i1.y) GSTEP(6,i1.z) GSTEP(7,i1.w)
        GSTEP(8,i2.x) GSTEP(9,i2.y) GSTEP(10,i2.z) GSTEP(11,i2.w)
        for(int j=12;j<cq;++j){ int u=idx[n*MAXNZ+j]; GBODY(u) }
        #pragma unroll
        for(int l=0;l<12;++l) t2v[l] *= di;

        uint4 b0[4];
        #pragma unroll
        for(int i=0;i<4;++i) b0[i]=make_uint4(0,0,0,0);
        if(lane < 48){
            #pragma unroll
            for(int i=0;i<4;++i){
                int nn_ = wv*64 + i*16 + (lane&15);
                b0[i] = *(const uint4*)&hsb[nn_*12 + ((lane>>4)<<2)];
            }
        }
        __syncthreads();   // ALL hsb reads (gather + B0, all waves) complete

        // ---- t2 pack -> own hsb row (input slab now dead) ----
        *(uint4*)&hsb[n*12  ] = make_uint4(
            pk2(t2v[0].x,t2v[0].y), pk2(t2v[1].x,t2v[1].y),
            pk2(t2v[2].x,t2v[2].y), pk2(t2v[3].x,t2v[3].y));
        *(uint4*)&hsb[n*12+4] = make_uint4(
            pk2(t2v[4].x,t2v[4].y), pk2(t2v[5].x,t2v[5].y),
            pk2(t2v[6].x,t2v[6].y), pk2(t2v[7].x,t2v[7].y));
        *(uint4*)&hsb[n*12+8] = make_uint4(
            pk2(t2v[8].x,t2v[8].y), pk2(t2v[9].x,t2v[9].y),
            pk2(t2v[10].x,t2v[10].y), pk2(t2v[11].x,t2v[11].y));
        __syncthreads();   // t2 rows visible

        // ---- phase 2: B1 frags (own rows), 32 MFMAs, pack, D -> own rows ----
        uint4 b1[4];
        #pragma unroll
        for(int i=0;i<4;++i) b1[i]=make_uint4(0,0,0,0);
        if(lane < 48){
            #pragma unroll
            for(int i=0;i<4;++i){
                int nn_ = wv*64 + i*16 + (lane&15);
                b1[i] = *(const uint4*)&hsb[nn_*12 + ((lane>>4)<<2)];
            }
        }
        uint2 pa[4], pb[4];
        #pragma unroll
        for(int i=0;i<4;++i){
            f32x4 Da = {biA[0],biA[1],biA[2],biA[3]};
            f32x4 Db = {biB[0],biB[1],biB[2],biB[3]};
            Da = MF(wsHiA, b0[i], Da);
            Da = MF(wsLoA, b0[i], Da);
            Da = MF(wnHiA, b1[i], Da);
            Da = MF(wnLoA, b1[i], Da);
            Db = MF(wsHiB, b0[i], Db);
            Db = MF(wsLoB, b0[i], Db);
            Db = MF(wnHiB, b1[i], Db);
            Db = MF(wnLoB, b1[i], Db);
            pa[i] = make_uint2(pk2(Da[0],Da[1]), pk2(Da[2],Da[3]));
            pb[i] = make_uint2(pk2(Db[0],Db[1]), pk2(Db[2],Db[3]));
        }
        __syncthreads();   // all B1 reads done before D overwrites rows
        #pragma unroll
        for(int i=0;i<4;++i){
            int nn_ = wv*64 + i*16 + (lane&15);
            int o = (lane>>4)*2;           // uints {0,2,4,6}: m = 2o..2o+3
            *(uint2*)&hsb[nn_*12 + o] = pa[i];
            if(lane < 32){                 // m = 16..23 -> uints {8,10}
                *(uint2*)&hsb[nn_*12 + 8 + (lane>>4)*2] = pb[i];
            }
        }
        __syncthreads();   // D visible for next layer's gather / writeback
    }
    for(int i=tid;i<1536;i+=512) ((uint4*)base)[i] = ((const uint4*)hsb)[i];
}

// ---- merged f1+f2 (round 9): blocks [0,512) = f1 role, [512,1024) = f2 ----
#define F2S 25
__global__ __launch_bounds__(256) void k_f12(const unsigned* h, fp w1, fp w2,
        float* f1, float* f2){
    __shared__ float red[256*F2S];
    int tid = threadIdx.x;
    if(blockIdx.x < 512){
        // f1[b,l,n] = sum_c sg(gate)*lk(filt)*w1[c]
        if(tid < 192){
            int blk = blockIdx.x; int b = blk>>6; int n0 = (blk&63)*8;
            float acc = 0.f;
            const unsigned* fb = h + (size_t)b*CO*NT + n0*12;
            const unsigned* gb = fb + (size_t)CO*(NT/2);
            int e = tid;
            for(int c=0;c<CO;++c){
                float w = w1[c];
                unsigned f = fb[(size_t)c*(NT/2) + (e>>1)];
                unsigned g = gb[(size_t)c*(NT/2) + (e>>1)];
                float fv = (e&1) ? hi2f(f) : lo2f(f);
                float gv = (e&1) ? hi2f(g) : lo2f(g);
                acc += sg(gv)*lk(fv)*w;
            }
            int nl = e/TT, t = e%TT;
            f1[(b*TT+t)*NN + n0+nl] = acc;
        }
        return;
    }
    // f2[b,c,l] = sum_n sg(gate)*lk(filt)*w2[n]
    int blk = blockIdx.x - 512; int b = blk/CO; int c = blk%CO;
    float acc[TT];
    #pragma unroll
    for(int l=0;l<TT;++l) acc[l]=0.f;
    const unsigned* fb = h + (size_t)b*CO*NT + (size_t)c*(NT/2);
    const unsigned* gb = fb + (size_t)CO*(NT/2);
    for(int n=tid;n<NN;n+=256){
        float w = w2[n];
        #pragma unroll
        for(int k=0;k<3;++k){
            uint4 f = *(const uint4*)(fb + n*12 + 4*k);
            uint4 g = *(const uint4*)(gb + n*12 + 4*k);
            acc[8*k  ] += sg(lo2f(g.x))*lk(lo2f(f.x))*w;
            acc[8*k+1] += sg(hi2f(g.x))*lk(hi2f(f.x))*w;
            acc[8*k+2] += sg(lo2f(g.y))*lk(lo2f(f.y))*w;
            acc[8*k+3] += sg(hi2f(g.y))*lk(hi2f(f.y))*w;
            acc[8*k+4] += sg(lo2f(g.z))*lk(lo2f(f.z))*w;
            acc[8*k+5] += sg(hi2f(g.z))*lk(hi2f(f.z))*w;
            acc[8*k+6] += sg(lo2f(g.w))*lk(lo2f(f.w))*w;
            acc[8*k+7] += sg(hi2f(g.w))*lk(hi2f(f.w))*w;
        }
    }
    #pragma unroll
    for(int l=0;l<TT;++l) red[tid*F2S+l]=acc[l];
    __syncthreads();
    for(int s=128;s>0;s>>=1){
        if(tid<s){
            #pragma unroll
            for(int l=0;l<TT;++l) red[tid*F2S+l]+=red[(tid+s)*F2S+l];
        }
        __syncthreads();
    }
    if(tid<TT) f2[(b*CO+c)*TT+tid] = red[tid];
}

// ---------------- dilated(2) conv over n on f1 ; split 4x over n ----------------
__global__ __launch_bounds__(256) void k_conv_f1(fp f1, fp wd1, float* f1c){
    __shared__ float fs[TT][130];
    __shared__ float w0[TT*TT], w1a[TT*TT];
    int bid = blockIdx.x; int b = bid>>2; int n0 = (bid&3)*128;
    int tid=threadIdx.x;
    for(int i=tid;i<TT*130;i+=256){
        int l=i/130, col=i%130; int n = n0+col-1;
        fs[l][col] = (n>=0 && n<NN) ? f1[(b*TT+l)*NN+n] : 0.f;
    }
    for(int i=tid;i<TT*TT;i+=256){ w0[i]=wd1[i*2]; w1a[i]=wd1[i*2+1]; }
    __syncthreads();
    for(int j=tid;j<TT*128;j+=256){
        int o=j>>7, nn=j&127;
        float acc=0.f;
        #pragma unroll
        for(int i=0;i<TT;++i) acc += fs[i][nn]*w0[o*TT+i] + fs[i][nn+2]*w1a[o*TT+i];
        f1c[(b*TT+o)*NN+n0+nn]=acc;
    }
}

// ---------------- dilated(2) conv over l on f2 ----------------
__global__ __launch_bounds__(256) void k_conv_f2(fp f2, fp wd2, float* f2c){
    __shared__ float fs[CO][TT+2];
    __shared__ float w0[CO*CO], w1a[CO*CO];
    int b = blockIdx.x; int tid=threadIdx.x;
    for(int i=tid;i<CO*TT;i+=256){ int c=i/TT,l=i%TT; fs[c][l+1]=f2[(b*CO+c)*TT+l]; }
    for(int c=tid;c<CO;c+=256){ fs[c][0]=0.f; fs[c][TT+1]=0.f; }
    for(int i=tid;i<CO*CO;i+=256){ w0[i]=wd2[i*2]; w1a[i]=wd2[i*2+1]; }
    __syncthreads();
    for(int j=tid;j<CO*TT;j+=256){
        int o=j/TT, l=j%TT;
        float acc=0.f;
        for(int i=0;i<CO;++i) acc += fs[i][l]*w0[o*CO+i] + fs[i][l+2]*w1a[o*CO+i];
        f2c[(b*CO+o)*TT+l]=acc;
    }
}

// ---------------- g1[b,l,c] = sum_n f1c[b,l,n]*tW[n,c] ----------------
__global__ __launch_bounds__(384) void k_g1(fp f1c, fp tW, float* g1){
    __shared__ float fs[6*NN];
    int blk=blockIdx.x; int b=blk>>2; int part=blk&3;
    int tid=threadIdx.x;
    for(int i=tid;i<6*NN;i+=384) fs[i]=f1c[b*TT*NN + part*6*NN + i];
    __syncthreads();
    int c = tid & 63; int r = tid >> 6;   // r = 0..5
    float acc=0.f;
    for(int n=0;n<NN;++n) acc += fs[r*NN + n]*tW[n*CO + c];
    g1[(b*TT + part*6 + r)*CO + c] = acc;
}

// -------- logits split (round 9): was one 1-block kernel, ~25us on one CU ------
// A: sig = sigmoid(g1 @ f2c + bias), 4608 outputs, 18 blocks
__global__ __launch_bounds__(256) void k_lgA(fp g1, fp f2c, fp tbias, float* sig){
    int j = blockIdx.x*256 + threadIdx.x;
    int b=j/(TT*TT); int r=j%(TT*TT); int l=r/TT; int q=r%TT;
    float acc = tbias[l*TT+q];
    fp gg = g1 + (b*TT+l)*CO;
    fp ff = f2c + b*CO*TT + q;
    for(int c=0;c<CO;++c) acc += gg[c]*ff[c*TT];
    sig[j] = sg(acc);
}
// B: lg2 = t_v @ sig, 4608 outputs, 18 blocks
__global__ __launch_bounds__(256) void k_lgB(fp tv, const float* sig, float* lg2){
    int j = blockIdx.x*256 + threadIdx.x;
    int b=j/(TT*TT); int r=j%(TT*TT); int l=r/TT; int q=r%TT;
    float acc=0.f;
    for(int k=0;k<TT;++k) acc += tv[l*TT+k]*sig[(b*TT+k)*TT+q];
    lg2[j]=acc;
}
// C: BN stats + masked softmax + transpose (tiny, 1 block)
__global__ __launch_bounds__(256) void k_lgC(const float* lg2, fp bng, fp bnb,
        float* coefs, float* tco){
    __shared__ float muq[TT], scq[TT], shq[TT];
    int tid=threadIdx.x;
    if(tid<TT){
        int q=tid;
        float s=0.f;
        for(int b=0;b<B_;++b) for(int l=0;l<TT;++l) s += lg2[(b*TT+l)*TT+q];
        float mu = s/192.f;
        float v=0.f;
        for(int b=0;b<B_;++b) for(int l=0;l<TT;++l){ float d = lg2[(b*TT+l)*TT+q]-mu; v += d*d; }
        v = fmaxf(v/192.f, 0.f);
        muq[q]=mu; scq[q]=rsqrtf(v+EPSL)*bng[q]; shq[q]=bnb[q];
    }
    __syncthreads();
    if(tid<192){
        int b=tid/TT, l=tid%TT;
        int base = (l<12)?0:12;
        float z[12];
        float mx=-1e30f;
        #pragma unroll
        for(int r=0;r<12;++r){
            int q=base+r;
            float zv=(lg2[(b*TT+l)*TT+q]-muq[q])*scq[q]+shq[q];
            z[r]=zv; mx = fmaxf(mx,zv);
        }
        float s=0.f;
        #pragma unroll
        for(int r=0;r<12;++r){ z[r]=expf(z[r]-mx); s+=z[r]; }
        float is=1.f/s;
        for(int q=0;q<TT;++q){
            float cf = (q>=base && q<base+12) ? z[q-base]*is : 0.f;
            coefs[(b*TT+l)*TT+q]=cf;
            tco[(b*TT+q)*TT+l]=cf;
        }
    }
}

// ---- x1new = xg @ coefs^T ; y = leaky(x1new)+x_input ; LN stats ----
__global__ __launch_bounds__(256, 4) void k_apply(const unsigned* h, fp xin, fp coefs,
        float* y, float* stats){
    __shared__ float cf[TT*TT];
    __shared__ float red[256];
    int blk=blockIdx.x; int b=blk>>7; int c=(blk>>1)&63; int half=blk&1;
    int tid=threadIdx.x;
    for(int i=tid;i<TT*TT;i+=256) cf[i]=coefs[b*TT*TT+i];
    __syncthreads();
    int n = half*256 + tid;
    const unsigned* fb = h + (size_t)b*CO*NT + (size_t)c*(NT/2) + n*12;
    const unsigned* gb = fb + (size_t)CO*(NT/2);
    fp xrow = xin + (size_t)(b*CO+c)*NT + n*TT;
    float* yrow = y + (size_t)(b*CO+c)*NT + n*TT;
    float row[TT];
    #pragma unroll
    for(int k=0;k<3;++k){
        uint4 f = *(const uint4*)(fb + 4*k);
        uint4 g = *(const uint4*)(gb + 4*k);
        row[8*k  ] = sg(lo2f(g.x))*lk(lo2f(f.x));
        row[8*k+1] = sg(hi2f(g.x))*lk(hi2f(f.x));
        row[8*k+2] = sg(lo2f(g.y))*lk(lo2f(f.y));
        row[8*k+3] = sg(hi2f(g.y))*lk(hi2f(f.y));
        row[8*k+4] = sg(lo2f(g.z))*lk(lo2f(f.z));
        row[8*k+5] = sg(hi2f(g.z))*lk(hi2f(f.z));
        row[8*k+6] = sg(lo2f(g.w))*lk(lo2f(f.w));
        row[8*k+7] = sg(hi2f(g.w))*lk(hi2f(f.w));
    }
    float ls=0.f, lsq=0.f;
    #pragma unroll
    for(int k=0;k<6;++k){
        float4 u = *(const float4*)(xrow + 4*k);
        float a0=0.f, a1=0.f, a2=0.f, a3=0.f;
        #pragma unroll
        for(int l=0;l<TT;++l){
            float r = row[l];
            a0 += r*cf[(4*k  )*TT+l];
            a1 += r*cf[(4*k+1)*TT+l];
            a2 += r*cf[(4*k+2)*TT+l];
            a3 += r*cf[(4*k+3)*TT+l];
        }
        float y0 = lk(a0)+u.x, y1 = lk(a1)+u.y, y2 = lk(a2)+u.z, y3 = lk(a3)+u.w;
        *(float4*)(yrow + 4*k) = make_float4(y0,y1,y2,y3);
        ls  += y0+y1+y2+y3;
        lsq += y0*y0+y1*y1+y2*y2+y3*y3;
    }
    red[tid]=ls; __syncthreads();
    for(int s=128;s>0;s>>=1){ if(tid<s) red[tid]+=red[tid+s]; __syncthreads(); }
    float t0=red[0]; __syncthreads();
    red[tid]=lsq; __syncthreads();
    for(int s=128;s>0;s>>=1){ if(tid<s) red[tid]+=red[tid+s]; __syncthreads(); }
    if(tid==0){ atomicAdd(&stats[32+b], t0); atomicAdd(&stats[40+b], red[0]); }
}

// ---------------- final LN apply; stats finalize inlined (k_stat dropped) ------
__global__ void k_final(fp y, fp lng, fp lnb, const float* stats, float* out){
    float mb[8], sb[8];
    #pragma unroll
    for(int b=0;b<8;++b){
        float mm = stats[32+b] / (float)LNCNT;
        float vv = fmaxf(stats[40+b] / (float)LNCNT - mm*mm, 0.f);
        mb[b]=mm; sb[b]=rsqrtf(vv + EPSL);
    }
    int tot = B_*CO*NT;
    for(int i = blockIdx.x*blockDim.x + threadIdx.x; i<tot; i+=gridDim.x*blockDim.x){
        int b = i/LNCNT; int r = i%LNCNT;
        out[i] = (y[i]-mb[b])*sb[b]*lng[r]+lnb[r];
    }
}

extern "C" void kernel_launch(void* const* d_in, const int* in_sizes, int n_in,
                              void* d_out, int out_size, void* d_ws, size_t ws_size,
                              hipStream_t stream){
    fp x    = (fp)d_in[0];
    fp adj  = (fp)d_in[1];
    fp w1   = (fp)d_in[2];
    fp b1   = (fp)d_in[3];
    fp wt   = (fp)d_in[4];
    fp bt   = (fp)d_in[5];
    fp lng  = (fp)d_in[6];
    fp lnb  = (fp)d_in[7];
    fp s0ws = (fp)d_in[8];
    fp s0wn = (fp)d_in[9];
    fp s0b  = (fp)d_in[10];
    fp s1ws = (fp)d_in[11];
    fp s1wn = (fp)d_in[12];
    fp s1b  = (fp)d_in[13];
    fp tw1  = (fp)d_in[14];
    fp tw2  = (fp)d_in[15];
    fp twd1 = (fp)d_in[16];
    fp twd2 = (fp)d_in[17];
    fp tW   = (fp)d_in[18];
    fp tbias= (fp)d_in[19];
    fp tv   = (fp)d_in[20];
    fp bng  = (fp)d_in[21];
    fp bnb  = (fp)d_in[22];

    float* W = (float*)d_ws;            // stats [0..63]
    int*   CNTp = (int*)(W+256);        // 512 ints (zeroed each launch)
    int*   IDXp = (int*)(W+1280);
    float* VALp = W+34048;
    float* F1   = W+66816;
    float* F1C  = W+165120;
    float* F2   = W+263424;
    float* F2C  = W+275712;
    float* G1   = W+288000;
    float* CF   = W+300288;
    float* XIN  = W+304896;
    float* X1   = W+6596352;
    float* SIG  = W+6596352;            // reuse X1 head (dead after hbuild)... 
    uint4* WFq  = (uint4*)(W+12887808); // sage weight frags: 1024 uint4 = 16KB
    uint4* WCF  = (uint4*)(W+12891904); // conv weight frags: 2048 uint4 = 32KB
    unsigned* HA = (unsigned*)(W+19179264);   // packed bf16 h: 6291456 uints
    float* Y    = W+31762176;           // ends 38053632 floats = 152.2 MB
    // SIG/LG2 occupy X1's first 9216 floats — X1 is consumed by k_hbuild which
    // runs before k_lgA/B/C; no later reader of X1.
    float* LG2  = SIG + 4608;

    float* oout   = (float*)d_out;
    float* o_adj  = oout + 6291456;
    float* o_tc   = oout + 6291456 + 262144;

    hipMemsetAsync(W, 0, 768*sizeof(float), stream);   // stats + cnt
    k_csc<<<1024,256,0,stream>>>(adj, CNTp, IDXp, VALp, o_adj);
    k_wprep<<<1,256,0,stream>>>(s0ws, s0wn, s1ws, s1wn, WFq, w1, wt, WCF);
    k_conv<<<512,256,0,stream>>>(x, WCF, b1, bt, XIN, X1, W);
    k_hbuild<<<512,512,0,stream>>>(X1, lng, lnb, W, CNTp, IDXp, VALp, HA);
    k_sageF<<<1024,512,0,stream>>>(HA, WFq, s0b, s1b, CNTp, IDXp);
    k_f12<<<1024,256,0,stream>>>(HA, tw1, tw2, F1, F2);
    k_conv_f1<<<32,256,0,stream>>>(F1, twd1, F1C);
    k_conv_f2<<<8,256,0,stream>>>(F2, twd2, F2C);
    k_g1<<<32,384,0,stream>>>(F1C, tW, G1);
    k_lgA<<<18,256,0,stream>>>(G1, F2C, tbias, SIG);
    k_lgB<<<18,256,0,stream>>>(tv, SIG, LG2);
    k_lgC<<<1,256,0,stream>>>(LG2, bng, bnb, CF, o_tc);
    k_apply<<<1024,256,0,stream>>>(HA, XIN, CF, Y, W);
    k_final<<<2048,256,0,stream>>>(Y, lng, lnb, W, oout);
}